// Round 20
// 471.537 us; speedup vs baseline: 1.5274x; 1.0360x over previous
//
#include <hip/hip_runtime.h>
#include <hip/hip_bf16.h>
#include <math.h>

#define DIMC 512
#define HEADS 8
#define HD 64
#define BB 4
#define HWX 1024
#define TXT 77
#define LATC 512
#define NE 8
#define HIDC 2048
#define NTOK 4096
#define MAXT 72           // MoE tiles of 64: 4096/64 + 8

typedef __attribute__((ext_vector_type(8))) short bf16x8;
typedef __attribute__((ext_vector_type(4))) float f32x4;
typedef __hip_bfloat16 bf16;

__device__ __forceinline__ void split2(float v, bf16& h, bf16& l) {
    h = __float2bfloat16(v);
    l = __float2bfloat16(v - __bfloat162float(h));
}
__device__ __forceinline__ void split2s(float v, short& h, short& l) {
    bf16 hb, lb; split2(v, hb, lb);
    h = *(short*)&hb; l = *(short*)&lb;
}

// ---------------- both styles in one launch: job 0 = in, job 1 = out ----------------
__global__ void style2_kernel(const float* __restrict__ w,
                              const float* __restrict__ mwA, const float* __restrict__ mbA,
                              const float* __restrict__ mwB, const float* __restrict__ mbB,
                              float* __restrict__ sA, float* __restrict__ sB) {
    int g = blockIdx.x * blockDim.x + threadIdx.x;
    int job = (g >= BB * DIMC) ? 1 : 0;
    int t = g - job * BB * DIMC;
    if (t >= BB * DIMC) return;
    const float* mw = job ? mwB : mwA;
    const float* mb = job ? mbB : mbA;
    float* st = job ? sB : sA;
    int b = t / DIMC, i = t % DIMC;
    const float* wr = w + (long)b * LATC;
    const float* mr = mw + (long)i * LATC;
    float s = 0.f;
    #pragma unroll 8
    for (int l = 0; l < LATC; l++) s += wr[l] * mr[l];
    st[t] = s + mb[i];
}

// ------- both wtmods in one launch -------
__global__ void wtmod2_kernel(const float* __restrict__ wA, const float* __restrict__ sA,
                              const float* __restrict__ wB, const float* __restrict__ sB,
                              bf16* __restrict__ whA, bf16* __restrict__ wlA,
                              bf16* __restrict__ whB, bf16* __restrict__ wlB) {
    int gb = blockIdx.x;
    int job = (gb >= BB * DIMC) ? 1 : 0;
    int bo = gb - job * BB * DIMC;
    const float* weight = job ? wB : wA;
    const float* style  = job ? sB : sA;
    bf16* wh = job ? whB : whA;
    bf16* wl = job ? wlB : wlA;
    int b = bo / DIMC, o = bo % DIMC;
    const float* wr = weight + (long)o * DIMC;
    const float* sr = style + (long)b * DIMC;
    int t = threadIdx.x;
    float vals[2]; float part = 0.f;
    for (int j = 0; j < 2; j++) {
        int i = t + j * 256;
        float v = wr[i] * sr[i];
        vals[j] = v; part += v * v;
    }
    __shared__ float red[256];
    red[t] = part; __syncthreads();
    for (int s = 128; s > 0; s >>= 1) { if (t < s) red[t] += red[t + s]; __syncthreads(); }
    float d = rsqrtf(red[0] + 1e-8f);
    for (int j = 0; j < 2; j++) {
        int i = t + j * 256;
        bf16 h, l; split2(vals[j] * d, h, l);
        wh[(long)bo * DIMC + i] = h; wl[(long)bo * DIMC + i] = l;
    }
}

// ---------------- fused segmented fp32 -> bf16 hi/lo convert (5 weight arrays) ----------------
__global__ void cvtall_kernel(
    const float* __restrict__ s0, bf16* __restrict__ h0, bf16* __restrict__ l0, int n0,
    const float* __restrict__ s1, bf16* __restrict__ h1, bf16* __restrict__ l1, int n1,
    const float* __restrict__ s2, bf16* __restrict__ h2, bf16* __restrict__ l2, int n2,
    const float* __restrict__ s3, bf16* __restrict__ h3, bf16* __restrict__ l3, int n3,
    const float* __restrict__ s4, bf16* __restrict__ h4, bf16* __restrict__ l4, int n4) {
    int i = (blockIdx.x * blockDim.x + threadIdx.x) * 4;
    const float* src; bf16 *hh, *ll;
    if (i < n0) { src = s0; hh = h0; ll = l0; }
    else if ((i -= n0) < n1) { src = s1; hh = h1; ll = l1; }
    else if ((i -= n1) < n2) { src = s2; hh = h2; ll = l2; }
    else if ((i -= n2) < n3) { src = s3; hh = h3; ll = l3; }
    else if ((i -= n3) < n4) { src = s4; hh = h4; ll = l4; }
    else return;
    float4 v = *(const float4*)(src + i);
    float a[4] = {v.x, v.y, v.z, v.w};
    #pragma unroll
    for (int j = 0; j < 4; j++) { bf16 h, l; split2(a[j], h, l); hh[i + j] = h; ll[i + j] = l; }
}

// ---- fused transpose hi/lo: z<4 -> x slice (512x1024), z==4 -> r_feat (512x128) ----
__global__ void trcvt2x_kernel(const float* __restrict__ x, bf16* __restrict__ xh,
                               bf16* __restrict__ xl, const float* __restrict__ rf,
                               bf16* __restrict__ rfh, bf16* __restrict__ rfl) {
    __shared__ float tile[32][33];
    int z = blockIdx.z;
    const float* in; bf16 *hi, *lo; int R, C;
    if (z < 4) {
        in = x + (long)z * 512 * 1024;
        hi = xh + (long)z * 1024 * 512; lo = xl + (long)z * 1024 * 512;
        R = 512; C = 1024;
    } else {
        if (blockIdx.x >= 4) return;
        in = rf; hi = rfh; lo = rfl;
        R = 512; C = 128;
    }
    int c0 = blockIdx.x * 32, r0 = blockIdx.y * 32;
    int tc = threadIdx.x & 31, tr = threadIdx.x >> 5;
    #pragma unroll
    for (int i = 0; i < 4; i++) {
        int r = tr + i * 8;
        tile[r][tc] = in[(long)(r0 + r) * C + c0 + tc];
    }
    __syncthreads();
    #pragma unroll
    for (int i = 0; i < 4; i++) {
        int r = tr + i * 8;
        bf16 h, l; split2(tile[tc][r], h, l);
        hi[(long)(c0 + r) * R + r0 + tc] = h;
        lo[(long)(c0 + r) * R + r0 + tc] = l;
    }
}

// ---- fused expert-weight transposes: z<8 -> e_w1[z] (512x2048), z>=8 -> e_w2[z-8] (2048x512) ----
__global__ void tr2x_kernel(const float* __restrict__ w1, bf16* __restrict__ e1T,
                            const float* __restrict__ w2, bf16* __restrict__ e2T) {
    __shared__ float tile[32][33];
    int z = blockIdx.z;
    const float* in; bf16* out; int R, C, c0, r0;
    if (z < 8) {
        in = w1 + (long)z * 512 * 2048;  out = e1T + (long)z * 2048 * 512;
        R = 512; C = 2048;
        c0 = blockIdx.x * 32; r0 = blockIdx.y * 32;       // grid x=64, y=16
    } else {
        in = w2 + (long)(z - 8) * 2048 * 512;  out = e2T + (long)(z - 8) * 512 * 2048;
        R = 2048; C = 512;
        int lin = blockIdx.y * 64 + blockIdx.x;           // 0..1023 -> (16 x, 64 y)
        c0 = (lin & 15) * 32; r0 = (lin >> 4) * 32;
    }
    int tc = threadIdx.x & 31, tr = threadIdx.x >> 5;
    #pragma unroll
    for (int i = 0; i < 4; i++) {
        int r = tr + i * 8;
        tile[r][tc] = in[(long)(r0 + r) * C + c0 + tc];
    }
    __syncthreads();
    #pragma unroll
    for (int i = 0; i < 4; i++) {
        int r = tr + i * 8;
        out[(long)(c0 + r) * R + r0 + tc] = __float2bfloat16(tile[tc][r]);
    }
}

// ---- split-precision bf16 MFMA GEMM, 64x64 tile (high machine fill) ----
__global__ __launch_bounds__(256) void mgemm64_kernel(
    const bf16* __restrict__ Ah, const bf16* __restrict__ Al,
    const bf16* __restrict__ Bh, const bf16* __restrict__ Bl,
    const float* __restrict__ bias, const float* __restrict__ resid, float* __restrict__ C,
    bf16* __restrict__ Oh, bf16* __restrict__ Ol,
    int M, int N, int K, long a_bat, long b_bat, long c_bat, int cs_m, int cs_n) {
    __shared__ short AsH[2 * 2048];
    __shared__ short AsL[2 * 2048];
    __shared__ short BsH[2 * 2048];
    __shared__ short BsL[2 * 2048];
    int bat = blockIdx.z;
    const short* AbH = (const short*)(Ah + (long)bat * a_bat);
    const short* AbL = (const short*)(Al + (long)bat * a_bat);
    const short* BbH = (const short*)(Bh + (long)bat * b_bat);
    const short* BbL = (const short*)(Bl + (long)bat * b_bat);
    float* Cb = C + (long)bat * c_bat;
    const float* Rb = resid ? resid + (long)bat * c_bat : nullptr;
    int bm = blockIdx.y * 64, bn = blockIdx.x * 64;
    int t = threadIdx.x, lane = t & 63, w = t >> 6;
    int wm = (w >> 1) * 32, wn = (w & 1) * 32;
    int r0 = t >> 2, k0s = (t & 3) ^ ((r0 >> 1) & 3);
    int ar0 = bm + r0; if (ar0 > M - 1) ar0 = M - 1;
    long aoff = (long)ar0 * K + k0s * 8;
    long boff = (long)(bn + r0) * K + k0s * 8;
    int fr = lane & 15, fq = lane >> 4;
    int aOff[2], bOff[2];
    #pragma unroll
    for (int i = 0; i < 2; i++) {
        int row = wm + i * 16 + fr;
        aOff[i] = row * 32 + ((fq ^ ((row >> 1) & 3)) * 8);
        int col = wn + i * 16 + fr;
        bOff[i] = col * 32 + ((fq ^ ((col >> 1) & 3)) * 8);
    }
    f32x4 acc[2][2] = {};
    bf16x8 vah = *(const bf16x8*)(AbH + aoff);
    bf16x8 val = *(const bf16x8*)(AbL + aoff);
    bf16x8 vbh = *(const bf16x8*)(BbH + boff);
    bf16x8 vbl = *(const bf16x8*)(BbL + boff);
    int bufo = 0;
    for (int kk = 0; kk < K; kk += 32) {
        *(bf16x8*)&AsH[bufo + t * 8] = vah;
        *(bf16x8*)&AsL[bufo + t * 8] = val;
        *(bf16x8*)&BsH[bufo + t * 8] = vbh;
        *(bf16x8*)&BsL[bufo + t * 8] = vbl;
        __syncthreads();
        int kn = (kk + 32 < K) ? kk + 32 : kk;
        bf16x8 nah = *(const bf16x8*)(AbH + aoff + kn);
        bf16x8 nal = *(const bf16x8*)(AbL + aoff + kn);
        bf16x8 nbh = *(const bf16x8*)(BbH + boff + kn);
        bf16x8 nbl = *(const bf16x8*)(BbL + boff + kn);
        bf16x8 aH[2], aL[2], bH[2], bL[2];
        #pragma unroll
        for (int i = 0; i < 2; i++) {
            aH[i] = *(const bf16x8*)&AsH[bufo + aOff[i]];
            aL[i] = *(const bf16x8*)&AsL[bufo + aOff[i]];
            bH[i] = *(const bf16x8*)&BsH[bufo + bOff[i]];
            bL[i] = *(const bf16x8*)&BsL[bufo + bOff[i]];
        }
        #pragma unroll
        for (int i = 0; i < 2; i++)
        #pragma unroll
        for (int j = 0; j < 2; j++) {
            acc[i][j] = __builtin_amdgcn_mfma_f32_16x16x32_bf16(aH[i], bH[j], acc[i][j], 0, 0, 0);
            acc[i][j] = __builtin_amdgcn_mfma_f32_16x16x32_bf16(aH[i], bL[j], acc[i][j], 0, 0, 0);
            acc[i][j] = __builtin_amdgcn_mfma_f32_16x16x32_bf16(aL[i], bH[j], acc[i][j], 0, 0, 0);
        }
        vah = nah; val = nal; vbh = nbh; vbl = nbl;
        bufo ^= 2048;
    }
    #pragma unroll
    for (int i = 0; i < 2; i++)
    #pragma unroll
    for (int j = 0; j < 2; j++)
    #pragma unroll
    for (int r = 0; r < 4; r++) {
        int row = bm + wm + i * 16 + fq * 4 + r;
        int col = bn + wn + j * 16 + fr;
        if (row < M) {
            long off = (long)row * cs_m + (long)col * cs_n;
            float v = acc[i][j][r];
            if (bias) v += bias[col];
            if (Oh) {
                bf16 hh, ll; split2(v, hh, ll);
                Oh[off] = hh; Ol[off] = ll;
            } else {
                if (Rb) v += Rb[off];
                Cb[off] = v;
            }
        }
    }
}

// ---- split-precision bf16 MFMA GEMM, 128x64 tile (high reuse; for the big qkv GEMM) ----
__global__ __launch_bounds__(256) void mgemm128x64_kernel(
    const bf16* __restrict__ Ah, const bf16* __restrict__ Al,
    const bf16* __restrict__ Bh, const bf16* __restrict__ Bl,
    const float* __restrict__ bias, bf16* __restrict__ Oh, bf16* __restrict__ Ol,
    int M, int N, int K) {
    __shared__ short AsH[2 * 4096];
    __shared__ short AsL[2 * 4096];
    __shared__ short BsH[2 * 2048];
    __shared__ short BsL[2 * 2048];
    const short* AbH = (const short*)Ah;
    const short* AbL = (const short*)Al;
    const short* BbH = (const short*)Bh;
    const short* BbL = (const short*)Bl;
    int bm = blockIdx.y * 128, bn = blockIdx.x * 64;
    int t = threadIdx.x, lane = t & 63, w = t >> 6;
    int wm = (w >> 1) * 64, wn = (w & 1) * 32;
    int p0 = t, p1 = t + 256;
    int ra0 = p0 >> 2, ka0 = (p0 & 3) ^ ((ra0 >> 1) & 3);
    int ra1 = p1 >> 2, ka1 = (p1 & 3) ^ ((ra1 >> 1) & 3);
    int arow0 = bm + ra0; if (arow0 > M - 1) arow0 = M - 1;
    int arow1 = bm + ra1; if (arow1 > M - 1) arow1 = M - 1;
    long aoff0 = (long)arow0 * K + ka0 * 8;
    long aoff1 = (long)arow1 * K + ka1 * 8;
    int rb = t >> 2, kb2 = (t & 3) ^ ((rb >> 1) & 3);
    long boff = (long)(bn + rb) * K + kb2 * 8;
    int fr = lane & 15, fq = lane >> 4;
    int aOff[4], bOff[2];
    #pragma unroll
    for (int i = 0; i < 4; i++) {
        int row = wm + i * 16 + fr;
        aOff[i] = row * 32 + ((fq ^ ((row >> 1) & 3)) * 8);
    }
    #pragma unroll
    for (int j = 0; j < 2; j++) {
        int col = wn + j * 16 + fr;
        bOff[j] = col * 32 + ((fq ^ ((col >> 1) & 3)) * 8);
    }
    f32x4 acc[4][2] = {};
    bf16x8 vah0 = *(const bf16x8*)(AbH + aoff0);
    bf16x8 vah1 = *(const bf16x8*)(AbH + aoff1);
    bf16x8 val0 = *(const bf16x8*)(AbL + aoff0);
    bf16x8 val1 = *(const bf16x8*)(AbL + aoff1);
    bf16x8 vbh  = *(const bf16x8*)(BbH + boff);
    bf16x8 vbl  = *(const bf16x8*)(BbL + boff);
    int bufA = 0, bufB = 0;
    for (int kk = 0; kk < K; kk += 32) {
        *(bf16x8*)&AsH[bufA + p0 * 8] = vah0;  *(bf16x8*)&AsH[bufA + p1 * 8] = vah1;
        *(bf16x8*)&AsL[bufA + p0 * 8] = val0;  *(bf16x8*)&AsL[bufA + p1 * 8] = val1;
        *(bf16x8*)&BsH[bufB + t * 8] = vbh;
        *(bf16x8*)&BsL[bufB + t * 8] = vbl;
        __syncthreads();
        int kn = (kk + 32 < K) ? kk + 32 : kk;
        bf16x8 nah0 = *(const bf16x8*)(AbH + aoff0 + kn);
        bf16x8 nah1 = *(const bf16x8*)(AbH + aoff1 + kn);
        bf16x8 nal0 = *(const bf16x8*)(AbL + aoff0 + kn);
        bf16x8 nal1 = *(const bf16x8*)(AbL + aoff1 + kn);
        bf16x8 nbh  = *(const bf16x8*)(BbH + boff + kn);
        bf16x8 nbl  = *(const bf16x8*)(BbL + boff + kn);
        bf16x8 aH[4], aL[4], bH[2], bL[2];
        #pragma unroll
        for (int i = 0; i < 4; i++) {
            aH[i] = *(const bf16x8*)&AsH[bufA + aOff[i]];
            aL[i] = *(const bf16x8*)&AsL[bufA + aOff[i]];
        }
        #pragma unroll
        for (int j = 0; j < 2; j++) {
            bH[j] = *(const bf16x8*)&BsH[bufB + bOff[j]];
            bL[j] = *(const bf16x8*)&BsL[bufB + bOff[j]];
        }
        #pragma unroll
        for (int i = 0; i < 4; i++)
        #pragma unroll
        for (int j = 0; j < 2; j++) {
            acc[i][j] = __builtin_amdgcn_mfma_f32_16x16x32_bf16(aH[i], bH[j], acc[i][j], 0, 0, 0);
            acc[i][j] = __builtin_amdgcn_mfma_f32_16x16x32_bf16(aH[i], bL[j], acc[i][j], 0, 0, 0);
            acc[i][j] = __builtin_amdgcn_mfma_f32_16x16x32_bf16(aL[i], bH[j], acc[i][j], 0, 0, 0);
        }
        vah0 = nah0; vah1 = nah1; val0 = nal0; val1 = nal1;
        vbh = nbh; vbl = nbl;
        bufA ^= 4096; bufB ^= 2048;
    }
    #pragma unroll
    for (int i = 0; i < 4; i++)
    #pragma unroll
    for (int j = 0; j < 2; j++)
    #pragma unroll
    for (int r = 0; r < 4; r++) {
        int row = bm + wm + i * 16 + fq * 4 + r;
        int col = bn + wn + j * 16 + fr;
        if (row < M) {
            long off = (long)row * N + col;
            float v = acc[i][j][r] + bias[col];
            bf16 hh, ll; split2(v, hh, ll);
            Oh[off] = hh; Ol[off] = ll;
        }
    }
}

// ---- split-precision MFMA flash SA: no-max softmax, single-bf16 P, V stride 72 ----
__global__ __launch_bounds__(256) void sa_mfma_kernel(
    const bf16* __restrict__ qh, const bf16* __restrict__ ql,
    bf16* __restrict__ oh, bf16* __restrict__ ol) {
    int qt = blockIdx.x, h = blockIdx.y, b = blockIdx.z;
    __shared__ short KsH[4096], KsL[4096];       // [kv][64], swz: col ^ ((kv&7)<<3)
    __shared__ short VtH[4608], VtL[4608];       // [d][72], swz: col ^ (((d>>3)&7)<<3)
    __shared__ short PHs[4][1024];               // per-wave P (single bf16)
    int t = threadIdx.x, lane = t & 63, w = t >> 6;
    int fr = lane & 15, fq = lane >> 4;
    const short* QH = (const short*)qh;
    const short* QL = (const short*)ql;
    long qrow = (long)(b * 1024 + qt * 64 + w * 16 + fr) * 1536 + h * 64;
    bf16x8 Qh2[2], Ql2[2];
    Qh2[0] = *(const bf16x8*)(QH + qrow + fq * 8);
    Qh2[1] = *(const bf16x8*)(QH + qrow + 32 + fq * 8);
    Ql2[0] = *(const bf16x8*)(QL + qrow + fq * 8);
    Ql2[1] = *(const bf16x8*)(QL + qrow + 32 + fq * 8);
    float l_i[4] = {0.f, 0.f, 0.f, 0.f};
    f32x4 o_acc[4] = {};
    int c0 = t, c1 = t + 256;
    int r0 = c0 >> 3, g0 = c0 & 7;               // r0 in 0..31
    int r1 = c1 >> 3, g1 = c1 & 7;               // r1 in 32..63
    int kd0 = r0 * 64 + ((g0 * 8) ^ ((r0 & 7) << 3));
    int kd1 = r1 * 64 + ((g1 * 8) ^ ((r1 & 7) << 3));
    long kb = (long)(b * 1024) * 1536 + 512 + h * 64;
    long vb = kb + 512;
    long lo0 = (long)r0 * 1536 + g0 * 8, lo1 = (long)r1 * 1536 + g1 * 8;
    short* ph = PHs[w];
    bf16x8 kh0 = *(const bf16x8*)(QH + kb + lo0);
    bf16x8 kh1 = *(const bf16x8*)(QH + kb + lo1);
    bf16x8 kl0 = *(const bf16x8*)(QL + kb + lo0);
    bf16x8 kl1 = *(const bf16x8*)(QL + kb + lo1);
    bf16x8 vh0 = *(const bf16x8*)(QH + vb + lo0);
    bf16x8 vh1 = *(const bf16x8*)(QH + vb + lo1);
    bf16x8 vl0 = *(const bf16x8*)(QL + vb + lo0);
    bf16x8 vl1 = *(const bf16x8*)(QL + vb + lo1);
    for (int kt = 0; kt < 16; kt++) {
        __syncthreads();          // A: all waves finished reading Ks/Vt of prev iter
        *(bf16x8*)&KsH[kd0] = kh0;  *(bf16x8*)&KsH[kd1] = kh1;
        *(bf16x8*)&KsL[kd0] = kl0;  *(bf16x8*)&KsL[kd1] = kl1;
        #pragma unroll
        for (int j = 0; j < 8; j++) {
            int d0 = g0 * 8 + j;
            int i0 = d0 * 72 + (r0 ^ (g0 << 3));
            VtH[i0] = ((short*)&vh0)[j];  VtL[i0] = ((short*)&vl0)[j];
            int d1 = g1 * 8 + j;
            int i1 = d1 * 72 + (r1 ^ (g1 << 3));
            VtH[i1] = ((short*)&vh1)[j];  VtL[i1] = ((short*)&vl1)[j];
        }
        __syncthreads();          // B: staging visible
        int ktn = (kt + 1 < 16) ? kt + 1 : kt;
        long ko = kb + (long)(ktn * 64) * 1536;
        long vo = vb + (long)(ktn * 64) * 1536;
        bf16x8 nkh0 = *(const bf16x8*)(QH + ko + lo0);
        bf16x8 nkh1 = *(const bf16x8*)(QH + ko + lo1);
        bf16x8 nkl0 = *(const bf16x8*)(QL + ko + lo0);
        bf16x8 nkl1 = *(const bf16x8*)(QL + ko + lo1);
        bf16x8 nvh0 = *(const bf16x8*)(QH + vo + lo0);
        bf16x8 nvh1 = *(const bf16x8*)(QH + vo + lo1);
        bf16x8 nvl0 = *(const bf16x8*)(QL + vo + lo0);
        bf16x8 nvl1 = *(const bf16x8*)(QL + vo + lo1);
        __builtin_amdgcn_s_setprio(1);
        f32x4 s[4] = {};
        #pragma unroll
        for (int cf = 0; cf < 4; cf++) {
            int kvrow = cf * 16 + fr;
            #pragma unroll
            for (int kf = 0; kf < 2; kf++) {
                int idx = kvrow * 64 + ((kf * 32 + fq * 8) ^ ((kvrow & 7) << 3));
                bf16x8 Bh2 = *(const bf16x8*)&KsH[idx];
                bf16x8 Bl2 = *(const bf16x8*)&KsL[idx];
                s[cf] = __builtin_amdgcn_mfma_f32_16x16x32_bf16(Qh2[kf], Bh2, s[cf], 0, 0, 0);
                s[cf] = __builtin_amdgcn_mfma_f32_16x16x32_bf16(Qh2[kf], Bl2, s[cf], 0, 0, 0);
                s[cf] = __builtin_amdgcn_mfma_f32_16x16x32_bf16(Ql2[kf], Bh2, s[cf], 0, 0, 0);
            }
        }
        __builtin_amdgcn_s_setprio(0);
        // ---- no-max softmax: P = exp(S/8) rounded to single bf16; l from rounded P ----
        #pragma unroll
        for (int cf = 0; cf < 4; cf++)
        #pragma unroll
        for (int reg = 0; reg < 4; reg++) {
            float e = __expf(s[cf][reg] * 0.125f);
            bf16 eb = __float2bfloat16(e);
            l_i[reg] += __bfloat162float(eb);
            int q = fq * 4 + reg, kv = cf * 16 + fr;
            int idx = q * 64 + (kv ^ ((q & 7) << 3));
            ph[idx] = *(short*)&eb;
        }
        asm volatile("s_waitcnt lgkmcnt(0)" ::: "memory");
        __builtin_amdgcn_sched_barrier(0);
        __builtin_amdgcn_s_setprio(1);
        bf16x8 Pf_h[2];
        #pragma unroll
        for (int kf = 0; kf < 2; kf++) {
            int idx = fr * 64 + ((kf * 32 + fq * 8) ^ ((fr & 7) << 3));
            Pf_h[kf] = *(const bf16x8*)&ph[idx];
        }
        #pragma unroll
        for (int cf = 0; cf < 4; cf++) {
            int d = cf * 16 + fr;
            #pragma unroll
            for (int kf = 0; kf < 2; kf++) {
                int idx = d * 72 + ((kf * 32 + fq * 8) ^ (((d >> 3) & 7) << 3));
                bf16x8 Vh2 = *(const bf16x8*)&VtH[idx];
                bf16x8 Vl2 = *(const bf16x8*)&VtL[idx];
                o_acc[cf] = __builtin_amdgcn_mfma_f32_16x16x32_bf16(Pf_h[kf], Vh2, o_acc[cf], 0, 0, 0);
                o_acc[cf] = __builtin_amdgcn_mfma_f32_16x16x32_bf16(Pf_h[kf], Vl2, o_acc[cf], 0, 0, 0);
            }
        }
        __builtin_amdgcn_s_setprio(0);
        kh0 = nkh0; kh1 = nkh1; kl0 = nkl0; kl1 = nkl1;
        vh0 = nvh0; vh1 = nvh1; vl0 = nvl0; vl1 = nvl1;
    }
    #pragma unroll
    for (int reg = 0; reg < 4; reg++) {
        float rs = l_i[reg];
        rs += __shfl_xor(rs, 1);
        rs += __shfl_xor(rs, 2);
        rs += __shfl_xor(rs, 4);
        rs += __shfl_xor(rs, 8);
        float inv = 1.f / rs;
        long m = (long)(b * 1024 + qt * 64 + w * 16 + fq * 4 + reg);
        #pragma unroll
        for (int cf = 0; cf < 4; cf++) {
            float v = o_acc[cf][reg] * inv;
            bf16 hh, ll; split2(v, hh, ll);
            long off = m * DIMC + h * 64 + cf * 16 + fr;
            oh[off] = hh; ol[off] = ll;
        }
    }
}

// ---- split-precision MFMA cross-attention: 77 keys padded to 96, single-bf16 P ----
__global__ __launch_bounds__(256) void ca_mfma_kernel(
    const bf16* __restrict__ qh, const bf16* __restrict__ ql,
    const bf16* __restrict__ kvh, const bf16* __restrict__ kvl,
    bf16* __restrict__ oh, bf16* __restrict__ ol) {
    int qt = blockIdx.x, h = blockIdx.y, b = blockIdx.z;
    __shared__ short UH[8192], UL[8192];
    __shared__ short PHs[4][2048];
    int t = threadIdx.x, lane = t & 63, w = t >> 6;
    int fr = lane & 15, fq = lane >> 4;
    const short* QH = (const short*)qh;
    const short* QL = (const short*)ql;
    const short* KVH = (const short*)kvh;
    const short* KVL = (const short*)kvl;
    long qrow = (long)(b * 1024 + qt * 64 + w * 16 + fr) * DIMC + h * 64;
    bf16x8 Qh2[2], Ql2[2];
    Qh2[0] = *(const bf16x8*)(QH + qrow + fq * 8);
    Qh2[1] = *(const bf16x8*)(QH + qrow + 32 + fq * 8);
    Ql2[0] = *(const bf16x8*)(QL + qrow + fq * 8);
    Ql2[1] = *(const bf16x8*)(QL + qrow + 32 + fq * 8);
    for (int c = t; c < 768; c += 256) {
        int r = c >> 3, g = c & 7;
        int idx = r * 64 + ((g * 8) ^ ((r & 7) << 3));
        bf16x8 vh = {}, vl = {};
        if (r < 77) {
            long src = (long)(b * 77 + r) * 1024 + h * 64 + g * 8;
            vh = *(const bf16x8*)(KVH + src);
            vl = *(const bf16x8*)(KVL + src);
        }
        *(bf16x8*)&UH[idx] = vh;
        *(bf16x8*)&UL[idx] = vl;
    }
    __syncthreads();
    f32x4 s[5] = {};
    #pragma unroll
    for (int cf = 0; cf < 5; cf++) {
        int kvrow = cf * 16 + fr;
        #pragma unroll
        for (int kf = 0; kf < 2; kf++) {
            int idx = kvrow * 64 + ((kf * 32 + fq * 8) ^ ((kvrow & 7) << 3));
            bf16x8 Bh2 = *(const bf16x8*)&UH[idx];
            bf16x8 Bl2 = *(const bf16x8*)&UL[idx];
            s[cf] = __builtin_amdgcn_mfma_f32_16x16x32_bf16(Qh2[kf], Bh2, s[cf], 0, 0, 0);
            s[cf] = __builtin_amdgcn_mfma_f32_16x16x32_bf16(Qh2[kf], Bl2, s[cf], 0, 0, 0);
            s[cf] = __builtin_amdgcn_mfma_f32_16x16x32_bf16(Ql2[kf], Bh2, s[cf], 0, 0, 0);
        }
    }
    float inv[4];
    #pragma unroll
    for (int reg = 0; reg < 4; reg++) {
        float rs = 0.f;
        #pragma unroll
        for (int cf = 0; cf < 5; cf++) {
            int kv = cf * 16 + fr;
            float e = (kv < 77) ? __expf(s[cf][reg] * 0.125f) : 0.f;
            s[cf][reg] = e;
            rs += e;
        }
        rs += __shfl_xor(rs, 1);
        rs += __shfl_xor(rs, 2);
        rs += __shfl_xor(rs, 4);
        rs += __shfl_xor(rs, 8);
        inv[reg] = 1.f / rs;
    }
    short* ph = PHs[w];
    #pragma unroll
    for (int cf = 0; cf < 6; cf++)
    #pragma unroll
    for (int reg = 0; reg < 4; reg++) {
        int q = fq * 4 + reg, kv = cf * 16 + fr;
        int idx = q * 128 + (kv ^ ((q & 7) << 3));
        float pv = (cf < 5) ? s[cf][reg] * inv[reg] : 0.f;
        bf16 pb = __float2bfloat16(pv);
        ph[idx] = *(short*)&pb;
    }
    __syncthreads();
    for (int c = t; c < 768; c += 256) {
        int r = c >> 3, g = c & 7;
        bf16x8 vh = {}, vl = {};
        if (r < 77) {
            long src = (long)(b * 77 + r) * 1024 + 512 + h * 64 + g * 8;
            vh = *(const bf16x8*)(KVH + src);
            vl = *(const bf16x8*)(KVL + src);
        }
        #pragma unroll
        for (int j = 0; j < 8; j++) {
            int d = g * 8 + j;
            int idx = d * 128 + (r ^ (((d >> 3) & 7) << 3));
            UH[idx] = ((short*)&vh)[j];
            UL[idx] = ((short*)&vl)[j];
        }
    }
    __syncthreads();
    f32x4 o_acc[4] = {};
    bf16x8 Pf_h[3];
    #pragma unroll
    for (int kf = 0; kf < 3; kf++) {
        int idx = fr * 128 + ((kf * 32 + fq * 8) ^ ((fr & 7) << 3));
        Pf_h[kf] = *(const bf16x8*)&ph[idx];
    }
    #pragma unroll
    for (int cf = 0; cf < 4; cf++) {
        int d = cf * 16 + fr;
        #pragma unroll
        for (int kf = 0; kf < 3; kf++) {
            int idx = d * 128 + ((kf * 32 + fq * 8) ^ (((d >> 3) & 7) << 3));
            bf16x8 Vh2 = *(const bf16x8*)&UH[idx];
            bf16x8 Vl2 = *(const bf16x8*)&UL[idx];
            o_acc[cf] = __builtin_amdgcn_mfma_f32_16x16x32_bf16(Pf_h[kf], Vh2, o_acc[cf], 0, 0, 0);
            o_acc[cf] = __builtin_amdgcn_mfma_f32_16x16x32_bf16(Pf_h[kf], Vl2, o_acc[cf], 0, 0, 0);
        }
    }
    #pragma unroll
    for (int reg = 0; reg < 4; reg++) {
        long m = (long)(b * 1024 + qt * 64 + w * 16 + fq * 4 + reg);
        #pragma unroll
        for (int cf = 0; cf < 4; cf++) {
            bf16 hh, ll; split2(o_acc[cf][reg], hh, ll);
            long off = m * DIMC + h * 64 + cf * 16 + fr;
            oh[off] = hh; ol[off] = ll;
        }
    }
}

// ---- MoE grouped MFMA GEMM1, 64x128 tile: hid = gelu(xn·w1 + b1), K=512 ----
__global__ __launch_bounds__(256) void moe128_1_kernel(
    const bf16* __restrict__ xn_b, const bf16* __restrict__ e1T, const float* __restrict__ e_b1,
    const int* __restrict__ table, const int* __restrict__ ntiles, const int* __restrict__ perm,
    bf16* __restrict__ hid_b) {
    if (blockIdx.y >= ntiles[0]) return;
    int e = table[2 * blockIdx.y], row0 = table[2 * blockIdx.y + 1];
    int bn = blockIdx.x * 128;
    __shared__ short As[2 * 2048];
    __shared__ short Bs[2 * 4096];
    __shared__ int rowsS[64];
    int t = threadIdx.x, lane = t & 63, w = t >> 6;
    if (t < 64) rowsS[t] = perm[row0 + t];
    __syncthreads();
    int wm = (w >> 1) * 32, wn = (w & 1) * 64;
    int ra = t >> 2, ka = (t & 3) ^ ((ra >> 1) & 3);
    int tok0 = rowsS[ra]; if (tok0 < 0) tok0 = 0;
    const short* Xs = (const short*)xn_b;
    const short* Ws = (const short*)(e1T + (long)e * HIDC * DIMC);
    const short* a0 = Xs + (long)tok0 * DIMC + ka * 8;
    int p0 = t, p1 = t + 256;
    int rb0 = p0 >> 2, kb0 = (p0 & 3) ^ ((rb0 >> 1) & 3);
    int rb1 = p1 >> 2, kb1 = (p1 & 3) ^ ((rb1 >> 1) & 3);
    const short* b0 = Ws + (long)(bn + rb0) * DIMC + kb0 * 8;
    const short* b1 = Ws + (long)(bn + rb1) * DIMC + kb1 * 8;
    int fr = lane & 15, fq = lane >> 4;
    int aOff[2], bOff[4];
    #pragma unroll
    for (int i = 0; i < 2; i++) {
        int row = wm + i * 16 + fr;
        aOff[i] = row * 32 + ((fq ^ ((row >> 1) & 3)) * 8);
    }
    #pragma unroll
    for (int j = 0; j < 4; j++) {
        int col = wn + j * 16 + fr;
        bOff[j] = col * 32 + ((fq ^ ((col >> 1) & 3)) * 8);
    }
    f32x4 acc[2][4] = {};
    bf16x8 va  = *(const bf16x8*)a0;
    bf16x8 vb0 = *(const bf16x8*)b0;
    bf16x8 vb1 = *(const bf16x8*)b1;
    int bufA = 0, bufB = 0;
    for (int kk = 0; kk < DIMC; kk += 32) {
        *(bf16x8*)&As[bufA + t * 8] = va;
        *(bf16x8*)&Bs[bufB + p0 * 8] = vb0;
        *(bf16x8*)&Bs[bufB + p1 * 8] = vb1;
        __syncthreads();
        int kn = (kk + 32 < DIMC) ? kk + 32 : kk;
        bf16x8 na  = *(const bf16x8*)(a0 + kn);
        bf16x8 nb0 = *(const bf16x8*)(b0 + kn);
        bf16x8 nb1 = *(const bf16x8*)(b1 + kn);
        bf16x8 aF[2], bF[4];
        #pragma unroll
        for (int i = 0; i < 2; i++) aF[i] = *(const bf16x8*)&As[bufA + aOff[i]];
        #pragma unroll
        for (int j = 0; j < 4; j++) bF[j] = *(const bf16x8*)&Bs[bufB + bOff[j]];
        #pragma unroll
        for (int i = 0; i < 2; i++)
        #pragma unroll
        for (int j = 0; j < 4; j++)
            acc[i][j] = __builtin_amdgcn_mfma_f32_16x16x32_bf16(aF[i], bF[j], acc[i][j], 0, 0, 0);
        va = na; vb0 = nb0; vb1 = nb1;
        bufA ^= 2048; bufB ^= 4096;
    }
    const float* bb = e_b1 + (long)e * HIDC;
    #pragma unroll
    for (int i = 0; i < 2; i++)
    #pragma unroll
    for (int r = 0; r < 4; r++) {
        int tok = rowsS[wm + i * 16 + fq * 4 + r];
        if (tok < 0) continue;
        #pragma unroll
        for (int j = 0; j < 4; j++) {
            int col = bn + wn + j * 16 + fr;
            float v = acc[i][j][r] + bb[col];
            v = 0.5f * v * (1.f + erff(v * 0.70710678f));
            hid_b[(long)tok * HIDC + col] = __float2bfloat16(v);
        }
    }
}

// ---- MoE grouped MFMA GEMM2, 64x128 tile: out = resid + hid·w2 + b2 -> split bf16 ----
__global__ __launch_bounds__(256) void moe128_2_kernel(
    const bf16* __restrict__ hid_b, const bf16* __restrict__ e2T, const float* __restrict__ e_b2,
    const int* __restrict__ table, const int* __restrict__ ntiles, const int* __restrict__ perm,
    const float* __restrict__ resid, bf16* __restrict__ outh, bf16* __restrict__ outl) {
    if (blockIdx.y >= ntiles[0]) return;
    int e = table[2 * blockIdx.y], row0 = table[2 * blockIdx.y + 1];
    int bn = blockIdx.x * 128;
    __shared__ short As[2 * 2048];
    __shared__ short Bs[2 * 4096];
    __shared__ int rowsS[64];
    int t = threadIdx.x, lane = t & 63, w = t >> 6;
    if (t < 64) rowsS[t] = perm[row0 + t];
    __syncthreads();
    int wm = (w >> 1) * 32, wn = (w & 1) * 64;
    int ra = t >> 2, ka = (t & 3) ^ ((ra >> 1) & 3);
    int tok0 = rowsS[ra]; if (tok0 < 0) tok0 = 0;
    const short* Hs = (const short*)hid_b;
    const short* Ws = (const short*)(e2T + (long)e * DIMC * HIDC);
    const short* a0 = Hs + (long)tok0 * HIDC + ka * 8;
    int p0 = t, p1 = t + 256;
    int rb0 = p0 >> 2, kb0 = (p0 & 3) ^ ((rb0 >> 1) & 3);
    int rb1 = p1 >> 2, kb1 = (p1 & 3) ^ ((rb1 >> 1) & 3);
    const short* b0 = Ws + (long)(bn + rb0) * HIDC + kb0 * 8;
    const short* b1 = Ws + (long)(bn + rb1) * HIDC + kb1 * 8;
    int fr = lane & 15, fq = lane >> 4;
    int aOff[2], bOff[4];
    #pragma unroll
    for (int i = 0; i < 2; i++) {
        int row = wm + i * 16 + fr;
        aOff[i] = row * 32 + ((fq ^ ((row >> 1) & 3)) * 8);
    }
    #pragma unroll
    for (int j = 0; j < 4; j++) {
        int col = wn + j * 16 + fr;
        bOff[j] = col * 32 + ((fq ^ ((col >> 1) & 3)) * 8);
    }
    f32x4 acc[2][4] = {};
    bf16x8 va  = *(const bf16x8*)a0;
    bf16x8 vb0 = *(const bf16x8*)b0;
    bf16x8 vb1 = *(const bf16x8*)b1;
    int bufA = 0, bufB = 0;
    for (int kk = 0; kk < HIDC; kk += 32) {
        *(bf16x8*)&As[bufA + t * 8] = va;
        *(bf16x8*)&Bs[bufB + p0 * 8] = vb0;
        *(bf16x8*)&Bs[bufB + p1 * 8] = vb1;
        __syncthreads();
        int kn = (kk + 32 < HIDC) ? kk + 32 : kk;
        bf16x8 na  = *(const bf16x8*)(a0 + kn);
        bf16x8 nb0 = *(const bf16x8*)(b0 + kn);
        bf16x8 nb1 = *(const bf16x8*)(b1 + kn);
        bf16x8 aF[2], bF[4];
        #pragma unroll
        for (int i = 0; i < 2; i++) aF[i] = *(const bf16x8*)&As[bufA + aOff[i]];
        #pragma unroll
        for (int j = 0; j < 4; j++) bF[j] = *(const bf16x8*)&Bs[bufB + bOff[j]];
        #pragma unroll
        for (int i = 0; i < 2; i++)
        #pragma unroll
        for (int j = 0; j < 4; j++)
            acc[i][j] = __builtin_amdgcn_mfma_f32_16x16x32_bf16(aF[i], bF[j], acc[i][j], 0, 0, 0);
        va = na; vb0 = nb0; vb1 = nb1;
        bufA ^= 2048; bufB ^= 4096;
    }
    const float* bb = e_b2 + (long)e * DIMC;
    #pragma unroll
    for (int i = 0; i < 2; i++)
    #pragma unroll
    for (int r = 0; r < 4; r++) {
        int tok = rowsS[wm + i * 16 + fq * 4 + r];
        if (tok < 0) continue;
        #pragma unroll
        for (int j = 0; j < 4; j++) {
            int col = bn + wn + j * 16 + fr;
            long off = (long)tok * DIMC + col;
            float v = resid[off] + acc[i][j][r] + bb[col];
            bf16 hh, ll; split2(v, hh, ll);
            outh[off] = hh; outl[off] = ll;
        }
    }
}

// ---------------- LayerNorm: optional fp32 + bf16 hi/lo outputs ----------------
__global__ void ln_kernel(const float* __restrict__ x, const float* __restrict__ g,
                          const float* __restrict__ b, float* __restrict__ y,
                          bf16* __restrict__ yh, bf16* __restrict__ yl) {
    int tok = blockIdx.x;
    int t = threadIdx.x;
    const float* xr = x + (long)tok * DIMC;
    float v0 = xr[t], v1 = xr[t + 256];
    __shared__ float red[256];
    red[t] = v0 + v1; __syncthreads();
    for (int s = 128; s > 0; s >>= 1) { if (t < s) red[t] += red[t + s]; __syncthreads(); }
    float mu = red[0] * (1.f / DIMC);
    __syncthreads();
    float d0 = v0 - mu, d1 = v1 - mu;
    red[t] = d0 * d0 + d1 * d1; __syncthreads();
    for (int s = 128; s > 0; s >>= 1) { if (t < s) red[t] += red[t + s]; __syncthreads(); }
    float rs = rsqrtf(red[0] * (1.f / DIMC) + 1e-5f);
    float o0 = d0 * rs * g[t] + b[t];
    float o1 = d1 * rs * g[t + 256] + b[t + 256];
    if (y) { y[(long)tok * DIMC + t] = o0; y[(long)tok * DIMC + t + 256] = o1; }
    bf16 h, l;
    split2(o0, h, l); yh[(long)tok * DIMC + t] = h;       yl[(long)tok * DIMC + t] = l;
    split2(o1, h, l); yh[(long)tok * DIMC + t + 256] = h; yl[(long)tok * DIMC + t + 256] = l;
}

// ---------------- router text part (+ cnt zeroing), latency-optimized ----------------
__global__ void textpart_kernel(const float* __restrict__ w, const float* __restrict__ r_text_mu,
                                const float* __restrict__ r_comb_mu, float* __restrict__ tp,
                                int* __restrict__ cnt) {
    __shared__ float ws[4][512];
    __shared__ float tw[4][128];
    int t = threadIdx.x;
    if (t < NE) cnt[t] = 0;
    for (int i = t; i < 2048; i += 256) ws[i >> 9][i & 511] = w[i];
    __syncthreads();
    for (int j = 0; j < 2; j++) {
        int idx = t + j * 256; int b = idx >> 7, c = idx & 127;
        float s = 0.f;
        #pragma unroll 8
        for (int k = 0; k < 512; k++) s += ws[b][k] * r_text_mu[(long)k * 128 + c];
        tw[b][c] = s;
    }
    __syncthreads();
    if (t < 32) {
        int b = t >> 3, e = t & 7;
        float s = 0.f;
        #pragma unroll 8
        for (int c = 0; c < 128; c++) s += tw[b][c] * r_comb_mu[(long)(128 + c) * 8 + e];
        tp[t] = s;
    }
}

// ---------------- router: perm poison + logits + argmax (latency-optimized) ----------------
// r_comb[0:128] staged in LDS; feat read as 32 unrolled float4 (high MLP).
// FP accumulation order per expert preserved exactly (c ascending) vs reference kernel.
__global__ void route_kernel(const float* __restrict__ feat, const float* __restrict__ tp,
                             const float* __restrict__ r_comb_mu, const float* __restrict__ r_temp,
                             float* __restrict__ onehot, int* __restrict__ idx, int* __restrict__ cnt,
                             int* __restrict__ perm) {
    __shared__ float rc[128][8];
    int t = threadIdx.x;
    for (int i = t; i < 1024; i += 256) rc[i >> 3][i & 7] = r_comb_mu[i];
    __syncthreads();
    int n = blockIdx.x * blockDim.x + t;
    if (n < MAXT * 64) perm[n] = -1;
    if (n >= NTOK) return;
    int b = n >> 10;
    float tmp = fmaxf(r_temp[0], 0.1f);
    float invt = 1.f / tmp;
    const float4* fr4 = (const float4*)(feat + (long)n * 128);
    float lg[8];
    #pragma unroll
    for (int e = 0; e < 8; e++) lg[e] = 0.f;
    #pragma unroll
    for (int c4 = 0; c4 < 32; c4++) {
        float4 f = fr4[c4];
        float fa[4] = {f.x, f.y, f.z, f.w};
        #pragma unroll
        for (int q = 0; q < 4; q++) {
            int c = c4 * 4 + q;
            #pragma unroll
            for (int e = 0; e < 8; e++) lg[e] += fa[q] * rc[c][e];
        }
    }
    #pragma unroll
    for (int e = 0; e < 8; e++) lg[e] = (lg[e] + tp[b * 8 + e]) * invt;
    float best = lg[0]; int bi = 0;
    #pragma unroll
    for (int e = 1; e < 8; e++) { if (lg[e] > best) { best = lg[e]; bi = e; } }
    #pragma unroll
    for (int e = 0; e < 8; e++) onehot[(long)n * 8 + e] = (e == bi) ? 1.f : 0.f;
    idx[n] = bi;
    atomicAdd(&cnt[bi], 1);
}

// ---------------- offsets + scatter fused (single block, LDS cursors) ----------------
__global__ void offscatter_kernel(const int* __restrict__ cnt, const int* __restrict__ idx,
                                  int* __restrict__ ntiles, int* __restrict__ table,
                                  int* __restrict__ perm) {
    __shared__ int cur[NE];
    int t = threadIdx.x;
    if (t == 0) {
        int po = 0, nt = 0;
        for (int e = 0; e < NE; e++) {
            cur[e] = po;
            int tiles = (cnt[e] + 63) >> 6;
            for (int j = 0; j < tiles; j++) { table[2 * nt] = e; table[2 * nt + 1] = po + j * 64; nt++; }
            po += tiles * 64;
        }
        ntiles[0] = nt;
    }
    __syncthreads();
    for (int n = t; n < NTOK; n += 256) {
        int e = idx[n];
        int pos = atomicAdd(&cur[e], 1);
        perm[pos] = n;
    }
}

extern "C" void kernel_launch(void* const* d_in, const int* in_sizes, int n_in,
                              void* d_out, int out_size, void* d_ws, size_t ws_size,
                              hipStream_t stream) {
    const float* x        = (const float*)d_in[0];
    const float* w        = (const float*)d_in[1];
    const float* text     = (const float*)d_in[2];
    const float* pin_w    = (const float*)d_in[3];
    const float* pin_mw   = (const float*)d_in[4];
    const float* pin_mb   = (const float*)d_in[5];
    const float* pout_w   = (const float*)d_in[6];
    const float* pout_mw  = (const float*)d_in[7];
    const float* pout_mb  = (const float*)d_in[8];
    const float* ln1g     = (const float*)d_in[9];
    const float* ln1b     = (const float*)d_in[10];
    const float* ln2g     = (const float*)d_in[11];
    const float* ln2b     = (const float*)d_in[12];
    const float* ln3g     = (const float*)d_in[13];
    const float* ln3b     = (const float*)d_in[14];
    const float* sa_in_w  = (const float*)d_in[15];
    const float* sa_in_b  = (const float*)d_in[16];
    const float* sa_out_w = (const float*)d_in[17];
    const float* sa_out_b = (const float*)d_in[18];
    const float* ca_in_w  = (const float*)d_in[19];
    const float* ca_in_b  = (const float*)d_in[20];
    const float* ca_out_w = (const float*)d_in[21];
    const float* ca_out_b = (const float*)d_in[22];
    const float* r_feat   = (const float*)d_in[23];
    const float* r_text   = (const float*)d_in[24];
    const float* r_comb   = (const float*)d_in[25];
    const float* r_temp   = (const float*)d_in[26];
    const float* e_w1     = (const float*)d_in[27];
    const float* e_b1     = (const float*)d_in[28];
    const float* e_w2     = (const float*)d_in[29];
    const float* e_b2     = (const float*)d_in[30];

    float* out    = (float*)d_out;               // [B, DIM, H, W]
    float* onehot = out + (long)BB * DIMC * HWX; // [4096, 8]

    // ---------------- workspace: fp32 pool ----------------
    float* f32p = (float*)d_ws;
    float* style_in  = f32p;                 // 2048
    float* style_out = f32p + 2048;          // 2048
    float* tp        = f32p + 4096;          // 32
    int*   idx       = (int*)(f32p + 4128);  // 4096
    int*   cnt       = (int*)(f32p + 8224);  // 8
    int*   ntiles    = (int*)(f32p + 8240);  // 8
    int*   table     = (int*)(f32p + 8248);  // 256
    int*   perm      = (int*)(f32p + 8504);  // 4608 -> ends 13112
    float* x_flat    = f32p + 13496;         // 2097152
    float* xn        = x_flat + 2097152;     // 2097152 (home of wtC split)
    float* qkv       = xn + 2097152;         // 6291456 (SA q split / CA q split home)
    float* spill     = qkv + 6291456;        // 2097152 (e2T tail)

    // ---------------- bf16 pool (phase-aliased) ----------------
    bf16* bp = (bf16*)(f32p + 12596408);
    bf16* R1 = bp;                           // 6291456 elems, phases
    bf16* xT_h  = R1;
    bf16* xT_l  = R1 + 2097152;
    bf16* wtA_h = R1 + 4194304;
    bf16* wtA_l = R1 + 5242880;
    bf16* obuf_h = R1;
    bf16* obuf_l = R1 + 2097152;
    bf16* kvt_h  = R1 + 4194304;                       // [308][1024] split
    bf16* kvt_l  = kvt_h + 315392;
    float* feat  = (float*)(kvt_l + 315392);           // 524288 fp32
    bf16* xn_h = R1 + 6291456;               // 2097152
    bf16* xn_l = xn_h + 2097152;             // 2097152
    bf16* WB   = xn_l + 2097152;             // 8388608: weights (early) / hid_b (late)
    bf16* text_h   = WB;
    bf16* text_l   = text_h + 157696;
    bf16* sawin_h  = text_l + 157696;
    bf16* sawin_l  = sawin_h + 786432;
    bf16* sawout_h = sawin_l + 786432;
    bf16* sawout_l = sawout_h + 262144;
    bf16* caw_h    = sawout_l + 262144;
    bf16* caw_l    = caw_h + 786432;
    bf16* cawout_h = caw_l + 786432;
    bf16* cawout_l = cawout_h + 262144;
    bf16* rfT_h    = cawout_l + 262144;      // [128][512] split r_feat^T
    bf16* rfT_l    = rfT_h + 65536;
    bf16* hid_b    = WB;                     // overlays weights after ca_out
    bf16* e1T = (bf16*)qkv;                  // [8][2048][512] in qkv+spill
    bf16* e2T = e1T + 8388608;
    bf16* xfl_h = xn_h;                      // moe128_2 writes split output here
    bf16* xfl_l = xn_l;
    bf16* wtC_h = (bf16*)xn;                 // modconv-out weight (dead fp32 region)
    bf16* wtC_l = wtC_h + 1048576;
    bf16* q_h = (bf16*)qkv;                  // [4096][1536]
    bf16* q_l = q_h + 6291456;
    bf16* ca_qh = (bf16*)qkv;                // [4096][512]
    bf16* ca_ql = ca_qh + 2097152;
    (void)ws_size; (void)spill;

    auto mg = [&](const bf16* Ah, const bf16* Al, const bf16* Bh, const bf16* Bl,
                  const float* bias, const float* resid, float* C, bf16* Oh, bf16* Ol,
                  int M, int N, int K, long ab, long bb, long cb, int csm, int csn, int nb) {
        dim3 g(N / 64, (M + 63) / 64, nb);
        hipLaunchKernelGGL(mgemm64_kernel, g, dim3(256), 0, stream,
                           Ah, Al, Bh, Bl, bias, resid, C, Oh, Ol, M, N, K, ab, bb, cb, csm, csn);
    };

    // ---- fused input conversions (hi/lo): one launch for all 5 flat arrays ----
    {
        int n0 = 1536 * 512, n1 = 512 * 512, n2 = 1536 * 512, n3 = 512 * 512, n4 = BB * TXT * 512;
        int total = n0 + n1 + n2 + n3 + n4;
        hipLaunchKernelGGL(cvtall_kernel, dim3((total / 4 + 255) / 256), dim3(256), 0, stream,
                           sa_in_w, sawin_h, sawin_l, n0,
                           sa_out_w, sawout_h, sawout_l, n1,
                           ca_in_w, caw_h, caw_l, n2,
                           ca_out_w, cawout_h, cawout_l, n3,
                           text, text_h, text_l, n4);
    }
    // ---- fused transposes: x (z<4) + r_feat (z==4) ----
    hipLaunchKernelGGL(trcvt2x_kernel, dim3(32, 16, 5), dim3(256), 0, stream,
                       x, xT_h, xT_l, r_feat, rfT_h, rfT_l);

    // ---- both modconv styles + weights up front (wtC in dead xn region) ----
    hipLaunchKernelGGL(style2_kernel, dim3(16), dim3(256), 0, stream,
                       w, pin_mw, pin_mb, pout_mw, pout_mb, style_in, style_out);
    hipLaunchKernelGGL(wtmod2_kernel, dim3(2 * BB * DIMC), dim3(256), 0, stream,
                       pin_w, style_in, pout_w, style_out, wtA_h, wtA_l, wtC_h, wtC_l);

    // ---- modconv in ----
    mg(xT_h, xT_l, wtA_h, wtA_l, nullptr, nullptr, x_flat, nullptr, nullptr,
       HWX, DIMC, DIMC, (long)HWX * DIMC, (long)DIMC * DIMC, (long)HWX * DIMC, DIMC, 1, BB);

    // ---- LN1 + self-attention (split MFMA) ----
    hipLaunchKernelGGL(ln_kernel, dim3(NTOK), dim3(256), 0, stream, x_flat, ln1g, ln1b,
                       (float*)nullptr, xn_h, xn_l);
    // qkv projection via high-reuse 128x64 kernel
    hipLaunchKernelGGL(mgemm128x64_kernel, dim3(1536 / 64, NTOK / 128), dim3(256), 0, stream,
                       xn_h, xn_l, sawin_h, sawin_l, sa_in_b, q_h, q_l, NTOK, 1536, 512);
    hipLaunchKernelGGL(sa_mfma_kernel, dim3(16, HEADS, BB), dim3(256), 0, stream,
                       q_h, q_l, obuf_h, obuf_l);
    mg(obuf_h, obuf_l, sawout_h, sawout_l, sa_out_b, x_flat, x_flat, nullptr, nullptr,
       NTOK, 512, 512, 0, 0, 0, 512, 1, 1);

    // ---- LN2 + cross-attention (split MFMA) ----
    hipLaunchKernelGGL(ln_kernel, dim3(NTOK), dim3(256), 0, stream, x_flat, ln2g, ln2b,
                       (float*)nullptr, xn_h, xn_l);
    mg(xn_h, xn_l, caw_h, caw_l, ca_in_b, nullptr, nullptr, ca_qh, ca_ql,
       NTOK, 512, 512, 0, 0, 0, 512, 1, 1);
    mg(text_h, text_l, caw_h + 512 * 512, caw_l + 512 * 512, ca_in_b + 512, nullptr, nullptr,
       kvt_h, kvt_l, BB * TXT, 1024, 512, 0, 0, 0, 1024, 1, 1);
    hipLaunchKernelGGL(ca_mfma_kernel, dim3(16, HEADS, BB), dim3(256), 0, stream,
                       ca_qh, ca_ql, kvt_h, kvt_l, obuf_h, obuf_l);
    // expert weight transposes (qkv region dead after ca_mfma) — one fused launch
    hipLaunchKernelGGL(tr2x_kernel, dim3(64, 16, 16), dim3(256), 0, stream,
                       e_w1, e1T, e_w2, e2T);
    mg(obuf_h, obuf_l, cawout_h, cawout_l, ca_out_b, x_flat, x_flat, nullptr, nullptr,
       NTOK, 512, 512, 0, 0, 0, 512, 1, 1);

    // ---- LN3 + router (feat via split MFMA) ----
    hipLaunchKernelGGL(ln_kernel, dim3(NTOK), dim3(256), 0, stream, x_flat, ln3g, ln3b,
                       (float*)nullptr, xn_h, xn_l);
    mg(xn_h, xn_l, rfT_h, rfT_l, nullptr, nullptr, feat, nullptr, nullptr,
       NTOK, 128, 512, 0, 0, 0, 128, 1, 1);
    hipLaunchKernelGGL(textpart_kernel, dim3(1), dim3(256), 0, stream, w, r_text, r_comb, tp, cnt);
    hipLaunchKernelGGL(route_kernel, dim3(18), dim3(256), 0, stream,
                       feat, tp, r_comb, r_temp, onehot, idx, cnt, perm);
    hipLaunchKernelGGL(offscatter_kernel, dim3(1), dim3(256), 0, stream,
                       cnt, idx, ntiles, table, perm);

    // ---- MoE grouped MFMA GEMMs (64x128 tiles; gemm2 emits split bf16 directly) ----
    hipLaunchKernelGGL(moe128_1_kernel, dim3(HIDC / 128, MAXT), dim3(256), 0, stream,
                       xn_h, e1T, e_b1, table, ntiles, perm, hid_b);
    hipLaunchKernelGGL(moe128_2_kernel, dim3(DIMC / 128, MAXT), dim3(256), 0, stream,
                       hid_b, e2T, e_b2, table, ntiles, perm, x_flat, xfl_h, xfl_l);

    // ---- modconv out (weights already prepared) ----
    mg(wtC_h, wtC_l, xfl_h, xfl_l, nullptr, nullptr, out, nullptr, nullptr,
       DIMC, HWX, DIMC, (long)DIMC * DIMC, (long)HWX * DIMC, (long)DIMC * HWX, HWX, 1, BB);
}

// Round 21
// 462.625 us; speedup vs baseline: 1.5568x; 1.0193x over previous
//
#include <hip/hip_runtime.h>
#include <hip/hip_bf16.h>
#include <math.h>

#define DIMC 512
#define HEADS 8
#define HD 64
#define BB 4
#define HWX 1024
#define TXT 77
#define LATC 512
#define NE 8
#define HIDC 2048
#define NTOK 4096
#define MAXT 72           // MoE tiles of 64: 4096/64 + 8

typedef __attribute__((ext_vector_type(8))) short bf16x8;
typedef __attribute__((ext_vector_type(4))) float f32x4;
typedef __hip_bfloat16 bf16;

__device__ __forceinline__ void split2(float v, bf16& h, bf16& l) {
    h = __float2bfloat16(v);
    l = __float2bfloat16(v - __bfloat162float(h));
}
__device__ __forceinline__ void split2s(float v, short& h, short& l) {
    bf16 hb, lb; split2(v, hb, lb);
    h = *(short*)&hb; l = *(short*)&lb;
}

// ---------------- both styles in one launch: job 0 = in, job 1 = out ----------------
__global__ void style2_kernel(const float* __restrict__ w,
                              const float* __restrict__ mwA, const float* __restrict__ mbA,
                              const float* __restrict__ mwB, const float* __restrict__ mbB,
                              float* __restrict__ sA, float* __restrict__ sB) {
    int g = blockIdx.x * blockDim.x + threadIdx.x;
    int job = (g >= BB * DIMC) ? 1 : 0;
    int t = g - job * BB * DIMC;
    if (t >= BB * DIMC) return;
    const float* mw = job ? mwB : mwA;
    const float* mb = job ? mbB : mbA;
    float* st = job ? sB : sA;
    int b = t / DIMC, i = t % DIMC;
    const float* wr = w + (long)b * LATC;
    const float* mr = mw + (long)i * LATC;
    float s = 0.f;
    #pragma unroll 8
    for (int l = 0; l < LATC; l++) s += wr[l] * mr[l];
    st[t] = s + mb[i];
}

// ------- both wtmods in one launch -------
__global__ void wtmod2_kernel(const float* __restrict__ wA, const float* __restrict__ sA,
                              const float* __restrict__ wB, const float* __restrict__ sB,
                              bf16* __restrict__ whA, bf16* __restrict__ wlA,
                              bf16* __restrict__ whB, bf16* __restrict__ wlB) {
    int gb = blockIdx.x;
    int job = (gb >= BB * DIMC) ? 1 : 0;
    int bo = gb - job * BB * DIMC;
    const float* weight = job ? wB : wA;
    const float* style  = job ? sB : sA;
    bf16* wh = job ? whB : whA;
    bf16* wl = job ? wlB : wlA;
    int b = bo / DIMC, o = bo % DIMC;
    const float* wr = weight + (long)o * DIMC;
    const float* sr = style + (long)b * DIMC;
    int t = threadIdx.x;
    float vals[2]; float part = 0.f;
    for (int j = 0; j < 2; j++) {
        int i = t + j * 256;
        float v = wr[i] * sr[i];
        vals[j] = v; part += v * v;
    }
    __shared__ float red[256];
    red[t] = part; __syncthreads();
    for (int s = 128; s > 0; s >>= 1) { if (t < s) red[t] += red[t + s]; __syncthreads(); }
    float d = rsqrtf(red[0] + 1e-8f);
    for (int j = 0; j < 2; j++) {
        int i = t + j * 256;
        bf16 h, l; split2(vals[j] * d, h, l);
        wh[(long)bo * DIMC + i] = h; wl[(long)bo * DIMC + i] = l;
    }
}

// ---------------- fused segmented fp32 -> bf16 hi/lo convert (5 weight arrays) ----------------
__global__ void cvtall_kernel(
    const float* __restrict__ s0, bf16* __restrict__ h0, bf16* __restrict__ l0, int n0,
    const float* __restrict__ s1, bf16* __restrict__ h1, bf16* __restrict__ l1, int n1,
    const float* __restrict__ s2, bf16* __restrict__ h2, bf16* __restrict__ l2, int n2,
    const float* __restrict__ s3, bf16* __restrict__ h3, bf16* __restrict__ l3, int n3,
    const float* __restrict__ s4, bf16* __restrict__ h4, bf16* __restrict__ l4, int n4) {
    int i = (blockIdx.x * blockDim.x + threadIdx.x) * 4;
    const float* src; bf16 *hh, *ll;
    if (i < n0) { src = s0; hh = h0; ll = l0; }
    else if ((i -= n0) < n1) { src = s1; hh = h1; ll = l1; }
    else if ((i -= n1) < n2) { src = s2; hh = h2; ll = l2; }
    else if ((i -= n2) < n3) { src = s3; hh = h3; ll = l3; }
    else if ((i -= n3) < n4) { src = s4; hh = h4; ll = l4; }
    else return;
    float4 v = *(const float4*)(src + i);
    float a[4] = {v.x, v.y, v.z, v.w};
    #pragma unroll
    for (int j = 0; j < 4; j++) { bf16 h, l; split2(a[j], h, l); hh[i + j] = h; ll[i + j] = l; }
}

// ---- fused transpose hi/lo: z<4 -> x slice (512x1024), z==4 -> r_feat (512x128) ----
__global__ void trcvt2x_kernel(const float* __restrict__ x, bf16* __restrict__ xh,
                               bf16* __restrict__ xl, const float* __restrict__ rf,
                               bf16* __restrict__ rfh, bf16* __restrict__ rfl) {
    __shared__ float tile[32][33];
    int z = blockIdx.z;
    const float* in; bf16 *hi, *lo; int R, C;
    if (z < 4) {
        in = x + (long)z * 512 * 1024;
        hi = xh + (long)z * 1024 * 512; lo = xl + (long)z * 1024 * 512;
        R = 512; C = 1024;
    } else {
        if (blockIdx.x >= 4) return;
        in = rf; hi = rfh; lo = rfl;
        R = 512; C = 128;
    }
    int c0 = blockIdx.x * 32, r0 = blockIdx.y * 32;
    int tc = threadIdx.x & 31, tr = threadIdx.x >> 5;
    #pragma unroll
    for (int i = 0; i < 4; i++) {
        int r = tr + i * 8;
        tile[r][tc] = in[(long)(r0 + r) * C + c0 + tc];
    }
    __syncthreads();
    #pragma unroll
    for (int i = 0; i < 4; i++) {
        int r = tr + i * 8;
        bf16 h, l; split2(tile[tc][r], h, l);
        hi[(long)(c0 + r) * R + r0 + tc] = h;
        lo[(long)(c0 + r) * R + r0 + tc] = l;
    }
}

// ---- fused expert-weight transposes: z<8 -> e_w1[z] (512x2048), z>=8 -> e_w2[z-8] (2048x512) ----
__global__ void tr2x_kernel(const float* __restrict__ w1, bf16* __restrict__ e1T,
                            const float* __restrict__ w2, bf16* __restrict__ e2T) {
    __shared__ float tile[32][33];
    int z = blockIdx.z;
    const float* in; bf16* out; int R, C, c0, r0;
    if (z < 8) {
        in = w1 + (long)z * 512 * 2048;  out = e1T + (long)z * 2048 * 512;
        R = 512; C = 2048;
        c0 = blockIdx.x * 32; r0 = blockIdx.y * 32;       // grid x=64, y=16
    } else {
        in = w2 + (long)(z - 8) * 2048 * 512;  out = e2T + (long)(z - 8) * 512 * 2048;
        R = 2048; C = 512;
        int lin = blockIdx.y * 64 + blockIdx.x;           // 0..1023 -> (16 x, 64 y)
        c0 = (lin & 15) * 32; r0 = (lin >> 4) * 32;
    }
    int tc = threadIdx.x & 31, tr = threadIdx.x >> 5;
    #pragma unroll
    for (int i = 0; i < 4; i++) {
        int r = tr + i * 8;
        tile[r][tc] = in[(long)(r0 + r) * C + c0 + tc];
    }
    __syncthreads();
    #pragma unroll
    for (int i = 0; i < 4; i++) {
        int r = tr + i * 8;
        out[(long)(c0 + r) * R + r0 + tc] = __float2bfloat16(tile[tc][r]);
    }
}

// ---- split-precision bf16 MFMA GEMM, 64x64 tile, depth-2 prefetch (K % 64 == 0) ----
__global__ __launch_bounds__(256) void mgemm64_kernel(
    const bf16* __restrict__ Ah, const bf16* __restrict__ Al,
    const bf16* __restrict__ Bh, const bf16* __restrict__ Bl,
    const float* __restrict__ bias, const float* __restrict__ resid, float* __restrict__ C,
    bf16* __restrict__ Oh, bf16* __restrict__ Ol,
    int M, int N, int K, long a_bat, long b_bat, long c_bat, int cs_m, int cs_n) {
    __shared__ short AsH[2 * 2048];
    __shared__ short AsL[2 * 2048];
    __shared__ short BsH[2 * 2048];
    __shared__ short BsL[2 * 2048];
    int bat = blockIdx.z;
    const short* AbH = (const short*)(Ah + (long)bat * a_bat);
    const short* AbL = (const short*)(Al + (long)bat * a_bat);
    const short* BbH = (const short*)(Bh + (long)bat * b_bat);
    const short* BbL = (const short*)(Bl + (long)bat * b_bat);
    float* Cb = C + (long)bat * c_bat;
    const float* Rb = resid ? resid + (long)bat * c_bat : nullptr;
    int bm = blockIdx.y * 64, bn = blockIdx.x * 64;
    int t = threadIdx.x, lane = t & 63, w = t >> 6;
    int wm = (w >> 1) * 32, wn = (w & 1) * 32;
    int r0 = t >> 2, k0s = (t & 3) ^ ((r0 >> 1) & 3);
    int ar0 = bm + r0; if (ar0 > M - 1) ar0 = M - 1;
    long aoff = (long)ar0 * K + k0s * 8;
    long boff = (long)(bn + r0) * K + k0s * 8;
    int fr = lane & 15, fq = lane >> 4;
    int aOff[2], bOff[2];
    #pragma unroll
    for (int i = 0; i < 2; i++) {
        int row = wm + i * 16 + fr;
        aOff[i] = row * 32 + ((fq ^ ((row >> 1) & 3)) * 8);
        int col = wn + i * 16 + fr;
        bOff[i] = col * 32 + ((fq ^ ((col >> 1) & 3)) * 8);
    }
    f32x4 acc[2][2] = {};
    bf16x8 vah0 = *(const bf16x8*)(AbH + aoff);
    bf16x8 val0 = *(const bf16x8*)(AbL + aoff);
    bf16x8 vbh0 = *(const bf16x8*)(BbH + boff);
    bf16x8 vbl0 = *(const bf16x8*)(BbL + boff);
    bf16x8 vah1 = *(const bf16x8*)(AbH + aoff + 32);
    bf16x8 val1 = *(const bf16x8*)(AbL + aoff + 32);
    bf16x8 vbh1 = *(const bf16x8*)(BbH + boff + 32);
    bf16x8 vbl1 = *(const bf16x8*)(BbL + boff + 32);
    for (int kk = 0; kk < K; kk += 64) {
        // ---- step 0: buffer 0, tile kk ----
        *(bf16x8*)&AsH[t * 8] = vah0;
        *(bf16x8*)&AsL[t * 8] = val0;
        *(bf16x8*)&BsH[t * 8] = vbh0;
        *(bf16x8*)&BsL[t * 8] = vbl0;
        __syncthreads();
        {
            int kn = (kk + 64 < K) ? kk + 64 : kk;
            vah0 = *(const bf16x8*)(AbH + aoff + kn);
            val0 = *(const bf16x8*)(AbL + aoff + kn);
            vbh0 = *(const bf16x8*)(BbH + boff + kn);
            vbl0 = *(const bf16x8*)(BbL + boff + kn);
        }
        {
            bf16x8 aH[2], aL[2], bH[2], bL[2];
            #pragma unroll
            for (int i = 0; i < 2; i++) {
                aH[i] = *(const bf16x8*)&AsH[aOff[i]];
                aL[i] = *(const bf16x8*)&AsL[aOff[i]];
                bH[i] = *(const bf16x8*)&BsH[bOff[i]];
                bL[i] = *(const bf16x8*)&BsL[bOff[i]];
            }
            #pragma unroll
            for (int i = 0; i < 2; i++)
            #pragma unroll
            for (int j = 0; j < 2; j++) {
                acc[i][j] = __builtin_amdgcn_mfma_f32_16x16x32_bf16(aH[i], bH[j], acc[i][j], 0, 0, 0);
                acc[i][j] = __builtin_amdgcn_mfma_f32_16x16x32_bf16(aH[i], bL[j], acc[i][j], 0, 0, 0);
                acc[i][j] = __builtin_amdgcn_mfma_f32_16x16x32_bf16(aL[i], bH[j], acc[i][j], 0, 0, 0);
            }
        }
        // ---- step 1: buffer 1, tile kk+32 ----
        *(bf16x8*)&AsH[2048 + t * 8] = vah1;
        *(bf16x8*)&AsL[2048 + t * 8] = val1;
        *(bf16x8*)&BsH[2048 + t * 8] = vbh1;
        *(bf16x8*)&BsL[2048 + t * 8] = vbl1;
        __syncthreads();
        {
            int kn = (kk + 96 < K) ? kk + 96 : kk + 32;
            vah1 = *(const bf16x8*)(AbH + aoff + kn);
            val1 = *(const bf16x8*)(AbL + aoff + kn);
            vbh1 = *(const bf16x8*)(BbH + boff + kn);
            vbl1 = *(const bf16x8*)(BbL + boff + kn);
        }
        {
            bf16x8 aH[2], aL[2], bH[2], bL[2];
            #pragma unroll
            for (int i = 0; i < 2; i++) {
                aH[i] = *(const bf16x8*)&AsH[2048 + aOff[i]];
                aL[i] = *(const bf16x8*)&AsL[2048 + aOff[i]];
                bH[i] = *(const bf16x8*)&BsH[2048 + bOff[i]];
                bL[i] = *(const bf16x8*)&BsL[2048 + bOff[i]];
            }
            #pragma unroll
            for (int i = 0; i < 2; i++)
            #pragma unroll
            for (int j = 0; j < 2; j++) {
                acc[i][j] = __builtin_amdgcn_mfma_f32_16x16x32_bf16(aH[i], bH[j], acc[i][j], 0, 0, 0);
                acc[i][j] = __builtin_amdgcn_mfma_f32_16x16x32_bf16(aH[i], bL[j], acc[i][j], 0, 0, 0);
                acc[i][j] = __builtin_amdgcn_mfma_f32_16x16x32_bf16(aL[i], bH[j], acc[i][j], 0, 0, 0);
            }
        }
    }
    #pragma unroll
    for (int i = 0; i < 2; i++)
    #pragma unroll
    for (int j = 0; j < 2; j++)
    #pragma unroll
    for (int r = 0; r < 4; r++) {
        int row = bm + wm + i * 16 + fq * 4 + r;
        int col = bn + wn + j * 16 + fr;
        if (row < M) {
            long off = (long)row * cs_m + (long)col * cs_n;
            float v = acc[i][j][r];
            if (bias) v += bias[col];
            if (Oh) {
                bf16 hh, ll; split2(v, hh, ll);
                Oh[off] = hh; Ol[off] = ll;
            } else {
                if (Rb) v += Rb[off];
                Cb[off] = v;
            }
        }
    }
}

// ---- split-precision bf16 MFMA GEMM, 128x64 tile, depth-2 prefetch (qkv GEMM) ----
__global__ __launch_bounds__(256) void mgemm128x64_kernel(
    const bf16* __restrict__ Ah, const bf16* __restrict__ Al,
    const bf16* __restrict__ Bh, const bf16* __restrict__ Bl,
    const float* __restrict__ bias, bf16* __restrict__ Oh, bf16* __restrict__ Ol,
    int M, int N, int K) {
    __shared__ short AsH[2 * 4096];
    __shared__ short AsL[2 * 4096];
    __shared__ short BsH[2 * 2048];
    __shared__ short BsL[2 * 2048];
    const short* AbH = (const short*)Ah;
    const short* AbL = (const short*)Al;
    const short* BbH = (const short*)Bh;
    const short* BbL = (const short*)Bl;
    int bm = blockIdx.y * 128, bn = blockIdx.x * 64;
    int t = threadIdx.x, lane = t & 63, w = t >> 6;
    int wm = (w >> 1) * 64, wn = (w & 1) * 32;
    int p0 = t, p1 = t + 256;
    int ra0 = p0 >> 2, ka0 = (p0 & 3) ^ ((ra0 >> 1) & 3);
    int ra1 = p1 >> 2, ka1 = (p1 & 3) ^ ((ra1 >> 1) & 3);
    int arow0 = bm + ra0; if (arow0 > M - 1) arow0 = M - 1;
    int arow1 = bm + ra1; if (arow1 > M - 1) arow1 = M - 1;
    long aoff0 = (long)arow0 * K + ka0 * 8;
    long aoff1 = (long)arow1 * K + ka1 * 8;
    int rb = t >> 2, kb2 = (t & 3) ^ ((rb >> 1) & 3);
    long boff = (long)(bn + rb) * K + kb2 * 8;
    int fr = lane & 15, fq = lane >> 4;
    int aOff[4], bOff[2];
    #pragma unroll
    for (int i = 0; i < 4; i++) {
        int row = wm + i * 16 + fr;
        aOff[i] = row * 32 + ((fq ^ ((row >> 1) & 3)) * 8);
    }
    #pragma unroll
    for (int j = 0; j < 2; j++) {
        int col = wn + j * 16 + fr;
        bOff[j] = col * 32 + ((fq ^ ((col >> 1) & 3)) * 8);
    }
    f32x4 acc[4][2] = {};
    // depth-2 prologue
    bf16x8 sA0h0 = *(const bf16x8*)(AbH + aoff0);
    bf16x8 sA1h0 = *(const bf16x8*)(AbH + aoff1);
    bf16x8 sA0l0 = *(const bf16x8*)(AbL + aoff0);
    bf16x8 sA1l0 = *(const bf16x8*)(AbL + aoff1);
    bf16x8 sBh0  = *(const bf16x8*)(BbH + boff);
    bf16x8 sBl0  = *(const bf16x8*)(BbL + boff);
    bf16x8 sA0h1 = *(const bf16x8*)(AbH + aoff0 + 32);
    bf16x8 sA1h1 = *(const bf16x8*)(AbH + aoff1 + 32);
    bf16x8 sA0l1 = *(const bf16x8*)(AbL + aoff0 + 32);
    bf16x8 sA1l1 = *(const bf16x8*)(AbL + aoff1 + 32);
    bf16x8 sBh1  = *(const bf16x8*)(BbH + boff + 32);
    bf16x8 sBl1  = *(const bf16x8*)(BbL + boff + 32);
    for (int kk = 0; kk < K; kk += 64) {
        // ---- step 0: buffer 0, tile kk ----
        *(bf16x8*)&AsH[p0 * 8] = sA0h0;  *(bf16x8*)&AsH[p1 * 8] = sA1h0;
        *(bf16x8*)&AsL[p0 * 8] = sA0l0;  *(bf16x8*)&AsL[p1 * 8] = sA1l0;
        *(bf16x8*)&BsH[t * 8] = sBh0;
        *(bf16x8*)&BsL[t * 8] = sBl0;
        __syncthreads();
        {
            int kn = (kk + 64 < K) ? kk + 64 : kk;
            sA0h0 = *(const bf16x8*)(AbH + aoff0 + kn);
            sA1h0 = *(const bf16x8*)(AbH + aoff1 + kn);
            sA0l0 = *(const bf16x8*)(AbL + aoff0 + kn);
            sA1l0 = *(const bf16x8*)(AbL + aoff1 + kn);
            sBh0  = *(const bf16x8*)(BbH + boff + kn);
            sBl0  = *(const bf16x8*)(BbL + boff + kn);
        }
        {
            bf16x8 aH[4], aL[4], bH[2], bL[2];
            #pragma unroll
            for (int i = 0; i < 4; i++) {
                aH[i] = *(const bf16x8*)&AsH[aOff[i]];
                aL[i] = *(const bf16x8*)&AsL[aOff[i]];
            }
            #pragma unroll
            for (int j = 0; j < 2; j++) {
                bH[j] = *(const bf16x8*)&BsH[bOff[j]];
                bL[j] = *(const bf16x8*)&BsL[bOff[j]];
            }
            #pragma unroll
            for (int i = 0; i < 4; i++)
            #pragma unroll
            for (int j = 0; j < 2; j++) {
                acc[i][j] = __builtin_amdgcn_mfma_f32_16x16x32_bf16(aH[i], bH[j], acc[i][j], 0, 0, 0);
                acc[i][j] = __builtin_amdgcn_mfma_f32_16x16x32_bf16(aH[i], bL[j], acc[i][j], 0, 0, 0);
                acc[i][j] = __builtin_amdgcn_mfma_f32_16x16x32_bf16(aL[i], bH[j], acc[i][j], 0, 0, 0);
            }
        }
        // ---- step 1: buffer 1, tile kk+32 ----
        *(bf16x8*)&AsH[4096 + p0 * 8] = sA0h1;  *(bf16x8*)&AsH[4096 + p1 * 8] = sA1h1;
        *(bf16x8*)&AsL[4096 + p0 * 8] = sA0l1;  *(bf16x8*)&AsL[4096 + p1 * 8] = sA1l1;
        *(bf16x8*)&BsH[2048 + t * 8] = sBh1;
        *(bf16x8*)&BsL[2048 + t * 8] = sBl1;
        __syncthreads();
        {
            int kn = (kk + 96 < K) ? kk + 96 : kk + 32;
            sA0h1 = *(const bf16x8*)(AbH + aoff0 + kn);
            sA1h1 = *(const bf16x8*)(AbH + aoff1 + kn);
            sA0l1 = *(const bf16x8*)(AbL + aoff0 + kn);
            sA1l1 = *(const bf16x8*)(AbL + aoff1 + kn);
            sBh1  = *(const bf16x8*)(BbH + boff + kn);
            sBl1  = *(const bf16x8*)(BbL + boff + kn);
        }
        {
            bf16x8 aH[4], aL[4], bH[2], bL[2];
            #pragma unroll
            for (int i = 0; i < 4; i++) {
                aH[i] = *(const bf16x8*)&AsH[4096 + aOff[i]];
                aL[i] = *(const bf16x8*)&AsL[4096 + aOff[i]];
            }
            #pragma unroll
            for (int j = 0; j < 2; j++) {
                bH[j] = *(const bf16x8*)&BsH[2048 + bOff[j]];
                bL[j] = *(const bf16x8*)&BsL[2048 + bOff[j]];
            }
            #pragma unroll
            for (int i = 0; i < 4; i++)
            #pragma unroll
            for (int j = 0; j < 2; j++) {
                acc[i][j] = __builtin_amdgcn_mfma_f32_16x16x32_bf16(aH[i], bH[j], acc[i][j], 0, 0, 0);
                acc[i][j] = __builtin_amdgcn_mfma_f32_16x16x32_bf16(aH[i], bL[j], acc[i][j], 0, 0, 0);
                acc[i][j] = __builtin_amdgcn_mfma_f32_16x16x32_bf16(aL[i], bH[j], acc[i][j], 0, 0, 0);
            }
        }
    }
    #pragma unroll
    for (int i = 0; i < 4; i++)
    #pragma unroll
    for (int j = 0; j < 2; j++)
    #pragma unroll
    for (int r = 0; r < 4; r++) {
        int row = bm + wm + i * 16 + fq * 4 + r;
        int col = bn + wn + j * 16 + fr;
        if (row < M) {
            long off = (long)row * N + col;
            float v = acc[i][j][r] + bias[col];
            bf16 hh, ll; split2(v, hh, ll);
            Oh[off] = hh; Ol[off] = ll;
        }
    }
}

// ---- split-precision MFMA flash SA: no-max softmax, single-bf16 P, V stride 72 ----
__global__ __launch_bounds__(256) void sa_mfma_kernel(
    const bf16* __restrict__ qh, const bf16* __restrict__ ql,
    bf16* __restrict__ oh, bf16* __restrict__ ol) {
    int qt = blockIdx.x, h = blockIdx.y, b = blockIdx.z;
    __shared__ short KsH[4096], KsL[4096];       // [kv][64], swz: col ^ ((kv&7)<<3)
    __shared__ short VtH[4608], VtL[4608];       // [d][72], swz: col ^ (((d>>3)&7)<<3)
    __shared__ short PHs[4][1024];               // per-wave P (single bf16)
    int t = threadIdx.x, lane = t & 63, w = t >> 6;
    int fr = lane & 15, fq = lane >> 4;
    const short* QH = (const short*)qh;
    const short* QL = (const short*)ql;
    long qrow = (long)(b * 1024 + qt * 64 + w * 16 + fr) * 1536 + h * 64;
    bf16x8 Qh2[2], Ql2[2];
    Qh2[0] = *(const bf16x8*)(QH + qrow + fq * 8);
    Qh2[1] = *(const bf16x8*)(QH + qrow + 32 + fq * 8);
    Ql2[0] = *(const bf16x8*)(QL + qrow + fq * 8);
    Ql2[1] = *(const bf16x8*)(QL + qrow + 32 + fq * 8);
    float l_i[4] = {0.f, 0.f, 0.f, 0.f};
    f32x4 o_acc[4] = {};
    int c0 = t, c1 = t + 256;
    int r0 = c0 >> 3, g0 = c0 & 7;               // r0 in 0..31
    int r1 = c1 >> 3, g1 = c1 & 7;               // r1 in 32..63
    int kd0 = r0 * 64 + ((g0 * 8) ^ ((r0 & 7) << 3));
    int kd1 = r1 * 64 + ((g1 * 8) ^ ((r1 & 7) << 3));
    long kb = (long)(b * 1024) * 1536 + 512 + h * 64;
    long vb = kb + 512;
    long lo0 = (long)r0 * 1536 + g0 * 8, lo1 = (long)r1 * 1536 + g1 * 8;
    short* ph = PHs[w];
    bf16x8 kh0 = *(const bf16x8*)(QH + kb + lo0);
    bf16x8 kh1 = *(const bf16x8*)(QH + kb + lo1);
    bf16x8 kl0 = *(const bf16x8*)(QL + kb + lo0);
    bf16x8 kl1 = *(const bf16x8*)(QL + kb + lo1);
    bf16x8 vh0 = *(const bf16x8*)(QH + vb + lo0);
    bf16x8 vh1 = *(const bf16x8*)(QH + vb + lo1);
    bf16x8 vl0 = *(const bf16x8*)(QL + vb + lo0);
    bf16x8 vl1 = *(const bf16x8*)(QL + vb + lo1);
    for (int kt = 0; kt < 16; kt++) {
        __syncthreads();          // A: all waves finished reading Ks/Vt of prev iter
        *(bf16x8*)&KsH[kd0] = kh0;  *(bf16x8*)&KsH[kd1] = kh1;
        *(bf16x8*)&KsL[kd0] = kl0;  *(bf16x8*)&KsL[kd1] = kl1;
        #pragma unroll
        for (int j = 0; j < 8; j++) {
            int d0 = g0 * 8 + j;
            int i0 = d0 * 72 + (r0 ^ (g0 << 3));
            VtH[i0] = ((short*)&vh0)[j];  VtL[i0] = ((short*)&vl0)[j];
            int d1 = g1 * 8 + j;
            int i1 = d1 * 72 + (r1 ^ (g1 << 3));
            VtH[i1] = ((short*)&vh1)[j];  VtL[i1] = ((short*)&vl1)[j];
        }
        __syncthreads();          // B: staging visible
        int ktn = (kt + 1 < 16) ? kt + 1 : kt;
        long ko = kb + (long)(ktn * 64) * 1536;
        long vo = vb + (long)(ktn * 64) * 1536;
        bf16x8 nkh0 = *(const bf16x8*)(QH + ko + lo0);
        bf16x8 nkh1 = *(const bf16x8*)(QH + ko + lo1);
        bf16x8 nkl0 = *(const bf16x8*)(QL + ko + lo0);
        bf16x8 nkl1 = *(const bf16x8*)(QL + ko + lo1);
        bf16x8 nvh0 = *(const bf16x8*)(QH + vo + lo0);
        bf16x8 nvh1 = *(const bf16x8*)(QH + vo + lo1);
        bf16x8 nvl0 = *(const bf16x8*)(QL + vo + lo0);
        bf16x8 nvl1 = *(const bf16x8*)(QL + vo + lo1);
        __builtin_amdgcn_s_setprio(1);
        f32x4 s[4] = {};
        #pragma unroll
        for (int cf = 0; cf < 4; cf++) {
            int kvrow = cf * 16 + fr;
            #pragma unroll
            for (int kf = 0; kf < 2; kf++) {
                int idx = kvrow * 64 + ((kf * 32 + fq * 8) ^ ((kvrow & 7) << 3));
                bf16x8 Bh2 = *(const bf16x8*)&KsH[idx];
                bf16x8 Bl2 = *(const bf16x8*)&KsL[idx];
                s[cf] = __builtin_amdgcn_mfma_f32_16x16x32_bf16(Qh2[kf], Bh2, s[cf], 0, 0, 0);
                s[cf] = __builtin_amdgcn_mfma_f32_16x16x32_bf16(Qh2[kf], Bl2, s[cf], 0, 0, 0);
                s[cf] = __builtin_amdgcn_mfma_f32_16x16x32_bf16(Ql2[kf], Bh2, s[cf], 0, 0, 0);
            }
        }
        __builtin_amdgcn_s_setprio(0);
        // ---- no-max softmax: P = exp(S/8) rounded to single bf16; l from rounded P ----
        #pragma unroll
        for (int cf = 0; cf < 4; cf++)
        #pragma unroll
        for (int reg = 0; reg < 4; reg++) {
            float e = __expf(s[cf][reg] * 0.125f);
            bf16 eb = __float2bfloat16(e);
            l_i[reg] += __bfloat162float(eb);
            int q = fq * 4 + reg, kv = cf * 16 + fr;
            int idx = q * 64 + (kv ^ ((q & 7) << 3));
            ph[idx] = *(short*)&eb;
        }
        asm volatile("s_waitcnt lgkmcnt(0)" ::: "memory");
        __builtin_amdgcn_sched_barrier(0);
        __builtin_amdgcn_s_setprio(1);
        bf16x8 Pf_h[2];
        #pragma unroll
        for (int kf = 0; kf < 2; kf++) {
            int idx = fr * 64 + ((kf * 32 + fq * 8) ^ ((fr & 7) << 3));
            Pf_h[kf] = *(const bf16x8*)&ph[idx];
        }
        #pragma unroll
        for (int cf = 0; cf < 4; cf++) {
            int d = cf * 16 + fr;
            #pragma unroll
            for (int kf = 0; kf < 2; kf++) {
                int idx = d * 72 + ((kf * 32 + fq * 8) ^ (((d >> 3) & 7) << 3));
                bf16x8 Vh2 = *(const bf16x8*)&VtH[idx];
                bf16x8 Vl2 = *(const bf16x8*)&VtL[idx];
                o_acc[cf] = __builtin_amdgcn_mfma_f32_16x16x32_bf16(Pf_h[kf], Vh2, o_acc[cf], 0, 0, 0);
                o_acc[cf] = __builtin_amdgcn_mfma_f32_16x16x32_bf16(Pf_h[kf], Vl2, o_acc[cf], 0, 0, 0);
            }
        }
        __builtin_amdgcn_s_setprio(0);
        kh0 = nkh0; kh1 = nkh1; kl0 = nkl0; kl1 = nkl1;
        vh0 = nvh0; vh1 = nvh1; vl0 = nvl0; vl1 = nvl1;
    }
    #pragma unroll
    for (int reg = 0; reg < 4; reg++) {
        float rs = l_i[reg];
        rs += __shfl_xor(rs, 1);
        rs += __shfl_xor(rs, 2);
        rs += __shfl_xor(rs, 4);
        rs += __shfl_xor(rs, 8);
        float inv = 1.f / rs;
        long m = (long)(b * 1024 + qt * 64 + w * 16 + fq * 4 + reg);
        #pragma unroll
        for (int cf = 0; cf < 4; cf++) {
            float v = o_acc[cf][reg] * inv;
            bf16 hh, ll; split2(v, hh, ll);
            long off = m * DIMC + h * 64 + cf * 16 + fr;
            oh[off] = hh; ol[off] = ll;
        }
    }
}

// ---- split-precision MFMA cross-attention: 77 keys padded to 96, single-bf16 P ----
__global__ __launch_bounds__(256) void ca_mfma_kernel(
    const bf16* __restrict__ qh, const bf16* __restrict__ ql,
    const bf16* __restrict__ kvh, const bf16* __restrict__ kvl,
    bf16* __restrict__ oh, bf16* __restrict__ ol) {
    int qt = blockIdx.x, h = blockIdx.y, b = blockIdx.z;
    __shared__ short UH[8192], UL[8192];
    __shared__ short PHs[4][2048];
    int t = threadIdx.x, lane = t & 63, w = t >> 6;
    int fr = lane & 15, fq = lane >> 4;
    const short* QH = (const short*)qh;
    const short* QL = (const short*)ql;
    const short* KVH = (const short*)kvh;
    const short* KVL = (const short*)kvl;
    long qrow = (long)(b * 1024 + qt * 64 + w * 16 + fr) * DIMC + h * 64;
    bf16x8 Qh2[2], Ql2[2];
    Qh2[0] = *(const bf16x8*)(QH + qrow + fq * 8);
    Qh2[1] = *(const bf16x8*)(QH + qrow + 32 + fq * 8);
    Ql2[0] = *(const bf16x8*)(QL + qrow + fq * 8);
    Ql2[1] = *(const bf16x8*)(QL + qrow + 32 + fq * 8);
    for (int c = t; c < 768; c += 256) {
        int r = c >> 3, g = c & 7;
        int idx = r * 64 + ((g * 8) ^ ((r & 7) << 3));
        bf16x8 vh = {}, vl = {};
        if (r < 77) {
            long src = (long)(b * 77 + r) * 1024 + h * 64 + g * 8;
            vh = *(const bf16x8*)(KVH + src);
            vl = *(const bf16x8*)(KVL + src);
        }
        *(bf16x8*)&UH[idx] = vh;
        *(bf16x8*)&UL[idx] = vl;
    }
    __syncthreads();
    f32x4 s[5] = {};
    #pragma unroll
    for (int cf = 0; cf < 5; cf++) {
        int kvrow = cf * 16 + fr;
        #pragma unroll
        for (int kf = 0; kf < 2; kf++) {
            int idx = kvrow * 64 + ((kf * 32 + fq * 8) ^ ((kvrow & 7) << 3));
            bf16x8 Bh2 = *(const bf16x8*)&UH[idx];
            bf16x8 Bl2 = *(const bf16x8*)&UL[idx];
            s[cf] = __builtin_amdgcn_mfma_f32_16x16x32_bf16(Qh2[kf], Bh2, s[cf], 0, 0, 0);
            s[cf] = __builtin_amdgcn_mfma_f32_16x16x32_bf16(Qh2[kf], Bl2, s[cf], 0, 0, 0);
            s[cf] = __builtin_amdgcn_mfma_f32_16x16x32_bf16(Ql2[kf], Bh2, s[cf], 0, 0, 0);
        }
    }
    float inv[4];
    #pragma unroll
    for (int reg = 0; reg < 4; reg++) {
        float rs = 0.f;
        #pragma unroll
        for (int cf = 0; cf < 5; cf++) {
            int kv = cf * 16 + fr;
            float e = (kv < 77) ? __expf(s[cf][reg] * 0.125f) : 0.f;
            s[cf][reg] = e;
            rs += e;
        }
        rs += __shfl_xor(rs, 1);
        rs += __shfl_xor(rs, 2);
        rs += __shfl_xor(rs, 4);
        rs += __shfl_xor(rs, 8);
        inv[reg] = 1.f / rs;
    }
    short* ph = PHs[w];
    #pragma unroll
    for (int cf = 0; cf < 6; cf++)
    #pragma unroll
    for (int reg = 0; reg < 4; reg++) {
        int q = fq * 4 + reg, kv = cf * 16 + fr;
        int idx = q * 128 + (kv ^ ((q & 7) << 3));
        float pv = (cf < 5) ? s[cf][reg] * inv[reg] : 0.f;
        bf16 pb = __float2bfloat16(pv);
        ph[idx] = *(short*)&pb;
    }
    __syncthreads();
    for (int c = t; c < 768; c += 256) {
        int r = c >> 3, g = c & 7;
        bf16x8 vh = {}, vl = {};
        if (r < 77) {
            long src = (long)(b * 77 + r) * 1024 + 512 + h * 64 + g * 8;
            vh = *(const bf16x8*)(KVH + src);
            vl = *(const bf16x8*)(KVL + src);
        }
        #pragma unroll
        for (int j = 0; j < 8; j++) {
            int d = g * 8 + j;
            int idx = d * 128 + (r ^ (((d >> 3) & 7) << 3));
            UH[idx] = ((short*)&vh)[j];
            UL[idx] = ((short*)&vl)[j];
        }
    }
    __syncthreads();
    f32x4 o_acc[4] = {};
    bf16x8 Pf_h[3];
    #pragma unroll
    for (int kf = 0; kf < 3; kf++) {
        int idx = fr * 128 + ((kf * 32 + fq * 8) ^ ((fr & 7) << 3));
        Pf_h[kf] = *(const bf16x8*)&ph[idx];
    }
    #pragma unroll
    for (int cf = 0; cf < 4; cf++) {
        int d = cf * 16 + fr;
        #pragma unroll
        for (int kf = 0; kf < 3; kf++) {
            int idx = d * 128 + ((kf * 32 + fq * 8) ^ (((d >> 3) & 7) << 3));
            bf16x8 Vh2 = *(const bf16x8*)&UH[idx];
            bf16x8 Vl2 = *(const bf16x8*)&UL[idx];
            o_acc[cf] = __builtin_amdgcn_mfma_f32_16x16x32_bf16(Pf_h[kf], Vh2, o_acc[cf], 0, 0, 0);
            o_acc[cf] = __builtin_amdgcn_mfma_f32_16x16x32_bf16(Pf_h[kf], Vl2, o_acc[cf], 0, 0, 0);
        }
    }
    #pragma unroll
    for (int reg = 0; reg < 4; reg++) {
        long m = (long)(b * 1024 + qt * 64 + w * 16 + fq * 4 + reg);
        #pragma unroll
        for (int cf = 0; cf < 4; cf++) {
            bf16 hh, ll; split2(o_acc[cf][reg], hh, ll);
            long off = m * DIMC + h * 64 + cf * 16 + fr;
            oh[off] = hh; ol[off] = ll;
        }
    }
}

// ---- MoE grouped MFMA GEMM1, 64x128 tile, depth-2 prefetch: hid = gelu(xn·w1 + b1) ----
__global__ __launch_bounds__(256) void moe128_1_kernel(
    const bf16* __restrict__ xn_b, const bf16* __restrict__ e1T, const float* __restrict__ e_b1,
    const int* __restrict__ table, const int* __restrict__ ntiles, const int* __restrict__ perm,
    bf16* __restrict__ hid_b) {
    if (blockIdx.y >= ntiles[0]) return;
    int e = table[2 * blockIdx.y], row0 = table[2 * blockIdx.y + 1];
    int bn = blockIdx.x * 128;
    __shared__ short As[2 * 2048];
    __shared__ short Bs[2 * 4096];
    __shared__ int rowsS[64];
    int t = threadIdx.x, lane = t & 63, w = t >> 6;
    if (t < 64) rowsS[t] = perm[row0 + t];
    __syncthreads();
    int wm = (w >> 1) * 32, wn = (w & 1) * 64;
    int ra = t >> 2, ka = (t & 3) ^ ((ra >> 1) & 3);
    int tok0 = rowsS[ra]; if (tok0 < 0) tok0 = 0;
    const short* Xs = (const short*)xn_b;
    const short* Ws = (const short*)(e1T + (long)e * HIDC * DIMC);
    const short* a0 = Xs + (long)tok0 * DIMC + ka * 8;
    int p0 = t, p1 = t + 256;
    int rb0 = p0 >> 2, kb0 = (p0 & 3) ^ ((rb0 >> 1) & 3);
    int rb1 = p1 >> 2, kb1 = (p1 & 3) ^ ((rb1 >> 1) & 3);
    const short* b0 = Ws + (long)(bn + rb0) * DIMC + kb0 * 8;
    const short* b1 = Ws + (long)(bn + rb1) * DIMC + kb1 * 8;
    int fr = lane & 15, fq = lane >> 4;
    int aOff[2], bOff[4];
    #pragma unroll
    for (int i = 0; i < 2; i++) {
        int row = wm + i * 16 + fr;
        aOff[i] = row * 32 + ((fq ^ ((row >> 1) & 3)) * 8);
    }
    #pragma unroll
    for (int j = 0; j < 4; j++) {
        int col = wn + j * 16 + fr;
        bOff[j] = col * 32 + ((fq ^ ((col >> 1) & 3)) * 8);
    }
    f32x4 acc[2][4] = {};
    bf16x8 va_0  = *(const bf16x8*)a0;
    bf16x8 vb0_0 = *(const bf16x8*)b0;
    bf16x8 vb1_0 = *(const bf16x8*)b1;
    bf16x8 va_1  = *(const bf16x8*)(a0 + 32);
    bf16x8 vb0_1 = *(const bf16x8*)(b0 + 32);
    bf16x8 vb1_1 = *(const bf16x8*)(b1 + 32);
    for (int kk = 0; kk < DIMC; kk += 64) {
        // ---- step 0: buffer 0, tile kk ----
        *(bf16x8*)&As[t * 8] = va_0;
        *(bf16x8*)&Bs[p0 * 8] = vb0_0;
        *(bf16x8*)&Bs[p1 * 8] = vb1_0;
        __syncthreads();
        {
            int kn = (kk + 64 < DIMC) ? kk + 64 : kk;
            va_0  = *(const bf16x8*)(a0 + kn);
            vb0_0 = *(const bf16x8*)(b0 + kn);
            vb1_0 = *(const bf16x8*)(b1 + kn);
        }
        {
            bf16x8 aF[2], bF[4];
            #pragma unroll
            for (int i = 0; i < 2; i++) aF[i] = *(const bf16x8*)&As[aOff[i]];
            #pragma unroll
            for (int j = 0; j < 4; j++) bF[j] = *(const bf16x8*)&Bs[bOff[j]];
            #pragma unroll
            for (int i = 0; i < 2; i++)
            #pragma unroll
            for (int j = 0; j < 4; j++)
                acc[i][j] = __builtin_amdgcn_mfma_f32_16x16x32_bf16(aF[i], bF[j], acc[i][j], 0, 0, 0);
        }
        // ---- step 1: buffer 1, tile kk+32 ----
        *(bf16x8*)&As[2048 + t * 8] = va_1;
        *(bf16x8*)&Bs[4096 + p0 * 8] = vb0_1;
        *(bf16x8*)&Bs[4096 + p1 * 8] = vb1_1;
        __syncthreads();
        {
            int kn = (kk + 96 < DIMC) ? kk + 96 : kk + 32;
            va_1  = *(const bf16x8*)(a0 + kn);
            vb0_1 = *(const bf16x8*)(b0 + kn);
            vb1_1 = *(const bf16x8*)(b1 + kn);
        }
        {
            bf16x8 aF[2], bF[4];
            #pragma unroll
            for (int i = 0; i < 2; i++) aF[i] = *(const bf16x8*)&As[2048 + aOff[i]];
            #pragma unroll
            for (int j = 0; j < 4; j++) bF[j] = *(const bf16x8*)&Bs[4096 + bOff[j]];
            #pragma unroll
            for (int i = 0; i < 2; i++)
            #pragma unroll
            for (int j = 0; j < 4; j++)
                acc[i][j] = __builtin_amdgcn_mfma_f32_16x16x32_bf16(aF[i], bF[j], acc[i][j], 0, 0, 0);
        }
    }
    const float* bb = e_b1 + (long)e * HIDC;
    #pragma unroll
    for (int i = 0; i < 2; i++)
    #pragma unroll
    for (int r = 0; r < 4; r++) {
        int tok = rowsS[wm + i * 16 + fq * 4 + r];
        if (tok < 0) continue;
        #pragma unroll
        for (int j = 0; j < 4; j++) {
            int col = bn + wn + j * 16 + fr;
            float v = acc[i][j][r] + bb[col];
            v = 0.5f * v * (1.f + erff(v * 0.70710678f));
            hid_b[(long)tok * HIDC + col] = __float2bfloat16(v);
        }
    }
}

// ---- MoE grouped MFMA GEMM2, 64x128 tile, depth-2 prefetch: out = resid + hid·w2 + b2 ----
__global__ __launch_bounds__(256) void moe128_2_kernel(
    const bf16* __restrict__ hid_b, const bf16* __restrict__ e2T, const float* __restrict__ e_b2,
    const int* __restrict__ table, const int* __restrict__ ntiles, const int* __restrict__ perm,
    const float* __restrict__ resid, bf16* __restrict__ outh, bf16* __restrict__ outl) {
    if (blockIdx.y >= ntiles[0]) return;
    int e = table[2 * blockIdx.y], row0 = table[2 * blockIdx.y + 1];
    int bn = blockIdx.x * 128;
    __shared__ short As[2 * 2048];
    __shared__ short Bs[2 * 4096];
    __shared__ int rowsS[64];
    int t = threadIdx.x, lane = t & 63, w = t >> 6;
    if (t < 64) rowsS[t] = perm[row0 + t];
    __syncthreads();
    int wm = (w >> 1) * 32, wn = (w & 1) * 64;
    int ra = t >> 2, ka = (t & 3) ^ ((ra >> 1) & 3);
    int tok0 = rowsS[ra]; if (tok0 < 0) tok0 = 0;
    const short* Hs = (const short*)hid_b;
    const short* Ws = (const short*)(e2T + (long)e * DIMC * HIDC);
    const short* a0 = Hs + (long)tok0 * HIDC + ka * 8;
    int p0 = t, p1 = t + 256;
    int rb0 = p0 >> 2, kb0 = (p0 & 3) ^ ((rb0 >> 1) & 3);
    int rb1 = p1 >> 2, kb1 = (p1 & 3) ^ ((rb1 >> 1) & 3);
    const short* b0 = Ws + (long)(bn + rb0) * HIDC + kb0 * 8;
    const short* b1 = Ws + (long)(bn + rb1) * HIDC + kb1 * 8;
    int fr = lane & 15, fq = lane >> 4;
    int aOff[2], bOff[4];
    #pragma unroll
    for (int i = 0; i < 2; i++) {
        int row = wm + i * 16 + fr;
        aOff[i] = row * 32 + ((fq ^ ((row >> 1) & 3)) * 8);
    }
    #pragma unroll
    for (int j = 0; j < 4; j++) {
        int col = wn + j * 16 + fr;
        bOff[j] = col * 32 + ((fq ^ ((col >> 1) & 3)) * 8);
    }
    f32x4 acc[2][4] = {};
    bf16x8 va_0  = *(const bf16x8*)a0;
    bf16x8 vb0_0 = *(const bf16x8*)b0;
    bf16x8 vb1_0 = *(const bf16x8*)b1;
    bf16x8 va_1  = *(const bf16x8*)(a0 + 32);
    bf16x8 vb0_1 = *(const bf16x8*)(b0 + 32);
    bf16x8 vb1_1 = *(const bf16x8*)(b1 + 32);
    for (int kk = 0; kk < HIDC; kk += 64) {
        // ---- step 0: buffer 0, tile kk ----
        *(bf16x8*)&As[t * 8] = va_0;
        *(bf16x8*)&Bs[p0 * 8] = vb0_0;
        *(bf16x8*)&Bs[p1 * 8] = vb1_0;
        __syncthreads();
        {
            int kn = (kk + 64 < HIDC) ? kk + 64 : kk;
            va_0  = *(const bf16x8*)(a0 + kn);
            vb0_0 = *(const bf16x8*)(b0 + kn);
            vb1_0 = *(const bf16x8*)(b1 + kn);
        }
        {
            bf16x8 aF[2], bF[4];
            #pragma unroll
            for (int i = 0; i < 2; i++) aF[i] = *(const bf16x8*)&As[aOff[i]];
            #pragma unroll
            for (int j = 0; j < 4; j++) bF[j] = *(const bf16x8*)&Bs[bOff[j]];
            #pragma unroll
            for (int i = 0; i < 2; i++)
            #pragma unroll
            for (int j = 0; j < 4; j++)
                acc[i][j] = __builtin_amdgcn_mfma_f32_16x16x32_bf16(aF[i], bF[j], acc[i][j], 0, 0, 0);
        }
        // ---- step 1: buffer 1, tile kk+32 ----
        *(bf16x8*)&As[2048 + t * 8] = va_1;
        *(bf16x8*)&Bs[4096 + p0 * 8] = vb0_1;
        *(bf16x8*)&Bs[4096 + p1 * 8] = vb1_1;
        __syncthreads();
        {
            int kn = (kk + 96 < HIDC) ? kk + 96 : kk + 32;
            va_1  = *(const bf16x8*)(a0 + kn);
            vb0_1 = *(const bf16x8*)(b0 + kn);
            vb1_1 = *(const bf16x8*)(b1 + kn);
        }
        {
            bf16x8 aF[2], bF[4];
            #pragma unroll
            for (int i = 0; i < 2; i++) aF[i] = *(const bf16x8*)&As[2048 + aOff[i]];
            #pragma unroll
            for (int j = 0; j < 4; j++) bF[j] = *(const bf16x8*)&Bs[4096 + bOff[j]];
            #pragma unroll
            for (int i = 0; i < 2; i++)
            #pragma unroll
            for (int j = 0; j < 4; j++)
                acc[i][j] = __builtin_amdgcn_mfma_f32_16x16x32_bf16(aF[i], bF[j], acc[i][j], 0, 0, 0);
        }
    }
    const float* bb = e_b2 + (long)e * DIMC;
    #pragma unroll
    for (int i = 0; i < 2; i++)
    #pragma unroll
    for (int r = 0; r < 4; r++) {
        int tok = rowsS[wm + i * 16 + fq * 4 + r];
        if (tok < 0) continue;
        #pragma unroll
        for (int j = 0; j < 4; j++) {
            int col = bn + wn + j * 16 + fr;
            long off = (long)tok * DIMC + col;
            float v = resid[off] + acc[i][j][r] + bb[col];
            bf16 hh, ll; split2(v, hh, ll);
            outh[off] = hh; outl[off] = ll;
        }
    }
}

// ---------------- LayerNorm: optional fp32 + bf16 hi/lo outputs ----------------
__global__ void ln_kernel(const float* __restrict__ x, const float* __restrict__ g,
                          const float* __restrict__ b, float* __restrict__ y,
                          bf16* __restrict__ yh, bf16* __restrict__ yl) {
    int tok = blockIdx.x;
    int t = threadIdx.x;
    const float* xr = x + (long)tok * DIMC;
    float v0 = xr[t], v1 = xr[t + 256];
    __shared__ float red[256];
    red[t] = v0 + v1; __syncthreads();
    for (int s = 128; s > 0; s >>= 1) { if (t < s) red[t] += red[t + s]; __syncthreads(); }
    float mu = red[0] * (1.f / DIMC);
    __syncthreads();
    float d0 = v0 - mu, d1 = v1 - mu;
    red[t] = d0 * d0 + d1 * d1; __syncthreads();
    for (int s = 128; s > 0; s >>= 1) { if (t < s) red[t] += red[t + s]; __syncthreads(); }
    float rs = rsqrtf(red[0] * (1.f / DIMC) + 1e-5f);
    float o0 = d0 * rs * g[t] + b[t];
    float o1 = d1 * rs * g[t + 256] + b[t + 256];
    if (y) { y[(long)tok * DIMC + t] = o0; y[(long)tok * DIMC + t + 256] = o1; }
    bf16 h, l;
    split2(o0, h, l); yh[(long)tok * DIMC + t] = h;       yl[(long)tok * DIMC + t] = l;
    split2(o1, h, l); yh[(long)tok * DIMC + t + 256] = h; yl[(long)tok * DIMC + t + 256] = l;
}

// ---------------- router text part (+ cnt zeroing), latency-optimized ----------------
__global__ void textpart_kernel(const float* __restrict__ w, const float* __restrict__ r_text_mu,
                                const float* __restrict__ r_comb_mu, float* __restrict__ tp,
                                int* __restrict__ cnt) {
    __shared__ float ws[4][512];
    __shared__ float tw[4][128];
    int t = threadIdx.x;
    if (t < NE) cnt[t] = 0;
    for (int i = t; i < 2048; i += 256) ws[i >> 9][i & 511] = w[i];
    __syncthreads();
    for (int j = 0; j < 2; j++) {
        int idx = t + j * 256; int b = idx >> 7, c = idx & 127;
        float s = 0.f;
        #pragma unroll 8
        for (int k = 0; k < 512; k++) s += ws[b][k] * r_text_mu[(long)k * 128 + c];
        tw[b][c] = s;
    }
    __syncthreads();
    if (t < 32) {
        int b = t >> 3, e = t & 7;
        float s = 0.f;
        #pragma unroll 8
        for (int c = 0; c < 128; c++) s += tw[b][c] * r_comb_mu[(long)(128 + c) * 8 + e];
        tp[t] = s;
    }
}

// ---------------- router: perm poison + logits + argmax (latency-optimized) ----------------
__global__ void route_kernel(const float* __restrict__ feat, const float* __restrict__ tp,
                             const float* __restrict__ r_comb_mu, const float* __restrict__ r_temp,
                             float* __restrict__ onehot, int* __restrict__ idx, int* __restrict__ cnt,
                             int* __restrict__ perm) {
    __shared__ float rc[128][8];
    int t = threadIdx.x;
    for (int i = t; i < 1024; i += 256) rc[i >> 3][i & 7] = r_comb_mu[i];
    __syncthreads();
    int n = blockIdx.x * blockDim.x + t;
    if (n < MAXT * 64) perm[n] = -1;
    if (n >= NTOK) return;
    int b = n >> 10;
    float tmp = fmaxf(r_temp[0], 0.1f);
    float invt = 1.f / tmp;
    const float4* fr4 = (const float4*)(feat + (long)n * 128);
    float lg[8];
    #pragma unroll
    for (int e = 0; e < 8; e++) lg[e] = 0.f;
    #pragma unroll
    for (int c4 = 0; c4 < 32; c4++) {
        float4 f = fr4[c4];
        float fa[4] = {f.x, f.y, f.z, f.w};
        #pragma unroll
        for (int q = 0; q < 4; q++) {
            int c = c4 * 4 + q;
            #pragma unroll
            for (int e = 0; e < 8; e++) lg[e] += fa[q] * rc[c][e];
        }
    }
    #pragma unroll
    for (int e = 0; e < 8; e++) lg[e] = (lg[e] + tp[b * 8 + e]) * invt;
    float best = lg[0]; int bi = 0;
    #pragma unroll
    for (int e = 1; e < 8; e++) { if (lg[e] > best) { best = lg[e]; bi = e; } }
    #pragma unroll
    for (int e = 0; e < 8; e++) onehot[(long)n * 8 + e] = (e == bi) ? 1.f : 0.f;
    idx[n] = bi;
    atomicAdd(&cnt[bi], 1);
}

// ---------------- offsets + scatter fused (single block, LDS cursors) ----------------
__global__ void offscatter_kernel(const int* __restrict__ cnt, const int* __restrict__ idx,
                                  int* __restrict__ ntiles, int* __restrict__ table,
                                  int* __restrict__ perm) {
    __shared__ int cur[NE];
    int t = threadIdx.x;
    if (t == 0) {
        int po = 0, nt = 0;
        for (int e = 0; e < NE; e++) {
            cur[e] = po;
            int tiles = (cnt[e] + 63) >> 6;
            for (int j = 0; j < tiles; j++) { table[2 * nt] = e; table[2 * nt + 1] = po + j * 64; nt++; }
            po += tiles * 64;
        }
        ntiles[0] = nt;
    }
    __syncthreads();
    for (int n = t; n < NTOK; n += 256) {
        int e = idx[n];
        int pos = atomicAdd(&cur[e], 1);
        perm[pos] = n;
    }
}

extern "C" void kernel_launch(void* const* d_in, const int* in_sizes, int n_in,
                              void* d_out, int out_size, void* d_ws, size_t ws_size,
                              hipStream_t stream) {
    const float* x        = (const float*)d_in[0];
    const float* w        = (const float*)d_in[1];
    const float* text     = (const float*)d_in[2];
    const float* pin_w    = (const float*)d_in[3];
    const float* pin_mw   = (const float*)d_in[4];
    const float* pin_mb   = (const float*)d_in[5];
    const float* pout_w   = (const float*)d_in[6];
    const float* pout_mw  = (const float*)d_in[7];
    const float* pout_mb  = (const float*)d_in[8];
    const float* ln1g     = (const float*)d_in[9];
    const float* ln1b     = (const float*)d_in[10];
    const float* ln2g     = (const float*)d_in[11];
    const float* ln2b     = (const float*)d_in[12];
    const float* ln3g     = (const float*)d_in[13];
    const float* ln3b     = (const float*)d_in[14];
    const float* sa_in_w  = (const float*)d_in[15];
    const float* sa_in_b  = (const float*)d_in[16];
    const float* sa_out_w = (const float*)d_in[17];
    const float* sa_out_b = (const float*)d_in[18];
    const float* ca_in_w  = (const float*)d_in[19];
    const float* ca_in_b  = (const float*)d_in[20];
    const float* ca_out_w = (const float*)d_in[21];
    const float* ca_out_b = (const float*)d_in[22];
    const float* r_feat   = (const float*)d_in[23];
    const float* r_text   = (const float*)d_in[24];
    const float* r_comb   = (const float*)d_in[25];
    const float* r_temp   = (const float*)d_in[26];
    const float* e_w1     = (const float*)d_in[27];
    const float* e_b1     = (const float*)d_in[28];
    const float* e_w2     = (const float*)d_in[29];
    const float* e_b2     = (const float*)d_in[30];

    float* out    = (float*)d_out;               // [B, DIM, H, W]
    float* onehot = out + (long)BB * DIMC * HWX; // [4096, 8]

    // ---------------- workspace: fp32 pool ----------------
    float* f32p = (float*)d_ws;
    float* style_in  = f32p;                 // 2048
    float* style_out = f32p + 2048;          // 2048
    float* tp        = f32p + 4096;          // 32
    int*   idx       = (int*)(f32p + 4128);  // 4096
    int*   cnt       = (int*)(f32p + 8224);  // 8
    int*   ntiles    = (int*)(f32p + 8240);  // 8
    int*   table     = (int*)(f32p + 8248);  // 256
    int*   perm      = (int*)(f32p + 8504);  // 4608 -> ends 13112
    float* x_flat    = f32p + 13496;         // 2097152
    float* xn        = x_flat + 2097152;     // 2097152 (home of wtC split)
    float* qkv       = xn + 2097152;         // 6291456 (SA q split / CA q split home)
    float* spill     = qkv + 6291456;        // 2097152 (e2T tail)

    // ---------------- bf16 pool (phase-aliased) ----------------
    bf16* bp = (bf16*)(f32p + 12596408);
    bf16* R1 = bp;                           // 6291456 elems, phases
    bf16* xT_h  = R1;
    bf16* xT_l  = R1 + 2097152;
    bf16* wtA_h = R1 + 4194304;
    bf16* wtA_l = R1 + 5242880;
    bf16* obuf_h = R1;
    bf16* obuf_l = R1 + 2097152;
    bf16* kvt_h  = R1 + 4194304;                       // [308][1024] split
    bf16* kvt_l  = kvt_h + 315392;
    float* feat  = (float*)(kvt_l + 315392);           // 524288 fp32
    bf16* xn_h = R1 + 6291456;               // 2097152
    bf16* xn_l = xn_h + 2097152;             // 2097152
    bf16* WB   = xn_l + 2097152;             // 8388608: weights (early) / hid_b (late)
    bf16* text_h   = WB;
    bf16* text_l   = text_h + 157696;
    bf16* sawin_h  = text_l + 157696;
    bf16* sawin_l  = sawin_h + 786432;
    bf16* sawout_h = sawin_l + 786432;
    bf16* sawout_l = sawout_h + 262144;
    bf16* caw_h    = sawout_l + 262144;
    bf16* caw_l    = caw_h + 786432;
    bf16* cawout_h = caw_l + 786432;
    bf16* cawout_l = cawout_h + 262144;
    bf16* rfT_h    = cawout_l + 262144;      // [128][512] split r_feat^T
    bf16* rfT_l    = rfT_h + 65536;
    bf16* hid_b    = WB;                     // overlays weights after ca_out
    bf16* e1T = (bf16*)qkv;                  // [8][2048][512] in qkv+spill
    bf16* e2T = e1T + 8388608;
    bf16* xfl_h = xn_h;                      // moe128_2 writes split output here
    bf16* xfl_l = xn_l;
    bf16* wtC_h = (bf16*)xn;                 // modconv-out weight (dead fp32 region)
    bf16* wtC_l = wtC_h + 1048576;
    bf16* q_h = (bf16*)qkv;                  // [4096][1536]
    bf16* q_l = q_h + 6291456;
    bf16* ca_qh = (bf16*)qkv;                // [4096][512]
    bf16* ca_ql = ca_qh + 2097152;
    (void)ws_size; (void)spill;

    auto mg = [&](const bf16* Ah, const bf16* Al, const bf16* Bh, const bf16* Bl,
                  const float* bias, const float* resid, float* C, bf16* Oh, bf16* Ol,
                  int M, int N, int K, long ab, long bb, long cb, int csm, int csn, int nb) {
        dim3 g(N / 64, (M + 63) / 64, nb);
        hipLaunchKernelGGL(mgemm64_kernel, g, dim3(256), 0, stream,
                           Ah, Al, Bh, Bl, bias, resid, C, Oh, Ol, M, N, K, ab, bb, cb, csm, csn);
    };

    // ---- fused input conversions (hi/lo): one launch for all 5 flat arrays ----
    {
        int n0 = 1536 * 512, n1 = 512 * 512, n2 = 1536 * 512, n3 = 512 * 512, n4 = BB * TXT * 512;
        int total = n0 + n1 + n2 + n3 + n4;
        hipLaunchKernelGGL(cvtall_kernel, dim3((total / 4 + 255) / 256), dim3(256), 0, stream,
                           sa_in_w, sawin_h, sawin_l, n0,
                           sa_out_w, sawout_h, sawout_l, n1,
                           ca_in_w, caw_h, caw_l, n2,
                           ca_out_w, cawout_h, cawout_l, n3,
                           text, text_h, text_l, n4);
    }
    // ---- fused transposes: x (z<4) + r_feat (z==4) ----
    hipLaunchKernelGGL(trcvt2x_kernel, dim3(32, 16, 5), dim3(256), 0, stream,
                       x, xT_h, xT_l, r_feat, rfT_h, rfT_l);

    // ---- both modconv styles + weights up front (wtC in dead xn region) ----
    hipLaunchKernelGGL(style2_kernel, dim3(16), dim3(256), 0, stream,
                       w, pin_mw, pin_mb, pout_mw, pout_mb, style_in, style_out);
    hipLaunchKernelGGL(wtmod2_kernel, dim3(2 * BB * DIMC), dim3(256), 0, stream,
                       pin_w, style_in, pout_w, style_out, wtA_h, wtA_l, wtC_h, wtC_l);

    // ---- modconv in ----
    mg(xT_h, xT_l, wtA_h, wtA_l, nullptr, nullptr, x_flat, nullptr, nullptr,
       HWX, DIMC, DIMC, (long)HWX * DIMC, (long)DIMC * DIMC, (long)HWX * DIMC, DIMC, 1, BB);

    // ---- LN1 + self-attention (split MFMA) ----
    hipLaunchKernelGGL(ln_kernel, dim3(NTOK), dim3(256), 0, stream, x_flat, ln1g, ln1b,
                       (float*)nullptr, xn_h, xn_l);
    // qkv projection via high-reuse 128x64 kernel
    hipLaunchKernelGGL(mgemm128x64_kernel, dim3(1536 / 64, NTOK / 128), dim3(256), 0, stream,
                       xn_h, xn_l, sawin_h, sawin_l, sa_in_b, q_h, q_l, NTOK, 1536, 512);
    hipLaunchKernelGGL(sa_mfma_kernel, dim3(16, HEADS, BB), dim3(256), 0, stream,
                       q_h, q_l, obuf_h, obuf_l);
    mg(obuf_h, obuf_l, sawout_h, sawout_l, sa_out_b, x_flat, x_flat, nullptr, nullptr,
       NTOK, 512, 512, 0, 0, 0, 512, 1, 1);

    // ---- LN2 + cross-attention (split MFMA) ----
    hipLaunchKernelGGL(ln_kernel, dim3(NTOK), dim3(256), 0, stream, x_flat, ln2g, ln2b,
                       (float*)nullptr, xn_h, xn_l);
    mg(xn_h, xn_l, caw_h, caw_l, ca_in_b, nullptr, nullptr, ca_qh, ca_ql,
       NTOK, 512, 512, 0, 0, 0, 512, 1, 1);
    mg(text_h, text_l, caw_h + 512 * 512, caw_l + 512 * 512, ca_in_b + 512, nullptr, nullptr,
       kvt_h, kvt_l, BB * TXT, 1024, 512, 0, 0, 0, 1024, 1, 1);
    hipLaunchKernelGGL(ca_mfma_kernel, dim3(16, HEADS, BB), dim3(256), 0, stream,
                       ca_qh, ca_ql, kvt_h, kvt_l, obuf_h, obuf_l);
    // expert weight transposes (qkv region dead after ca_mfma) — one fused launch
    hipLaunchKernelGGL(tr2x_kernel, dim3(64, 16, 16), dim3(256), 0, stream,
                       e_w1, e1T, e_w2, e2T);
    mg(obuf_h, obuf_l, cawout_h, cawout_l, ca_out_b, x_flat, x_flat, nullptr, nullptr,
       NTOK, 512, 512, 0, 0, 0, 512, 1, 1);

    // ---- LN3 + router (feat via split MFMA) ----
    hipLaunchKernelGGL(ln_kernel, dim3(NTOK), dim3(256), 0, stream, x_flat, ln3g, ln3b,
                       (float*)nullptr, xn_h, xn_l);
    mg(xn_h, xn_l, rfT_h, rfT_l, nullptr, nullptr, feat, nullptr, nullptr,
       NTOK, 128, 512, 0, 0, 0, 128, 1, 1);
    hipLaunchKernelGGL(textpart_kernel, dim3(1), dim3(256), 0, stream, w, r_text, r_comb, tp, cnt);
    hipLaunchKernelGGL(route_kernel, dim3(18), dim3(256), 0, stream,
                       feat, tp, r_comb, r_temp, onehot, idx, cnt, perm);
    hipLaunchKernelGGL(offscatter_kernel, dim3(1), dim3(256), 0, stream,
                       cnt, idx, ntiles, table, perm);

    // ---- MoE grouped MFMA GEMMs (64x128 tiles, depth-2 prefetch) ----
    hipLaunchKernelGGL(moe128_1_kernel, dim3(HIDC / 128, MAXT), dim3(256), 0, stream,
                       xn_h, e1T, e_b1, table, ntiles, perm, hid_b);
    hipLaunchKernelGGL(moe128_2_kernel, dim3(DIMC / 128, MAXT), dim3(256), 0, stream,
                       hid_b, e2T, e_b2, table, ntiles, perm, x_flat, xfl_h, xfl_l);

    // ---- modconv out (weights already prepared) ----
    mg(wtC_h, wtC_l, xfl_h, xfl_l, nullptr, nullptr, out, nullptr, nullptr,
       DIMC, HWX, DIMC, (long)DIMC * DIMC, (long)HWX * DIMC, (long)DIMC * HWX, HWX, 1, BB);
}

// Round 22
// 440.940 us; speedup vs baseline: 1.6334x; 1.0492x over previous
//
#include <hip/hip_runtime.h>
#include <hip/hip_bf16.h>
#include <math.h>

#define DIMC 512
#define HEADS 8
#define HD 64
#define BB 4
#define HWX 1024
#define TXT 77
#define LATC 512
#define NE 8
#define HIDC 2048
#define NTOK 4096
#define MAXT 72           // MoE tiles of 64: 4096/64 + 8

typedef __attribute__((ext_vector_type(8))) short bf16x8;
typedef __attribute__((ext_vector_type(4))) float f32x4;
typedef __hip_bfloat16 bf16;

__device__ __forceinline__ void split2(float v, bf16& h, bf16& l) {
    h = __float2bfloat16(v);
    l = __float2bfloat16(v - __bfloat162float(h));
}
__device__ __forceinline__ void split2s(float v, short& h, short& l) {
    bf16 hb, lb; split2(v, hb, lb);
    h = *(short*)&hb; l = *(short*)&lb;
}

// ---------------- both styles in one launch: job 0 = in, job 1 = out ----------------
__global__ void style2_kernel(const float* __restrict__ w,
                              const float* __restrict__ mwA, const float* __restrict__ mbA,
                              const float* __restrict__ mwB, const float* __restrict__ mbB,
                              float* __restrict__ sA, float* __restrict__ sB) {
    int g = blockIdx.x * blockDim.x + threadIdx.x;
    int job = (g >= BB * DIMC) ? 1 : 0;
    int t = g - job * BB * DIMC;
    if (t >= BB * DIMC) return;
    const float* mw = job ? mwB : mwA;
    const float* mb = job ? mbB : mbA;
    float* st = job ? sB : sA;
    int b = t / DIMC, i = t % DIMC;
    const float* wr = w + (long)b * LATC;
    const float* mr = mw + (long)i * LATC;
    float s = 0.f;
    #pragma unroll 8
    for (int l = 0; l < LATC; l++) s += wr[l] * mr[l];
    st[t] = s + mb[i];
}

// ------- both wtmods in one launch -------
__global__ void wtmod2_kernel(const float* __restrict__ wA, const float* __restrict__ sA,
                              const float* __restrict__ wB, const float* __restrict__ sB,
                              bf16* __restrict__ whA, bf16* __restrict__ wlA,
                              bf16* __restrict__ whB, bf16* __restrict__ wlB) {
    int gb = blockIdx.x;
    int job = (gb >= BB * DIMC) ? 1 : 0;
    int bo = gb - job * BB * DIMC;
    const float* weight = job ? wB : wA;
    const float* style  = job ? sB : sA;
    bf16* wh = job ? whB : whA;
    bf16* wl = job ? wlB : wlA;
    int b = bo / DIMC, o = bo % DIMC;
    const float* wr = weight + (long)o * DIMC;
    const float* sr = style + (long)b * DIMC;
    int t = threadIdx.x;
    float vals[2]; float part = 0.f;
    for (int j = 0; j < 2; j++) {
        int i = t + j * 256;
        float v = wr[i] * sr[i];
        vals[j] = v; part += v * v;
    }
    __shared__ float red[256];
    red[t] = part; __syncthreads();
    for (int s = 128; s > 0; s >>= 1) { if (t < s) red[t] += red[t + s]; __syncthreads(); }
    float d = rsqrtf(red[0] + 1e-8f);
    for (int j = 0; j < 2; j++) {
        int i = t + j * 256;
        bf16 h, l; split2(vals[j] * d, h, l);
        wh[(long)bo * DIMC + i] = h; wl[(long)bo * DIMC + i] = l;
    }
}

// ---------------- fused segmented fp32 -> bf16 hi/lo convert (5 weight arrays) ----------------
__global__ void cvtall_kernel(
    const float* __restrict__ s0, bf16* __restrict__ h0, bf16* __restrict__ l0, int n0,
    const float* __restrict__ s1, bf16* __restrict__ h1, bf16* __restrict__ l1, int n1,
    const float* __restrict__ s2, bf16* __restrict__ h2, bf16* __restrict__ l2, int n2,
    const float* __restrict__ s3, bf16* __restrict__ h3, bf16* __restrict__ l3, int n3,
    const float* __restrict__ s4, bf16* __restrict__ h4, bf16* __restrict__ l4, int n4) {
    int i = (blockIdx.x * blockDim.x + threadIdx.x) * 4;
    const float* src; bf16 *hh, *ll;
    if (i < n0) { src = s0; hh = h0; ll = l0; }
    else if ((i -= n0) < n1) { src = s1; hh = h1; ll = l1; }
    else if ((i -= n1) < n2) { src = s2; hh = h2; ll = l2; }
    else if ((i -= n2) < n3) { src = s3; hh = h3; ll = l3; }
    else if ((i -= n3) < n4) { src = s4; hh = h4; ll = l4; }
    else return;
    float4 v = *(const float4*)(src + i);
    float a[4] = {v.x, v.y, v.z, v.w};
    #pragma unroll
    for (int j = 0; j < 4; j++) { bf16 h, l; split2(a[j], h, l); hh[i + j] = h; ll[i + j] = l; }
}

// ---- fused transpose hi/lo: z<4 -> x slice (512x1024), z==4 -> r_feat (512x128) ----
__global__ void trcvt2x_kernel(const float* __restrict__ x, bf16* __restrict__ xh,
                               bf16* __restrict__ xl, const float* __restrict__ rf,
                               bf16* __restrict__ rfh, bf16* __restrict__ rfl) {
    __shared__ float tile[32][33];
    int z = blockIdx.z;
    const float* in; bf16 *hi, *lo; int R, C;
    if (z < 4) {
        in = x + (long)z * 512 * 1024;
        hi = xh + (long)z * 1024 * 512; lo = xl + (long)z * 1024 * 512;
        R = 512; C = 1024;
    } else {
        if (blockIdx.x >= 4) return;
        in = rf; hi = rfh; lo = rfl;
        R = 512; C = 128;
    }
    int c0 = blockIdx.x * 32, r0 = blockIdx.y * 32;
    int tc = threadIdx.x & 31, tr = threadIdx.x >> 5;
    #pragma unroll
    for (int i = 0; i < 4; i++) {
        int r = tr + i * 8;
        tile[r][tc] = in[(long)(r0 + r) * C + c0 + tc];
    }
    __syncthreads();
    #pragma unroll
    for (int i = 0; i < 4; i++) {
        int r = tr + i * 8;
        bf16 h, l; split2(tile[tc][r], h, l);
        hi[(long)(c0 + r) * R + r0 + tc] = h;
        lo[(long)(c0 + r) * R + r0 + tc] = l;
    }
}

// ---- fused expert-weight transposes: z<8 -> e_w1[z] (512x2048), z>=8 -> e_w2[z-8] (2048x512) ----
__global__ void tr2x_kernel(const float* __restrict__ w1, bf16* __restrict__ e1T,
                            const float* __restrict__ w2, bf16* __restrict__ e2T) {
    __shared__ float tile[32][33];
    int z = blockIdx.z;
    const float* in; bf16* out; int R, C, c0, r0;
    if (z < 8) {
        in = w1 + (long)z * 512 * 2048;  out = e1T + (long)z * 2048 * 512;
        R = 512; C = 2048;
        c0 = blockIdx.x * 32; r0 = blockIdx.y * 32;       // grid x=64, y=16
    } else {
        in = w2 + (long)(z - 8) * 2048 * 512;  out = e2T + (long)(z - 8) * 512 * 2048;
        R = 2048; C = 512;
        int lin = blockIdx.y * 64 + blockIdx.x;           // 0..1023 -> (16 x, 64 y)
        c0 = (lin & 15) * 32; r0 = (lin >> 4) * 32;
    }
    int tc = threadIdx.x & 31, tr = threadIdx.x >> 5;
    #pragma unroll
    for (int i = 0; i < 4; i++) {
        int r = tr + i * 8;
        tile[r][tc] = in[(long)(r0 + r) * C + c0 + tc];
    }
    __syncthreads();
    #pragma unroll
    for (int i = 0; i < 4; i++) {
        int r = tr + i * 8;
        out[(long)(c0 + r) * R + r0 + tc] = __float2bfloat16(tile[tc][r]);
    }
}

// ---- split-precision bf16 MFMA GEMM, 64x64 tile, depth-2 prefetch (K % 64 == 0) ----
__global__ __launch_bounds__(256) void mgemm64_kernel(
    const bf16* __restrict__ Ah, const bf16* __restrict__ Al,
    const bf16* __restrict__ Bh, const bf16* __restrict__ Bl,
    const float* __restrict__ bias, const float* __restrict__ resid, float* __restrict__ C,
    bf16* __restrict__ Oh, bf16* __restrict__ Ol,
    int M, int N, int K, long a_bat, long b_bat, long c_bat, int cs_m, int cs_n) {
    __shared__ short AsH[2 * 2048];
    __shared__ short AsL[2 * 2048];
    __shared__ short BsH[2 * 2048];
    __shared__ short BsL[2 * 2048];
    int bat = blockIdx.z;
    const short* AbH = (const short*)(Ah + (long)bat * a_bat);
    const short* AbL = (const short*)(Al + (long)bat * a_bat);
    const short* BbH = (const short*)(Bh + (long)bat * b_bat);
    const short* BbL = (const short*)(Bl + (long)bat * b_bat);
    float* Cb = C + (long)bat * c_bat;
    const float* Rb = resid ? resid + (long)bat * c_bat : nullptr;
    int bm = blockIdx.y * 64, bn = blockIdx.x * 64;
    int t = threadIdx.x, lane = t & 63, w = t >> 6;
    int wm = (w >> 1) * 32, wn = (w & 1) * 32;
    int r0 = t >> 2, k0s = (t & 3) ^ ((r0 >> 1) & 3);
    int ar0 = bm + r0; if (ar0 > M - 1) ar0 = M - 1;
    long aoff = (long)ar0 * K + k0s * 8;
    long boff = (long)(bn + r0) * K + k0s * 8;
    int fr = lane & 15, fq = lane >> 4;
    int aOff[2], bOff[2];
    #pragma unroll
    for (int i = 0; i < 2; i++) {
        int row = wm + i * 16 + fr;
        aOff[i] = row * 32 + ((fq ^ ((row >> 1) & 3)) * 8);
        int col = wn + i * 16 + fr;
        bOff[i] = col * 32 + ((fq ^ ((col >> 1) & 3)) * 8);
    }
    f32x4 acc[2][2] = {};
    bf16x8 vah0 = *(const bf16x8*)(AbH + aoff);
    bf16x8 val0 = *(const bf16x8*)(AbL + aoff);
    bf16x8 vbh0 = *(const bf16x8*)(BbH + boff);
    bf16x8 vbl0 = *(const bf16x8*)(BbL + boff);
    bf16x8 vah1 = *(const bf16x8*)(AbH + aoff + 32);
    bf16x8 val1 = *(const bf16x8*)(AbL + aoff + 32);
    bf16x8 vbh1 = *(const bf16x8*)(BbH + boff + 32);
    bf16x8 vbl1 = *(const bf16x8*)(BbL + boff + 32);
    for (int kk = 0; kk < K; kk += 64) {
        // ---- step 0: buffer 0, tile kk ----
        *(bf16x8*)&AsH[t * 8] = vah0;
        *(bf16x8*)&AsL[t * 8] = val0;
        *(bf16x8*)&BsH[t * 8] = vbh0;
        *(bf16x8*)&BsL[t * 8] = vbl0;
        __syncthreads();
        {
            int kn = (kk + 64 < K) ? kk + 64 : kk;
            vah0 = *(const bf16x8*)(AbH + aoff + kn);
            val0 = *(const bf16x8*)(AbL + aoff + kn);
            vbh0 = *(const bf16x8*)(BbH + boff + kn);
            vbl0 = *(const bf16x8*)(BbL + boff + kn);
        }
        {
            bf16x8 aH[2], aL[2], bH[2], bL[2];
            #pragma unroll
            for (int i = 0; i < 2; i++) {
                aH[i] = *(const bf16x8*)&AsH[aOff[i]];
                aL[i] = *(const bf16x8*)&AsL[aOff[i]];
                bH[i] = *(const bf16x8*)&BsH[bOff[i]];
                bL[i] = *(const bf16x8*)&BsL[bOff[i]];
            }
            #pragma unroll
            for (int i = 0; i < 2; i++)
            #pragma unroll
            for (int j = 0; j < 2; j++) {
                acc[i][j] = __builtin_amdgcn_mfma_f32_16x16x32_bf16(aH[i], bH[j], acc[i][j], 0, 0, 0);
                acc[i][j] = __builtin_amdgcn_mfma_f32_16x16x32_bf16(aH[i], bL[j], acc[i][j], 0, 0, 0);
                acc[i][j] = __builtin_amdgcn_mfma_f32_16x16x32_bf16(aL[i], bH[j], acc[i][j], 0, 0, 0);
            }
        }
        // ---- step 1: buffer 1, tile kk+32 ----
        *(bf16x8*)&AsH[2048 + t * 8] = vah1;
        *(bf16x8*)&AsL[2048 + t * 8] = val1;
        *(bf16x8*)&BsH[2048 + t * 8] = vbh1;
        *(bf16x8*)&BsL[2048 + t * 8] = vbl1;
        __syncthreads();
        {
            int kn = (kk + 96 < K) ? kk + 96 : kk + 32;
            vah1 = *(const bf16x8*)(AbH + aoff + kn);
            val1 = *(const bf16x8*)(AbL + aoff + kn);
            vbh1 = *(const bf16x8*)(BbH + boff + kn);
            vbl1 = *(const bf16x8*)(BbL + boff + kn);
        }
        {
            bf16x8 aH[2], aL[2], bH[2], bL[2];
            #pragma unroll
            for (int i = 0; i < 2; i++) {
                aH[i] = *(const bf16x8*)&AsH[2048 + aOff[i]];
                aL[i] = *(const bf16x8*)&AsL[2048 + aOff[i]];
                bH[i] = *(const bf16x8*)&BsH[2048 + bOff[i]];
                bL[i] = *(const bf16x8*)&BsL[2048 + bOff[i]];
            }
            #pragma unroll
            for (int i = 0; i < 2; i++)
            #pragma unroll
            for (int j = 0; j < 2; j++) {
                acc[i][j] = __builtin_amdgcn_mfma_f32_16x16x32_bf16(aH[i], bH[j], acc[i][j], 0, 0, 0);
                acc[i][j] = __builtin_amdgcn_mfma_f32_16x16x32_bf16(aH[i], bL[j], acc[i][j], 0, 0, 0);
                acc[i][j] = __builtin_amdgcn_mfma_f32_16x16x32_bf16(aL[i], bH[j], acc[i][j], 0, 0, 0);
            }
        }
    }
    #pragma unroll
    for (int i = 0; i < 2; i++)
    #pragma unroll
    for (int j = 0; j < 2; j++)
    #pragma unroll
    for (int r = 0; r < 4; r++) {
        int row = bm + wm + i * 16 + fq * 4 + r;
        int col = bn + wn + j * 16 + fr;
        if (row < M) {
            long off = (long)row * cs_m + (long)col * cs_n;
            float v = acc[i][j][r];
            if (bias) v += bias[col];
            if (Oh) {
                bf16 hh, ll; split2(v, hh, ll);
                Oh[off] = hh; Ol[off] = ll;
            } else {
                if (Rb) v += Rb[off];
                Cb[off] = v;
            }
        }
    }
}

// ---- split-precision bf16 MFMA GEMM, 128x64 tile, depth-2 prefetch (qkv GEMM) ----
__global__ __launch_bounds__(256) void mgemm128x64_kernel(
    const bf16* __restrict__ Ah, const bf16* __restrict__ Al,
    const bf16* __restrict__ Bh, const bf16* __restrict__ Bl,
    const float* __restrict__ bias, bf16* __restrict__ Oh, bf16* __restrict__ Ol,
    int M, int N, int K) {
    __shared__ short AsH[2 * 4096];
    __shared__ short AsL[2 * 4096];
    __shared__ short BsH[2 * 2048];
    __shared__ short BsL[2 * 2048];
    const short* AbH = (const short*)Ah;
    const short* AbL = (const short*)Al;
    const short* BbH = (const short*)Bh;
    const short* BbL = (const short*)Bl;
    int bm = blockIdx.y * 128, bn = blockIdx.x * 64;
    int t = threadIdx.x, lane = t & 63, w = t >> 6;
    int wm = (w >> 1) * 64, wn = (w & 1) * 32;
    int p0 = t, p1 = t + 256;
    int ra0 = p0 >> 2, ka0 = (p0 & 3) ^ ((ra0 >> 1) & 3);
    int ra1 = p1 >> 2, ka1 = (p1 & 3) ^ ((ra1 >> 1) & 3);
    int arow0 = bm + ra0; if (arow0 > M - 1) arow0 = M - 1;
    int arow1 = bm + ra1; if (arow1 > M - 1) arow1 = M - 1;
    long aoff0 = (long)arow0 * K + ka0 * 8;
    long aoff1 = (long)arow1 * K + ka1 * 8;
    int rb = t >> 2, kb2 = (t & 3) ^ ((rb >> 1) & 3);
    long boff = (long)(bn + rb) * K + kb2 * 8;
    int fr = lane & 15, fq = lane >> 4;
    int aOff[4], bOff[2];
    #pragma unroll
    for (int i = 0; i < 4; i++) {
        int row = wm + i * 16 + fr;
        aOff[i] = row * 32 + ((fq ^ ((row >> 1) & 3)) * 8);
    }
    #pragma unroll
    for (int j = 0; j < 2; j++) {
        int col = wn + j * 16 + fr;
        bOff[j] = col * 32 + ((fq ^ ((col >> 1) & 3)) * 8);
    }
    f32x4 acc[4][2] = {};
    bf16x8 sA0h0 = *(const bf16x8*)(AbH + aoff0);
    bf16x8 sA1h0 = *(const bf16x8*)(AbH + aoff1);
    bf16x8 sA0l0 = *(const bf16x8*)(AbL + aoff0);
    bf16x8 sA1l0 = *(const bf16x8*)(AbL + aoff1);
    bf16x8 sBh0  = *(const bf16x8*)(BbH + boff);
    bf16x8 sBl0  = *(const bf16x8*)(BbL + boff);
    bf16x8 sA0h1 = *(const bf16x8*)(AbH + aoff0 + 32);
    bf16x8 sA1h1 = *(const bf16x8*)(AbH + aoff1 + 32);
    bf16x8 sA0l1 = *(const bf16x8*)(AbL + aoff0 + 32);
    bf16x8 sA1l1 = *(const bf16x8*)(AbL + aoff1 + 32);
    bf16x8 sBh1  = *(const bf16x8*)(BbH + boff + 32);
    bf16x8 sBl1  = *(const bf16x8*)(BbL + boff + 32);
    for (int kk = 0; kk < K; kk += 64) {
        // ---- step 0 ----
        *(bf16x8*)&AsH[p0 * 8] = sA0h0;  *(bf16x8*)&AsH[p1 * 8] = sA1h0;
        *(bf16x8*)&AsL[p0 * 8] = sA0l0;  *(bf16x8*)&AsL[p1 * 8] = sA1l0;
        *(bf16x8*)&BsH[t * 8] = sBh0;
        *(bf16x8*)&BsL[t * 8] = sBl0;
        __syncthreads();
        {
            int kn = (kk + 64 < K) ? kk + 64 : kk;
            sA0h0 = *(const bf16x8*)(AbH + aoff0 + kn);
            sA1h0 = *(const bf16x8*)(AbH + aoff1 + kn);
            sA0l0 = *(const bf16x8*)(AbL + aoff0 + kn);
            sA1l0 = *(const bf16x8*)(AbL + aoff1 + kn);
            sBh0  = *(const bf16x8*)(BbH + boff + kn);
            sBl0  = *(const bf16x8*)(BbL + boff + kn);
        }
        {
            bf16x8 aH[4], aL[4], bH[2], bL[2];
            #pragma unroll
            for (int i = 0; i < 4; i++) {
                aH[i] = *(const bf16x8*)&AsH[aOff[i]];
                aL[i] = *(const bf16x8*)&AsL[aOff[i]];
            }
            #pragma unroll
            for (int j = 0; j < 2; j++) {
                bH[j] = *(const bf16x8*)&BsH[bOff[j]];
                bL[j] = *(const bf16x8*)&BsL[bOff[j]];
            }
            #pragma unroll
            for (int i = 0; i < 4; i++)
            #pragma unroll
            for (int j = 0; j < 2; j++) {
                acc[i][j] = __builtin_amdgcn_mfma_f32_16x16x32_bf16(aH[i], bH[j], acc[i][j], 0, 0, 0);
                acc[i][j] = __builtin_amdgcn_mfma_f32_16x16x32_bf16(aH[i], bL[j], acc[i][j], 0, 0, 0);
                acc[i][j] = __builtin_amdgcn_mfma_f32_16x16x32_bf16(aL[i], bH[j], acc[i][j], 0, 0, 0);
            }
        }
        // ---- step 1 ----
        *(bf16x8*)&AsH[4096 + p0 * 8] = sA0h1;  *(bf16x8*)&AsH[4096 + p1 * 8] = sA1h1;
        *(bf16x8*)&AsL[4096 + p0 * 8] = sA0l1;  *(bf16x8*)&AsL[4096 + p1 * 8] = sA1l1;
        *(bf16x8*)&BsH[2048 + t * 8] = sBh1;
        *(bf16x8*)&BsL[2048 + t * 8] = sBl1;
        __syncthreads();
        {
            int kn = (kk + 96 < K) ? kk + 96 : kk + 32;
            sA0h1 = *(const bf16x8*)(AbH + aoff0 + kn);
            sA1h1 = *(const bf16x8*)(AbH + aoff1 + kn);
            sA0l1 = *(const bf16x8*)(AbL + aoff0 + kn);
            sA1l1 = *(const bf16x8*)(AbL + aoff1 + kn);
            sBh1  = *(const bf16x8*)(BbH + boff + kn);
            sBl1  = *(const bf16x8*)(BbL + boff + kn);
        }
        {
            bf16x8 aH[4], aL[4], bH[2], bL[2];
            #pragma unroll
            for (int i = 0; i < 4; i++) {
                aH[i] = *(const bf16x8*)&AsH[4096 + aOff[i]];
                aL[i] = *(const bf16x8*)&AsL[4096 + aOff[i]];
            }
            #pragma unroll
            for (int j = 0; j < 2; j++) {
                bH[j] = *(const bf16x8*)&BsH[2048 + bOff[j]];
                bL[j] = *(const bf16x8*)&BsL[2048 + bOff[j]];
            }
            #pragma unroll
            for (int i = 0; i < 4; i++)
            #pragma unroll
            for (int j = 0; j < 2; j++) {
                acc[i][j] = __builtin_amdgcn_mfma_f32_16x16x32_bf16(aH[i], bH[j], acc[i][j], 0, 0, 0);
                acc[i][j] = __builtin_amdgcn_mfma_f32_16x16x32_bf16(aH[i], bL[j], acc[i][j], 0, 0, 0);
                acc[i][j] = __builtin_amdgcn_mfma_f32_16x16x32_bf16(aL[i], bH[j], acc[i][j], 0, 0, 0);
            }
        }
    }
    #pragma unroll
    for (int i = 0; i < 4; i++)
    #pragma unroll
    for (int j = 0; j < 2; j++)
    #pragma unroll
    for (int r = 0; r < 4; r++) {
        int row = bm + wm + i * 16 + fq * 4 + r;
        int col = bn + wn + j * 16 + fr;
        if (row < M) {
            long off = (long)row * N + col;
            float v = acc[i][j][r] + bias[col];
            bf16 hh, ll; split2(v, hh, ll);
            Oh[off] = hh; Ol[off] = ll;
        }
    }
}

// ---- split-precision MFMA flash SA: no-max softmax, single-bf16 P, V stride 72 ----
__global__ __launch_bounds__(256) void sa_mfma_kernel(
    const bf16* __restrict__ qh, const bf16* __restrict__ ql,
    bf16* __restrict__ oh, bf16* __restrict__ ol) {
    int qt = blockIdx.x, h = blockIdx.y, b = blockIdx.z;
    __shared__ short KsH[4096], KsL[4096];       // [kv][64], swz: col ^ ((kv&7)<<3)
    __shared__ short VtH[4608], VtL[4608];       // [d][72], swz: col ^ (((d>>3)&7)<<3)
    __shared__ short PHs[4][1024];               // per-wave P (single bf16)
    int t = threadIdx.x, lane = t & 63, w = t >> 6;
    int fr = lane & 15, fq = lane >> 4;
    const short* QH = (const short*)qh;
    const short* QL = (const short*)ql;
    long qrow = (long)(b * 1024 + qt * 64 + w * 16 + fr) * 1536 + h * 64;
    bf16x8 Qh2[2], Ql2[2];
    Qh2[0] = *(const bf16x8*)(QH + qrow + fq * 8);
    Qh2[1] = *(const bf16x8*)(QH + qrow + 32 + fq * 8);
    Ql2[0] = *(const bf16x8*)(QL + qrow + fq * 8);
    Ql2[1] = *(const bf16x8*)(QL + qrow + 32 + fq * 8);
    float l_i[4] = {0.f, 0.f, 0.f, 0.f};
    f32x4 o_acc[4] = {};
    int c0 = t, c1 = t + 256;
    int r0 = c0 >> 3, g0 = c0 & 7;               // r0 in 0..31
    int r1 = c1 >> 3, g1 = c1 & 7;               // r1 in 32..63
    int kd0 = r0 * 64 + ((g0 * 8) ^ ((r0 & 7) << 3));
    int kd1 = r1 * 64 + ((g1 * 8) ^ ((r1 & 7) << 3));
    long kb = (long)(b * 1024) * 1536 + 512 + h * 64;
    long vb = kb + 512;
    long lo0 = (long)r0 * 1536 + g0 * 8, lo1 = (long)r1 * 1536 + g1 * 8;
    short* ph = PHs[w];
    bf16x8 kh0 = *(const bf16x8*)(QH + kb + lo0);
    bf16x8 kh1 = *(const bf16x8*)(QH + kb + lo1);
    bf16x8 kl0 = *(const bf16x8*)(QL + kb + lo0);
    bf16x8 kl1 = *(const bf16x8*)(QL + kb + lo1);
    bf16x8 vh0 = *(const bf16x8*)(QH + vb + lo0);
    bf16x8 vh1 = *(const bf16x8*)(QH + vb + lo1);
    bf16x8 vl0 = *(const bf16x8*)(QL + vb + lo0);
    bf16x8 vl1 = *(const bf16x8*)(QL + vb + lo1);
    for (int kt = 0; kt < 16; kt++) {
        __syncthreads();          // A: all waves finished reading Ks/Vt of prev iter
        *(bf16x8*)&KsH[kd0] = kh0;  *(bf16x8*)&KsH[kd1] = kh1;
        *(bf16x8*)&KsL[kd0] = kl0;  *(bf16x8*)&KsL[kd1] = kl1;
        #pragma unroll
        for (int j = 0; j < 8; j++) {
            int d0 = g0 * 8 + j;
            int i0 = d0 * 72 + (r0 ^ (g0 << 3));
            VtH[i0] = ((short*)&vh0)[j];  VtL[i0] = ((short*)&vl0)[j];
            int d1 = g1 * 8 + j;
            int i1 = d1 * 72 + (r1 ^ (g1 << 3));
            VtH[i1] = ((short*)&vh1)[j];  VtL[i1] = ((short*)&vl1)[j];
        }
        __syncthreads();          // B: staging visible
        int ktn = (kt + 1 < 16) ? kt + 1 : kt;
        long ko = kb + (long)(ktn * 64) * 1536;
        long vo = vb + (long)(ktn * 64) * 1536;
        bf16x8 nkh0 = *(const bf16x8*)(QH + ko + lo0);
        bf16x8 nkh1 = *(const bf16x8*)(QH + ko + lo1);
        bf16x8 nkl0 = *(const bf16x8*)(QL + ko + lo0);
        bf16x8 nkl1 = *(const bf16x8*)(QL + ko + lo1);
        bf16x8 nvh0 = *(const bf16x8*)(QH + vo + lo0);
        bf16x8 nvh1 = *(const bf16x8*)(QH + vo + lo1);
        bf16x8 nvl0 = *(const bf16x8*)(QL + vo + lo0);
        bf16x8 nvl1 = *(const bf16x8*)(QL + vo + lo1);
        __builtin_amdgcn_s_setprio(1);
        f32x4 s[4] = {};
        #pragma unroll
        for (int cf = 0; cf < 4; cf++) {
            int kvrow = cf * 16 + fr;
            #pragma unroll
            for (int kf = 0; kf < 2; kf++) {
                int idx = kvrow * 64 + ((kf * 32 + fq * 8) ^ ((kvrow & 7) << 3));
                bf16x8 Bh2 = *(const bf16x8*)&KsH[idx];
                bf16x8 Bl2 = *(const bf16x8*)&KsL[idx];
                s[cf] = __builtin_amdgcn_mfma_f32_16x16x32_bf16(Qh2[kf], Bh2, s[cf], 0, 0, 0);
                s[cf] = __builtin_amdgcn_mfma_f32_16x16x32_bf16(Qh2[kf], Bl2, s[cf], 0, 0, 0);
                s[cf] = __builtin_amdgcn_mfma_f32_16x16x32_bf16(Ql2[kf], Bh2, s[cf], 0, 0, 0);
            }
        }
        __builtin_amdgcn_s_setprio(0);
        #pragma unroll
        for (int cf = 0; cf < 4; cf++)
        #pragma unroll
        for (int reg = 0; reg < 4; reg++) {
            float e = __expf(s[cf][reg] * 0.125f);
            bf16 eb = __float2bfloat16(e);
            l_i[reg] += __bfloat162float(eb);
            int q = fq * 4 + reg, kv = cf * 16 + fr;
            int idx = q * 64 + (kv ^ ((q & 7) << 3));
            ph[idx] = *(short*)&eb;
        }
        asm volatile("s_waitcnt lgkmcnt(0)" ::: "memory");
        __builtin_amdgcn_sched_barrier(0);
        __builtin_amdgcn_s_setprio(1);
        bf16x8 Pf_h[2];
        #pragma unroll
        for (int kf = 0; kf < 2; kf++) {
            int idx = fr * 64 + ((kf * 32 + fq * 8) ^ ((fr & 7) << 3));
            Pf_h[kf] = *(const bf16x8*)&ph[idx];
        }
        #pragma unroll
        for (int cf = 0; cf < 4; cf++) {
            int d = cf * 16 + fr;
            #pragma unroll
            for (int kf = 0; kf < 2; kf++) {
                int idx = d * 72 + ((kf * 32 + fq * 8) ^ (((d >> 3) & 7) << 3));
                bf16x8 Vh2 = *(const bf16x8*)&VtH[idx];
                bf16x8 Vl2 = *(const bf16x8*)&VtL[idx];
                o_acc[cf] = __builtin_amdgcn_mfma_f32_16x16x32_bf16(Pf_h[kf], Vh2, o_acc[cf], 0, 0, 0);
                o_acc[cf] = __builtin_amdgcn_mfma_f32_16x16x32_bf16(Pf_h[kf], Vl2, o_acc[cf], 0, 0, 0);
            }
        }
        __builtin_amdgcn_s_setprio(0);
        kh0 = nkh0; kh1 = nkh1; kl0 = nkl0; kl1 = nkl1;
        vh0 = nvh0; vh1 = nvh1; vl0 = nvl0; vl1 = nvl1;
    }
    #pragma unroll
    for (int reg = 0; reg < 4; reg++) {
        float rs = l_i[reg];
        rs += __shfl_xor(rs, 1);
        rs += __shfl_xor(rs, 2);
        rs += __shfl_xor(rs, 4);
        rs += __shfl_xor(rs, 8);
        float inv = 1.f / rs;
        long m = (long)(b * 1024 + qt * 64 + w * 16 + fq * 4 + reg);
        #pragma unroll
        for (int cf = 0; cf < 4; cf++) {
            float v = o_acc[cf][reg] * inv;
            bf16 hh, ll; split2(v, hh, ll);
            long off = m * DIMC + h * 64 + cf * 16 + fr;
            oh[off] = hh; ol[off] = ll;
        }
    }
}

// ---- split-precision MFMA cross-attention: 77 keys padded to 96, single-bf16 P ----
__global__ __launch_bounds__(256) void ca_mfma_kernel(
    const bf16* __restrict__ qh, const bf16* __restrict__ ql,
    const bf16* __restrict__ kvh, const bf16* __restrict__ kvl,
    bf16* __restrict__ oh, bf16* __restrict__ ol) {
    int qt = blockIdx.x, h = blockIdx.y, b = blockIdx.z;
    __shared__ short UH[8192], UL[8192];
    __shared__ short PHs[4][2048];
    int t = threadIdx.x, lane = t & 63, w = t >> 6;
    int fr = lane & 15, fq = lane >> 4;
    const short* QH = (const short*)qh;
    const short* QL = (const short*)ql;
    const short* KVH = (const short*)kvh;
    const short* KVL = (const short*)kvl;
    long qrow = (long)(b * 1024 + qt * 64 + w * 16 + fr) * DIMC + h * 64;
    bf16x8 Qh2[2], Ql2[2];
    Qh2[0] = *(const bf16x8*)(QH + qrow + fq * 8);
    Qh2[1] = *(const bf16x8*)(QH + qrow + 32 + fq * 8);
    Ql2[0] = *(const bf16x8*)(QL + qrow + fq * 8);
    Ql2[1] = *(const bf16x8*)(QL + qrow + 32 + fq * 8);
    for (int c = t; c < 768; c += 256) {
        int r = c >> 3, g = c & 7;
        int idx = r * 64 + ((g * 8) ^ ((r & 7) << 3));
        bf16x8 vh = {}, vl = {};
        if (r < 77) {
            long src = (long)(b * 77 + r) * 1024 + h * 64 + g * 8;
            vh = *(const bf16x8*)(KVH + src);
            vl = *(const bf16x8*)(KVL + src);
        }
        *(bf16x8*)&UH[idx] = vh;
        *(bf16x8*)&UL[idx] = vl;
    }
    __syncthreads();
    f32x4 s[5] = {};
    #pragma unroll
    for (int cf = 0; cf < 5; cf++) {
        int kvrow = cf * 16 + fr;
        #pragma unroll
        for (int kf = 0; kf < 2; kf++) {
            int idx = kvrow * 64 + ((kf * 32 + fq * 8) ^ ((kvrow & 7) << 3));
            bf16x8 Bh2 = *(const bf16x8*)&UH[idx];
            bf16x8 Bl2 = *(const bf16x8*)&UL[idx];
            s[cf] = __builtin_amdgcn_mfma_f32_16x16x32_bf16(Qh2[kf], Bh2, s[cf], 0, 0, 0);
            s[cf] = __builtin_amdgcn_mfma_f32_16x16x32_bf16(Qh2[kf], Bl2, s[cf], 0, 0, 0);
            s[cf] = __builtin_amdgcn_mfma_f32_16x16x32_bf16(Ql2[kf], Bh2, s[cf], 0, 0, 0);
        }
    }
    float inv[4];
    #pragma unroll
    for (int reg = 0; reg < 4; reg++) {
        float rs = 0.f;
        #pragma unroll
        for (int cf = 0; cf < 5; cf++) {
            int kv = cf * 16 + fr;
            float e = (kv < 77) ? __expf(s[cf][reg] * 0.125f) : 0.f;
            s[cf][reg] = e;
            rs += e;
        }
        rs += __shfl_xor(rs, 1);
        rs += __shfl_xor(rs, 2);
        rs += __shfl_xor(rs, 4);
        rs += __shfl_xor(rs, 8);
        inv[reg] = 1.f / rs;
    }
    short* ph = PHs[w];
    #pragma unroll
    for (int cf = 0; cf < 6; cf++)
    #pragma unroll
    for (int reg = 0; reg < 4; reg++) {
        int q = fq * 4 + reg, kv = cf * 16 + fr;
        int idx = q * 128 + (kv ^ ((q & 7) << 3));
        float pv = (cf < 5) ? s[cf][reg] * inv[reg] : 0.f;
        bf16 pb = __float2bfloat16(pv);
        ph[idx] = *(short*)&pb;
    }
    __syncthreads();
    for (int c = t; c < 768; c += 256) {
        int r = c >> 3, g = c & 7;
        bf16x8 vh = {}, vl = {};
        if (r < 77) {
            long src = (long)(b * 77 + r) * 1024 + 512 + h * 64 + g * 8;
            vh = *(const bf16x8*)(KVH + src);
            vl = *(const bf16x8*)(KVL + src);
        }
        #pragma unroll
        for (int j = 0; j < 8; j++) {
            int d = g * 8 + j;
            int idx = d * 128 + (r ^ (((d >> 3) & 7) << 3));
            UH[idx] = ((short*)&vh)[j];
            UL[idx] = ((short*)&vl)[j];
        }
    }
    __syncthreads();
    f32x4 o_acc[4] = {};
    bf16x8 Pf_h[3];
    #pragma unroll
    for (int kf = 0; kf < 3; kf++) {
        int idx = fr * 128 + ((kf * 32 + fq * 8) ^ ((fr & 7) << 3));
        Pf_h[kf] = *(const bf16x8*)&ph[idx];
    }
    #pragma unroll
    for (int cf = 0; cf < 4; cf++) {
        int d = cf * 16 + fr;
        #pragma unroll
        for (int kf = 0; kf < 3; kf++) {
            int idx = d * 128 + ((kf * 32 + fq * 8) ^ (((d >> 3) & 7) << 3));
            bf16x8 Vh2 = *(const bf16x8*)&UH[idx];
            bf16x8 Vl2 = *(const bf16x8*)&UL[idx];
            o_acc[cf] = __builtin_amdgcn_mfma_f32_16x16x32_bf16(Pf_h[kf], Vh2, o_acc[cf], 0, 0, 0);
            o_acc[cf] = __builtin_amdgcn_mfma_f32_16x16x32_bf16(Pf_h[kf], Vl2, o_acc[cf], 0, 0, 0);
        }
    }
    #pragma unroll
    for (int reg = 0; reg < 4; reg++) {
        long m = (long)(b * 1024 + qt * 64 + w * 16 + fq * 4 + reg);
        #pragma unroll
        for (int cf = 0; cf < 4; cf++) {
            bf16 hh, ll; split2(o_acc[cf][reg], hh, ll);
            long off = m * DIMC + h * 64 + cf * 16 + fr;
            oh[off] = hh; ol[off] = ll;
        }
    }
}

// ---- MoE grouped MFMA GEMM1, 64x128 tile, depth-2 prefetch: hid = gelu(xn·w1 + b1) ----
__global__ __launch_bounds__(256) void moe128_1_kernel(
    const bf16* __restrict__ xn_b, const bf16* __restrict__ e1T, const float* __restrict__ e_b1,
    const int* __restrict__ table, const int* __restrict__ ntiles, const int* __restrict__ perm,
    bf16* __restrict__ hid_b) {
    if (blockIdx.y >= ntiles[0]) return;
    int e = table[2 * blockIdx.y], row0 = table[2 * blockIdx.y + 1];
    int bn = blockIdx.x * 128;
    __shared__ short As[2 * 2048];
    __shared__ short Bs[2 * 4096];
    __shared__ int rowsS[64];
    int t = threadIdx.x, lane = t & 63, w = t >> 6;
    if (t < 64) rowsS[t] = perm[row0 + t];
    __syncthreads();
    int wm = (w >> 1) * 32, wn = (w & 1) * 64;
    int ra = t >> 2, ka = (t & 3) ^ ((ra >> 1) & 3);
    int tok0 = rowsS[ra]; if (tok0 < 0) tok0 = 0;
    const short* Xs = (const short*)xn_b;
    const short* Ws = (const short*)(e1T + (long)e * HIDC * DIMC);
    const short* a0 = Xs + (long)tok0 * DIMC + ka * 8;
    int p0 = t, p1 = t + 256;
    int rb0 = p0 >> 2, kb0 = (p0 & 3) ^ ((rb0 >> 1) & 3);
    int rb1 = p1 >> 2, kb1 = (p1 & 3) ^ ((rb1 >> 1) & 3);
    const short* b0 = Ws + (long)(bn + rb0) * DIMC + kb0 * 8;
    const short* b1 = Ws + (long)(bn + rb1) * DIMC + kb1 * 8;
    int fr = lane & 15, fq = lane >> 4;
    int aOff[2], bOff[4];
    #pragma unroll
    for (int i = 0; i < 2; i++) {
        int row = wm + i * 16 + fr;
        aOff[i] = row * 32 + ((fq ^ ((row >> 1) & 3)) * 8);
    }
    #pragma unroll
    for (int j = 0; j < 4; j++) {
        int col = wn + j * 16 + fr;
        bOff[j] = col * 32 + ((fq ^ ((col >> 1) & 3)) * 8);
    }
    f32x4 acc[2][4] = {};
    bf16x8 va_0  = *(const bf16x8*)a0;
    bf16x8 vb0_0 = *(const bf16x8*)b0;
    bf16x8 vb1_0 = *(const bf16x8*)b1;
    bf16x8 va_1  = *(const bf16x8*)(a0 + 32);
    bf16x8 vb0_1 = *(const bf16x8*)(b0 + 32);
    bf16x8 vb1_1 = *(const bf16x8*)(b1 + 32);
    for (int kk = 0; kk < DIMC; kk += 64) {
        *(bf16x8*)&As[t * 8] = va_0;
        *(bf16x8*)&Bs[p0 * 8] = vb0_0;
        *(bf16x8*)&Bs[p1 * 8] = vb1_0;
        __syncthreads();
        {
            int kn = (kk + 64 < DIMC) ? kk + 64 : kk;
            va_0  = *(const bf16x8*)(a0 + kn);
            vb0_0 = *(const bf16x8*)(b0 + kn);
            vb1_0 = *(const bf16x8*)(b1 + kn);
        }
        {
            bf16x8 aF[2], bF[4];
            #pragma unroll
            for (int i = 0; i < 2; i++) aF[i] = *(const bf16x8*)&As[aOff[i]];
            #pragma unroll
            for (int j = 0; j < 4; j++) bF[j] = *(const bf16x8*)&Bs[bOff[j]];
            #pragma unroll
            for (int i = 0; i < 2; i++)
            #pragma unroll
            for (int j = 0; j < 4; j++)
                acc[i][j] = __builtin_amdgcn_mfma_f32_16x16x32_bf16(aF[i], bF[j], acc[i][j], 0, 0, 0);
        }
        *(bf16x8*)&As[2048 + t * 8] = va_1;
        *(bf16x8*)&Bs[4096 + p0 * 8] = vb0_1;
        *(bf16x8*)&Bs[4096 + p1 * 8] = vb1_1;
        __syncthreads();
        {
            int kn = (kk + 96 < DIMC) ? kk + 96 : kk + 32;
            va_1  = *(const bf16x8*)(a0 + kn);
            vb0_1 = *(const bf16x8*)(b0 + kn);
            vb1_1 = *(const bf16x8*)(b1 + kn);
        }
        {
            bf16x8 aF[2], bF[4];
            #pragma unroll
            for (int i = 0; i < 2; i++) aF[i] = *(const bf16x8*)&As[2048 + aOff[i]];
            #pragma unroll
            for (int j = 0; j < 4; j++) bF[j] = *(const bf16x8*)&Bs[4096 + bOff[j]];
            #pragma unroll
            for (int i = 0; i < 2; i++)
            #pragma unroll
            for (int j = 0; j < 4; j++)
                acc[i][j] = __builtin_amdgcn_mfma_f32_16x16x32_bf16(aF[i], bF[j], acc[i][j], 0, 0, 0);
        }
    }
    const float* bb = e_b1 + (long)e * HIDC;
    #pragma unroll
    for (int i = 0; i < 2; i++)
    #pragma unroll
    for (int r = 0; r < 4; r++) {
        int tok = rowsS[wm + i * 16 + fq * 4 + r];
        if (tok < 0) continue;
        #pragma unroll
        for (int j = 0; j < 4; j++) {
            int col = bn + wn + j * 16 + fr;
            float v = acc[i][j][r] + bb[col];
            v = 0.5f * v * (1.f + erff(v * 0.70710678f));
            hid_b[(long)tok * HIDC + col] = __float2bfloat16(v);
        }
    }
}

// ---- MoE grouped MFMA GEMM2, 64x64 tile (high grid fill), depth-2 prefetch ----
__global__ __launch_bounds__(256) void moe64_2_kernel(
    const bf16* __restrict__ hid_b, const bf16* __restrict__ e2T, const float* __restrict__ e_b2,
    const int* __restrict__ table, const int* __restrict__ ntiles, const int* __restrict__ perm,
    const float* __restrict__ resid, bf16* __restrict__ outh, bf16* __restrict__ outl) {
    if (blockIdx.y >= ntiles[0]) return;
    int e = table[2 * blockIdx.y], row0 = table[2 * blockIdx.y + 1];
    int bn = blockIdx.x * 64;
    __shared__ short As[2 * 2048];
    __shared__ short Bs[2 * 2048];
    __shared__ int rowsS[64];
    int t = threadIdx.x, lane = t & 63, w = t >> 6;
    if (t < 64) rowsS[t] = perm[row0 + t];
    __syncthreads();
    int wm = (w >> 1) * 32, wn = (w & 1) * 32;
    int r0 = t >> 2, k0s = (t & 3) ^ ((r0 >> 1) & 3);
    int tok0 = rowsS[r0]; if (tok0 < 0) tok0 = 0;
    const short* Hs = (const short*)hid_b;
    const short* Ws = (const short*)(e2T + (long)e * DIMC * HIDC);
    const short* a0 = Hs + (long)tok0 * HIDC + k0s * 8;
    const short* b0 = Ws + (long)(bn + r0) * HIDC + k0s * 8;
    int fr = lane & 15, fq = lane >> 4;
    int aOff[2], bOff[2];
    #pragma unroll
    for (int i = 0; i < 2; i++) {
        int row = wm + i * 16 + fr;
        aOff[i] = row * 32 + ((fq ^ ((row >> 1) & 3)) * 8);
        int col = wn + i * 16 + fr;
        bOff[i] = col * 32 + ((fq ^ ((col >> 1) & 3)) * 8);
    }
    f32x4 acc[2][2] = {};
    bf16x8 va_0 = *(const bf16x8*)a0;
    bf16x8 vb_0 = *(const bf16x8*)b0;
    bf16x8 va_1 = *(const bf16x8*)(a0 + 32);
    bf16x8 vb_1 = *(const bf16x8*)(b0 + 32);
    for (int kk = 0; kk < HIDC; kk += 64) {
        // ---- step 0 ----
        *(bf16x8*)&As[t * 8] = va_0;
        *(bf16x8*)&Bs[t * 8] = vb_0;
        __syncthreads();
        {
            int kn = (kk + 64 < HIDC) ? kk + 64 : kk;
            va_0 = *(const bf16x8*)(a0 + kn);
            vb_0 = *(const bf16x8*)(b0 + kn);
        }
        {
            bf16x8 aF[2], bF[2];
            #pragma unroll
            for (int i = 0; i < 2; i++) {
                aF[i] = *(const bf16x8*)&As[aOff[i]];
                bF[i] = *(const bf16x8*)&Bs[bOff[i]];
            }
            #pragma unroll
            for (int i = 0; i < 2; i++)
            #pragma unroll
            for (int j = 0; j < 2; j++)
                acc[i][j] = __builtin_amdgcn_mfma_f32_16x16x32_bf16(aF[i], bF[j], acc[i][j], 0, 0, 0);
        }
        // ---- step 1 ----
        *(bf16x8*)&As[2048 + t * 8] = va_1;
        *(bf16x8*)&Bs[2048 + t * 8] = vb_1;
        __syncthreads();
        {
            int kn = (kk + 96 < HIDC) ? kk + 96 : kk + 32;
            va_1 = *(const bf16x8*)(a0 + kn);
            vb_1 = *(const bf16x8*)(b0 + kn);
        }
        {
            bf16x8 aF[2], bF[2];
            #pragma unroll
            for (int i = 0; i < 2; i++) {
                aF[i] = *(const bf16x8*)&As[2048 + aOff[i]];
                bF[i] = *(const bf16x8*)&Bs[2048 + bOff[i]];
            }
            #pragma unroll
            for (int i = 0; i < 2; i++)
            #pragma unroll
            for (int j = 0; j < 2; j++)
                acc[i][j] = __builtin_amdgcn_mfma_f32_16x16x32_bf16(aF[i], bF[j], acc[i][j], 0, 0, 0);
        }
    }
    const float* bb = e_b2 + (long)e * DIMC;
    #pragma unroll
    for (int i = 0; i < 2; i++)
    #pragma unroll
    for (int r = 0; r < 4; r++) {
        int tok = rowsS[wm + i * 16 + fq * 4 + r];
        if (tok < 0) continue;
        #pragma unroll
        for (int j = 0; j < 2; j++) {
            int col = bn + wn + j * 16 + fr;
            long off = (long)tok * DIMC + col;
            float v = resid[off] + acc[i][j][r] + bb[col];
            bf16 hh, ll; split2(v, hh, ll);
            outh[off] = hh; outl[off] = ll;
        }
    }
}

// ---------------- LayerNorm: optional fp32 + bf16 hi/lo outputs ----------------
__global__ void ln_kernel(const float* __restrict__ x, const float* __restrict__ g,
                          const float* __restrict__ b, float* __restrict__ y,
                          bf16* __restrict__ yh, bf16* __restrict__ yl) {
    int tok = blockIdx.x;
    int t = threadIdx.x;
    const float* xr = x + (long)tok * DIMC;
    float v0 = xr[t], v1 = xr[t + 256];
    __shared__ float red[256];
    red[t] = v0 + v1; __syncthreads();
    for (int s = 128; s > 0; s >>= 1) { if (t < s) red[t] += red[t + s]; __syncthreads(); }
    float mu = red[0] * (1.f / DIMC);
    __syncthreads();
    float d0 = v0 - mu, d1 = v1 - mu;
    red[t] = d0 * d0 + d1 * d1; __syncthreads();
    for (int s = 128; s > 0; s >>= 1) { if (t < s) red[t] += red[t + s]; __syncthreads(); }
    float rs = rsqrtf(red[0] * (1.f / DIMC) + 1e-5f);
    float o0 = d0 * rs * g[t] + b[t];
    float o1 = d1 * rs * g[t + 256] + b[t + 256];
    if (y) { y[(long)tok * DIMC + t] = o0; y[(long)tok * DIMC + t + 256] = o1; }
    bf16 h, l;
    split2(o0, h, l); yh[(long)tok * DIMC + t] = h;       yl[(long)tok * DIMC + t] = l;
    split2(o1, h, l); yh[(long)tok * DIMC + t + 256] = h; yl[(long)tok * DIMC + t + 256] = l;
}

// ---------------- router text-part tw = w @ r_text_mu, wave-parallel (+ cnt zero) ----------------
// 512 entries, one wave each: lane sums k = lane + 64j (8 strided loads), 6-step shuffle reduce.
__global__ void tw_kernel(const float* __restrict__ w, const float* __restrict__ r_text_mu,
                          float* __restrict__ tw, int* __restrict__ cnt) {
    int t = threadIdx.x, wv = t >> 6, lane = t & 63;
    if (blockIdx.x == 0 && t < NE) cnt[t] = 0;
    int entry = blockIdx.x * 4 + wv;          // 0..511
    int b = entry >> 7, c = entry & 127;
    const float* wr = w + (long)b * LATC;
    float s = 0.f;
    #pragma unroll
    for (int j = 0; j < 8; j++) {
        int k = lane + j * 64;
        s += wr[k] * r_text_mu[(long)k * 128 + c];
    }
    s += __shfl_xor(s, 1);
    s += __shfl_xor(s, 2);
    s += __shfl_xor(s, 4);
    s += __shfl_xor(s, 8);
    s += __shfl_xor(s, 16);
    s += __shfl_xor(s, 32);
    if (lane == 0) tw[entry] = s;
}

// ---------------- router: perm poison + tp (from tw) + logits + argmax ----------------
// rc[256][8] = full r_comb in LDS; tp computed per block with c-ascending order preserved.
__global__ void route_kernel(const float* __restrict__ feat, const float* __restrict__ tw,
                             const float* __restrict__ r_comb_mu, const float* __restrict__ r_temp,
                             float* __restrict__ onehot, int* __restrict__ idx, int* __restrict__ cnt,
                             int* __restrict__ perm) {
    __shared__ float rc[256][8];
    __shared__ float tws[512];
    __shared__ float tps[32];
    int t = threadIdx.x;
    for (int i = t; i < 2048; i += 256) rc[i >> 3][i & 7] = r_comb_mu[i];
    for (int i = t; i < 512; i += 256) tws[i] = tw[i];
    __syncthreads();
    if (t < 32) {
        int b = t >> 3, e = t & 7;
        float s = 0.f;
        #pragma unroll 8
        for (int c = 0; c < 128; c++) s += tws[b * 128 + c] * rc[128 + c][e];
        tps[t] = s;
    }
    __syncthreads();
    int n = blockIdx.x * blockDim.x + t;
    if (n < MAXT * 64) perm[n] = -1;
    if (n >= NTOK) return;
    int b = n >> 10;
    float tmp = fmaxf(r_temp[0], 0.1f);
    float invt = 1.f / tmp;
    const float4* fr4 = (const float4*)(feat + (long)n * 128);
    float lg[8];
    #pragma unroll
    for (int e = 0; e < 8; e++) lg[e] = 0.f;
    #pragma unroll
    for (int c4 = 0; c4 < 32; c4++) {
        float4 f = fr4[c4];
        float fa[4] = {f.x, f.y, f.z, f.w};
        #pragma unroll
        for (int q = 0; q < 4; q++) {
            int c = c4 * 4 + q;
            #pragma unroll
            for (int e = 0; e < 8; e++) lg[e] += fa[q] * rc[c][e];
        }
    }
    #pragma unroll
    for (int e = 0; e < 8; e++) lg[e] = (lg[e] + tps[b * 8 + e]) * invt;
    float best = lg[0]; int bi = 0;
    #pragma unroll
    for (int e = 1; e < 8; e++) { if (lg[e] > best) { best = lg[e]; bi = e; } }
    #pragma unroll
    for (int e = 0; e < 8; e++) onehot[(long)n * 8 + e] = (e == bi) ? 1.f : 0.f;
    idx[n] = bi;
    atomicAdd(&cnt[bi], 1);
}

// ---------------- offsets + scatter fused (single block, LDS cursors) ----------------
__global__ void offscatter_kernel(const int* __restrict__ cnt, const int* __restrict__ idx,
                                  int* __restrict__ ntiles, int* __restrict__ table,
                                  int* __restrict__ perm) {
    __shared__ int cur[NE];
    int t = threadIdx.x;
    if (t == 0) {
        int po = 0, nt = 0;
        for (int e = 0; e < NE; e++) {
            cur[e] = po;
            int tiles = (cnt[e] + 63) >> 6;
            for (int j = 0; j < tiles; j++) { table[2 * nt] = e; table[2 * nt + 1] = po + j * 64; nt++; }
            po += tiles * 64;
        }
        ntiles[0] = nt;
    }
    __syncthreads();
    for (int n = t; n < NTOK; n += 256) {
        int e = idx[n];
        int pos = atomicAdd(&cur[e], 1);
        perm[pos] = n;
    }
}

extern "C" void kernel_launch(void* const* d_in, const int* in_sizes, int n_in,
                              void* d_out, int out_size, void* d_ws, size_t ws_size,
                              hipStream_t stream) {
    const float* x        = (const float*)d_in[0];
    const float* w        = (const float*)d_in[1];
    const float* text     = (const float*)d_in[2];
    const float* pin_w    = (const float*)d_in[3];
    const float* pin_mw   = (const float*)d_in[4];
    const float* pin_mb   = (const float*)d_in[5];
    const float* pout_w   = (const float*)d_in[6];
    const float* pout_mw  = (const float*)d_in[7];
    const float* pout_mb  = (const float*)d_in[8];
    const float* ln1g     = (const float*)d_in[9];
    const float* ln1b     = (const float*)d_in[10];
    const float* ln2g     = (const float*)d_in[11];
    const float* ln2b     = (const float*)d_in[12];
    const float* ln3g     = (const float*)d_in[13];
    const float* ln3b     = (const float*)d_in[14];
    const float* sa_in_w  = (const float*)d_in[15];
    const float* sa_in_b  = (const float*)d_in[16];
    const float* sa_out_w = (const float*)d_in[17];
    const float* sa_out_b = (const float*)d_in[18];
    const float* ca_in_w  = (const float*)d_in[19];
    const float* ca_in_b  = (const float*)d_in[20];
    const float* ca_out_w = (const float*)d_in[21];
    const float* ca_out_b = (const float*)d_in[22];
    const float* r_feat   = (const float*)d_in[23];
    const float* r_text   = (const float*)d_in[24];
    const float* r_comb   = (const float*)d_in[25];
    const float* r_temp   = (const float*)d_in[26];
    const float* e_w1     = (const float*)d_in[27];
    const float* e_b1     = (const float*)d_in[28];
    const float* e_w2     = (const float*)d_in[29];
    const float* e_b2     = (const float*)d_in[30];

    float* out    = (float*)d_out;               // [B, DIM, H, W]
    float* onehot = out + (long)BB * DIMC * HWX; // [4096, 8]

    // ---------------- workspace: fp32 pool ----------------
    float* f32p = (float*)d_ws;
    float* style_in  = f32p;                 // 2048 (reused as tw[512] after wtmod2)
    float* style_out = f32p + 2048;          // 2048
    int*   idx       = (int*)(f32p + 4128);  // 4096
    int*   cnt       = (int*)(f32p + 8224);  // 8
    int*   ntiles    = (int*)(f32p + 8240);  // 8
    int*   table     = (int*)(f32p + 8248);  // 256
    int*   perm      = (int*)(f32p + 8504);  // 4608 -> ends 13112
    float* x_flat    = f32p + 13496;         // 2097152
    float* xn        = x_flat + 2097152;     // 2097152 (home of wtC split)
    float* qkv       = xn + 2097152;         // 6291456 (SA q split / CA q split home)
    float* spill     = qkv + 6291456;        // 2097152 (e2T tail)
    float* tw        = style_in;             // 512 floats, dead style region

    // ---------------- bf16 pool (phase-aliased) ----------------
    bf16* bp = (bf16*)(f32p + 12596408);
    bf16* R1 = bp;                           // 6291456 elems, phases
    bf16* xT_h  = R1;
    bf16* xT_l  = R1 + 2097152;
    bf16* wtA_h = R1 + 4194304;
    bf16* wtA_l = R1 + 5242880;
    bf16* obuf_h = R1;
    bf16* obuf_l = R1 + 2097152;
    bf16* kvt_h  = R1 + 4194304;                       // [308][1024] split
    bf16* kvt_l  = kvt_h + 315392;
    float* feat  = (float*)(kvt_l + 315392);           // 524288 fp32
    bf16* xn_h = R1 + 6291456;               // 2097152
    bf16* xn_l = xn_h + 2097152;             // 2097152
    bf16* WB   = xn_l + 2097152;             // 8388608: weights (early) / hid_b (late)
    bf16* text_h   = WB;
    bf16* text_l   = text_h + 157696;
    bf16* sawin_h  = text_l + 157696;
    bf16* sawin_l  = sawin_h + 786432;
    bf16* sawout_h = sawin_l + 786432;
    bf16* sawout_l = sawout_h + 262144;
    bf16* caw_h    = sawout_l + 262144;
    bf16* caw_l    = caw_h + 786432;
    bf16* cawout_h = caw_l + 786432;
    bf16* cawout_l = cawout_h + 262144;
    bf16* rfT_h    = cawout_l + 262144;      // [128][512] split r_feat^T
    bf16* rfT_l    = rfT_h + 65536;
    bf16* hid_b    = WB;                     // overlays weights after ca_out
    bf16* e1T = (bf16*)qkv;                  // [8][2048][512] in qkv+spill
    bf16* e2T = e1T + 8388608;
    bf16* xfl_h = xn_h;                      // moe64_2 writes split output here
    bf16* xfl_l = xn_l;
    bf16* wtC_h = (bf16*)xn;                 // modconv-out weight (dead fp32 region)
    bf16* wtC_l = wtC_h + 1048576;
    bf16* q_h = (bf16*)qkv;                  // [4096][1536]
    bf16* q_l = q_h + 6291456;
    bf16* ca_qh = (bf16*)qkv;                // [4096][512]
    bf16* ca_ql = ca_qh + 2097152;
    (void)ws_size; (void)spill;

    auto mg = [&](const bf16* Ah, const bf16* Al, const bf16* Bh, const bf16* Bl,
                  const float* bias, const float* resid, float* C, bf16* Oh, bf16* Ol,
                  int M, int N, int K, long ab, long bb, long cb, int csm, int csn, int nb) {
        dim3 g(N / 64, (M + 63) / 64, nb);
        hipLaunchKernelGGL(mgemm64_kernel, g, dim3(256), 0, stream,
                           Ah, Al, Bh, Bl, bias, resid, C, Oh, Ol, M, N, K, ab, bb, cb, csm, csn);
    };

    // ---- fused input conversions (hi/lo): one launch for all 5 flat arrays ----
    {
        int n0 = 1536 * 512, n1 = 512 * 512, n2 = 1536 * 512, n3 = 512 * 512, n4 = BB * TXT * 512;
        int total = n0 + n1 + n2 + n3 + n4;
        hipLaunchKernelGGL(cvtall_kernel, dim3((total / 4 + 255) / 256), dim3(256), 0, stream,
                           sa_in_w, sawin_h, sawin_l, n0,
                           sa_out_w, sawout_h, sawout_l, n1,
                           ca_in_w, caw_h, caw_l, n2,
                           ca_out_w, cawout_h, cawout_l, n3,
                           text, text_h, text_l, n4);
    }
    // ---- fused transposes: x (z<4) + r_feat (z==4) ----
    hipLaunchKernelGGL(trcvt2x_kernel, dim3(32, 16, 5), dim3(256), 0, stream,
                       x, xT_h, xT_l, r_feat, rfT_h, rfT_l);

    // ---- both modconv styles + weights up front (wtC in dead xn region) ----
    hipLaunchKernelGGL(style2_kernel, dim3(16), dim3(256), 0, stream,
                       w, pin_mw, pin_mb, pout_mw, pout_mb, style_in, style_out);
    hipLaunchKernelGGL(wtmod2_kernel, dim3(2 * BB * DIMC), dim3(256), 0, stream,
                       pin_w, style_in, pout_w, style_out, wtA_h, wtA_l, wtC_h, wtC_l);
    // ---- router text part, early (style_in region now dead -> tw) ----
    hipLaunchKernelGGL(tw_kernel, dim3(128), dim3(256), 0, stream, w, r_text, tw, cnt);

    // ---- modconv in ----
    mg(xT_h, xT_l, wtA_h, wtA_l, nullptr, nullptr, x_flat, nullptr, nullptr,
       HWX, DIMC, DIMC, (long)HWX * DIMC, (long)DIMC * DIMC, (long)HWX * DIMC, DIMC, 1, BB);

    // ---- LN1 + self-attention (split MFMA) ----
    hipLaunchKernelGGL(ln_kernel, dim3(NTOK), dim3(256), 0, stream, x_flat, ln1g, ln1b,
                       (float*)nullptr, xn_h, xn_l);
    // qkv projection via high-reuse 128x64 kernel
    hipLaunchKernelGGL(mgemm128x64_kernel, dim3(1536 / 64, NTOK / 128), dim3(256), 0, stream,
                       xn_h, xn_l, sawin_h, sawin_l, sa_in_b, q_h, q_l, NTOK, 1536, 512);
    hipLaunchKernelGGL(sa_mfma_kernel, dim3(16, HEADS, BB), dim3(256), 0, stream,
                       q_h, q_l, obuf_h, obuf_l);
    mg(obuf_h, obuf_l, sawout_h, sawout_l, sa_out_b, x_flat, x_flat, nullptr, nullptr,
       NTOK, 512, 512, 0, 0, 0, 512, 1, 1);

    // ---- LN2 + cross-attention (split MFMA) ----
    hipLaunchKernelGGL(ln_kernel, dim3(NTOK), dim3(256), 0, stream, x_flat, ln2g, ln2b,
                       (float*)nullptr, xn_h, xn_l);
    mg(xn_h, xn_l, caw_h, caw_l, ca_in_b, nullptr, nullptr, ca_qh, ca_ql,
       NTOK, 512, 512, 0, 0, 0, 512, 1, 1);
    mg(text_h, text_l, caw_h + 512 * 512, caw_l + 512 * 512, ca_in_b + 512, nullptr, nullptr,
       kvt_h, kvt_l, BB * TXT, 1024, 512, 0, 0, 0, 1024, 1, 1);
    hipLaunchKernelGGL(ca_mfma_kernel, dim3(16, HEADS, BB), dim3(256), 0, stream,
                       ca_qh, ca_ql, kvt_h, kvt_l, obuf_h, obuf_l);
    // expert weight transposes (qkv region dead after ca_mfma) — one fused launch
    hipLaunchKernelGGL(tr2x_kernel, dim3(64, 16, 16), dim3(256), 0, stream,
                       e_w1, e1T, e_w2, e2T);
    mg(obuf_h, obuf_l, cawout_h, cawout_l, ca_out_b, x_flat, x_flat, nullptr, nullptr,
       NTOK, 512, 512, 0, 0, 0, 512, 1, 1);

    // ---- LN3 + router (feat via split MFMA) ----
    hipLaunchKernelGGL(ln_kernel, dim3(NTOK), dim3(256), 0, stream, x_flat, ln3g, ln3b,
                       (float*)nullptr, xn_h, xn_l);
    mg(xn_h, xn_l, rfT_h, rfT_l, nullptr, nullptr, feat, nullptr, nullptr,
       NTOK, 128, 512, 0, 0, 0, 128, 1, 1);
    hipLaunchKernelGGL(route_kernel, dim3(18), dim3(256), 0, stream,
                       feat, tw, r_comb, r_temp, onehot, idx, cnt, perm);
    hipLaunchKernelGGL(offscatter_kernel, dim3(1), dim3(256), 0, stream,
                       cnt, idx, ntiles, table, perm);

    // ---- MoE grouped MFMA GEMMs (gemm1 64x128, gemm2 64x64; both depth-2) ----
    hipLaunchKernelGGL(moe128_1_kernel, dim3(HIDC / 128, MAXT), dim3(256), 0, stream,
                       xn_h, e1T, e_b1, table, ntiles, perm, hid_b);
    hipLaunchKernelGGL(moe64_2_kernel, dim3(DIMC / 64, MAXT), dim3(256), 0, stream,
                       hid_b, e2T, e_b2, table, ntiles, perm, x_flat, xfl_h, xfl_l);

    // ---- modconv out (weights already prepared) ----
    mg(wtC_h, wtC_l, xfl_h, xfl_l, nullptr, nullptr, out, nullptr, nullptr,
       DIMC, HWX, DIMC, (long)DIMC * DIMC, (long)HWX * DIMC, (long)DIMC * HWX, HWX, 1, BB);
}

// Round 23
// 439.119 us; speedup vs baseline: 1.6402x; 1.0041x over previous
//
#include <hip/hip_runtime.h>
#include <hip/hip_bf16.h>
#include <math.h>

#define DIMC 512
#define HEADS 8
#define HD 64
#define BB 4
#define HWX 1024
#define TXT 77
#define LATC 512
#define NE 8
#define HIDC 2048
#define NTOK 4096
#define MAXT 72           // MoE tiles of 64: 4096/64 + 8

typedef __attribute__((ext_vector_type(8))) short bf16x8;
typedef __attribute__((ext_vector_type(4))) float f32x4;
typedef __hip_bfloat16 bf16;

__device__ __forceinline__ void split2(float v, bf16& h, bf16& l) {
    h = __float2bfloat16(v);
    l = __float2bfloat16(v - __bfloat162float(h));
}
__device__ __forceinline__ void split2s(float v, short& h, short& l) {
    bf16 hb, lb; split2(v, hb, lb);
    h = *(short*)&hb; l = *(short*)&lb;
}

// ---------------- both styles in one launch: job 0 = in, job 1 = out ----------------
__global__ void style2_kernel(const float* __restrict__ w,
                              const float* __restrict__ mwA, const float* __restrict__ mbA,
                              const float* __restrict__ mwB, const float* __restrict__ mbB,
                              float* __restrict__ sA, float* __restrict__ sB) {
    int g = blockIdx.x * blockDim.x + threadIdx.x;
    int job = (g >= BB * DIMC) ? 1 : 0;
    int t = g - job * BB * DIMC;
    if (t >= BB * DIMC) return;
    const float* mw = job ? mwB : mwA;
    const float* mb = job ? mbB : mbA;
    float* st = job ? sB : sA;
    int b = t / DIMC, i = t % DIMC;
    const float* wr = w + (long)b * LATC;
    const float* mr = mw + (long)i * LATC;
    float s = 0.f;
    #pragma unroll 8
    for (int l = 0; l < LATC; l++) s += wr[l] * mr[l];
    st[t] = s + mb[i];
}

// ------- both wtmods in one launch -------
__global__ void wtmod2_kernel(const float* __restrict__ wA, const float* __restrict__ sA,
                              const float* __restrict__ wB, const float* __restrict__ sB,
                              bf16* __restrict__ whA, bf16* __restrict__ wlA,
                              bf16* __restrict__ whB, bf16* __restrict__ wlB) {
    int gb = blockIdx.x;
    int job = (gb >= BB * DIMC) ? 1 : 0;
    int bo = gb - job * BB * DIMC;
    const float* weight = job ? wB : wA;
    const float* style  = job ? sB : sA;
    bf16* wh = job ? whB : whA;
    bf16* wl = job ? wlB : wlA;
    int b = bo / DIMC, o = bo % DIMC;
    const float* wr = weight + (long)o * DIMC;
    const float* sr = style + (long)b * DIMC;
    int t = threadIdx.x;
    float vals[2]; float part = 0.f;
    for (int j = 0; j < 2; j++) {
        int i = t + j * 256;
        float v = wr[i] * sr[i];
        vals[j] = v; part += v * v;
    }
    __shared__ float red[256];
    red[t] = part; __syncthreads();
    for (int s = 128; s > 0; s >>= 1) { if (t < s) red[t] += red[t + s]; __syncthreads(); }
    float d = rsqrtf(red[0] + 1e-8f);
    for (int j = 0; j < 2; j++) {
        int i = t + j * 256;
        bf16 h, l; split2(vals[j] * d, h, l);
        wh[(long)bo * DIMC + i] = h; wl[(long)bo * DIMC + i] = l;
    }
}

// ---------------- fused segmented fp32 -> bf16 hi/lo convert (5 weight arrays) ----------------
__global__ void cvtall_kernel(
    const float* __restrict__ s0, bf16* __restrict__ h0, bf16* __restrict__ l0, int n0,
    const float* __restrict__ s1, bf16* __restrict__ h1, bf16* __restrict__ l1, int n1,
    const float* __restrict__ s2, bf16* __restrict__ h2, bf16* __restrict__ l2, int n2,
    const float* __restrict__ s3, bf16* __restrict__ h3, bf16* __restrict__ l3, int n3,
    const float* __restrict__ s4, bf16* __restrict__ h4, bf16* __restrict__ l4, int n4) {
    int i = (blockIdx.x * blockDim.x + threadIdx.x) * 4;
    const float* src; bf16 *hh, *ll;
    if (i < n0) { src = s0; hh = h0; ll = l0; }
    else if ((i -= n0) < n1) { src = s1; hh = h1; ll = l1; }
    else if ((i -= n1) < n2) { src = s2; hh = h2; ll = l2; }
    else if ((i -= n2) < n3) { src = s3; hh = h3; ll = l3; }
    else if ((i -= n3) < n4) { src = s4; hh = h4; ll = l4; }
    else return;
    float4 v = *(const float4*)(src + i);
    float a[4] = {v.x, v.y, v.z, v.w};
    #pragma unroll
    for (int j = 0; j < 4; j++) { bf16 h, l; split2(a[j], h, l); hh[i + j] = h; ll[i + j] = l; }
}

// ---- fused transpose hi/lo: z<4 -> x slice (512x1024), z==4 -> r_feat (512x128) ----
__global__ void trcvt2x_kernel(const float* __restrict__ x, bf16* __restrict__ xh,
                               bf16* __restrict__ xl, const float* __restrict__ rf,
                               bf16* __restrict__ rfh, bf16* __restrict__ rfl) {
    __shared__ float tile[32][33];
    int z = blockIdx.z;
    const float* in; bf16 *hi, *lo; int R, C;
    if (z < 4) {
        in = x + (long)z * 512 * 1024;
        hi = xh + (long)z * 1024 * 512; lo = xl + (long)z * 1024 * 512;
        R = 512; C = 1024;
    } else {
        if (blockIdx.x >= 4) return;
        in = rf; hi = rfh; lo = rfl;
        R = 512; C = 128;
    }
    int c0 = blockIdx.x * 32, r0 = blockIdx.y * 32;
    int tc = threadIdx.x & 31, tr = threadIdx.x >> 5;
    #pragma unroll
    for (int i = 0; i < 4; i++) {
        int r = tr + i * 8;
        tile[r][tc] = in[(long)(r0 + r) * C + c0 + tc];
    }
    __syncthreads();
    #pragma unroll
    for (int i = 0; i < 4; i++) {
        int r = tr + i * 8;
        bf16 h, l; split2(tile[tc][r], h, l);
        hi[(long)(c0 + r) * R + r0 + tc] = h;
        lo[(long)(c0 + r) * R + r0 + tc] = l;
    }
}

// ---- fused expert-weight transposes: z<8 -> e_w1[z] (512x2048), z>=8 -> e_w2[z-8] (2048x512) ----
__global__ void tr2x_kernel(const float* __restrict__ w1, bf16* __restrict__ e1T,
                            const float* __restrict__ w2, bf16* __restrict__ e2T) {
    __shared__ float tile[32][33];
    int z = blockIdx.z;
    const float* in; bf16* out; int R, C, c0, r0;
    if (z < 8) {
        in = w1 + (long)z * 512 * 2048;  out = e1T + (long)z * 2048 * 512;
        R = 512; C = 2048;
        c0 = blockIdx.x * 32; r0 = blockIdx.y * 32;       // grid x=64, y=16
    } else {
        in = w2 + (long)(z - 8) * 2048 * 512;  out = e2T + (long)(z - 8) * 512 * 2048;
        R = 2048; C = 512;
        int lin = blockIdx.y * 64 + blockIdx.x;           // 0..1023 -> (16 x, 64 y)
        c0 = (lin & 15) * 32; r0 = (lin >> 4) * 32;
    }
    int tc = threadIdx.x & 31, tr = threadIdx.x >> 5;
    #pragma unroll
    for (int i = 0; i < 4; i++) {
        int r = tr + i * 8;
        tile[r][tc] = in[(long)(r0 + r) * C + c0 + tc];
    }
    __syncthreads();
    #pragma unroll
    for (int i = 0; i < 4; i++) {
        int r = tr + i * 8;
        out[(long)(c0 + r) * R + r0 + tc] = __float2bfloat16(tile[tc][r]);
    }
}

// ---- split-precision bf16 MFMA GEMM, 64x64 tile, depth-2 prefetch (K % 64 == 0) ----
__global__ __launch_bounds__(256) void mgemm64_kernel(
    const bf16* __restrict__ Ah, const bf16* __restrict__ Al,
    const bf16* __restrict__ Bh, const bf16* __restrict__ Bl,
    const float* __restrict__ bias, const float* __restrict__ resid, float* __restrict__ C,
    bf16* __restrict__ Oh, bf16* __restrict__ Ol,
    int M, int N, int K, long a_bat, long b_bat, long c_bat, int cs_m, int cs_n) {
    __shared__ short AsH[2 * 2048];
    __shared__ short AsL[2 * 2048];
    __shared__ short BsH[2 * 2048];
    __shared__ short BsL[2 * 2048];
    int bat = blockIdx.z;
    const short* AbH = (const short*)(Ah + (long)bat * a_bat);
    const short* AbL = (const short*)(Al + (long)bat * a_bat);
    const short* BbH = (const short*)(Bh + (long)bat * b_bat);
    const short* BbL = (const short*)(Bl + (long)bat * b_bat);
    float* Cb = C + (long)bat * c_bat;
    const float* Rb = resid ? resid + (long)bat * c_bat : nullptr;
    int bm = blockIdx.y * 64, bn = blockIdx.x * 64;
    int t = threadIdx.x, lane = t & 63, w = t >> 6;
    int wm = (w >> 1) * 32, wn = (w & 1) * 32;
    int r0 = t >> 2, k0s = (t & 3) ^ ((r0 >> 1) & 3);
    int ar0 = bm + r0; if (ar0 > M - 1) ar0 = M - 1;
    long aoff = (long)ar0 * K + k0s * 8;
    long boff = (long)(bn + r0) * K + k0s * 8;
    int fr = lane & 15, fq = lane >> 4;
    int aOff[2], bOff[2];
    #pragma unroll
    for (int i = 0; i < 2; i++) {
        int row = wm + i * 16 + fr;
        aOff[i] = row * 32 + ((fq ^ ((row >> 1) & 3)) * 8);
        int col = wn + i * 16 + fr;
        bOff[i] = col * 32 + ((fq ^ ((col >> 1) & 3)) * 8);
    }
    f32x4 acc[2][2] = {};
    bf16x8 vah0 = *(const bf16x8*)(AbH + aoff);
    bf16x8 val0 = *(const bf16x8*)(AbL + aoff);
    bf16x8 vbh0 = *(const bf16x8*)(BbH + boff);
    bf16x8 vbl0 = *(const bf16x8*)(BbL + boff);
    bf16x8 vah1 = *(const bf16x8*)(AbH + aoff + 32);
    bf16x8 val1 = *(const bf16x8*)(AbL + aoff + 32);
    bf16x8 vbh1 = *(const bf16x8*)(BbH + boff + 32);
    bf16x8 vbl1 = *(const bf16x8*)(BbL + boff + 32);
    for (int kk = 0; kk < K; kk += 64) {
        // ---- step 0: buffer 0, tile kk ----
        *(bf16x8*)&AsH[t * 8] = vah0;
        *(bf16x8*)&AsL[t * 8] = val0;
        *(bf16x8*)&BsH[t * 8] = vbh0;
        *(bf16x8*)&BsL[t * 8] = vbl0;
        __syncthreads();
        {
            int kn = (kk + 64 < K) ? kk + 64 : kk;
            vah0 = *(const bf16x8*)(AbH + aoff + kn);
            val0 = *(const bf16x8*)(AbL + aoff + kn);
            vbh0 = *(const bf16x8*)(BbH + boff + kn);
            vbl0 = *(const bf16x8*)(BbL + boff + kn);
        }
        {
            bf16x8 aH[2], aL[2], bH[2], bL[2];
            #pragma unroll
            for (int i = 0; i < 2; i++) {
                aH[i] = *(const bf16x8*)&AsH[aOff[i]];
                aL[i] = *(const bf16x8*)&AsL[aOff[i]];
                bH[i] = *(const bf16x8*)&BsH[bOff[i]];
                bL[i] = *(const bf16x8*)&BsL[bOff[i]];
            }
            #pragma unroll
            for (int i = 0; i < 2; i++)
            #pragma unroll
            for (int j = 0; j < 2; j++) {
                acc[i][j] = __builtin_amdgcn_mfma_f32_16x16x32_bf16(aH[i], bH[j], acc[i][j], 0, 0, 0);
                acc[i][j] = __builtin_amdgcn_mfma_f32_16x16x32_bf16(aH[i], bL[j], acc[i][j], 0, 0, 0);
                acc[i][j] = __builtin_amdgcn_mfma_f32_16x16x32_bf16(aL[i], bH[j], acc[i][j], 0, 0, 0);
            }
        }
        // ---- step 1: buffer 1, tile kk+32 ----
        *(bf16x8*)&AsH[2048 + t * 8] = vah1;
        *(bf16x8*)&AsL[2048 + t * 8] = val1;
        *(bf16x8*)&BsH[2048 + t * 8] = vbh1;
        *(bf16x8*)&BsL[2048 + t * 8] = vbl1;
        __syncthreads();
        {
            int kn = (kk + 96 < K) ? kk + 96 : kk + 32;
            vah1 = *(const bf16x8*)(AbH + aoff + kn);
            val1 = *(const bf16x8*)(AbL + aoff + kn);
            vbh1 = *(const bf16x8*)(BbH + boff + kn);
            vbl1 = *(const bf16x8*)(BbL + boff + kn);
        }
        {
            bf16x8 aH[2], aL[2], bH[2], bL[2];
            #pragma unroll
            for (int i = 0; i < 2; i++) {
                aH[i] = *(const bf16x8*)&AsH[2048 + aOff[i]];
                aL[i] = *(const bf16x8*)&AsL[2048 + aOff[i]];
                bH[i] = *(const bf16x8*)&BsH[2048 + bOff[i]];
                bL[i] = *(const bf16x8*)&BsL[2048 + bOff[i]];
            }
            #pragma unroll
            for (int i = 0; i < 2; i++)
            #pragma unroll
            for (int j = 0; j < 2; j++) {
                acc[i][j] = __builtin_amdgcn_mfma_f32_16x16x32_bf16(aH[i], bH[j], acc[i][j], 0, 0, 0);
                acc[i][j] = __builtin_amdgcn_mfma_f32_16x16x32_bf16(aH[i], bL[j], acc[i][j], 0, 0, 0);
                acc[i][j] = __builtin_amdgcn_mfma_f32_16x16x32_bf16(aL[i], bH[j], acc[i][j], 0, 0, 0);
            }
        }
    }
    #pragma unroll
    for (int i = 0; i < 2; i++)
    #pragma unroll
    for (int j = 0; j < 2; j++)
    #pragma unroll
    for (int r = 0; r < 4; r++) {
        int row = bm + wm + i * 16 + fq * 4 + r;
        int col = bn + wn + j * 16 + fr;
        if (row < M) {
            long off = (long)row * cs_m + (long)col * cs_n;
            float v = acc[i][j][r];
            if (bias) v += bias[col];
            if (Oh) {
                bf16 hh, ll; split2(v, hh, ll);
                Oh[off] = hh; Ol[off] = ll;
            } else {
                if (Rb) v += Rb[off];
                Cb[off] = v;
            }
        }
    }
}

// ---- split-precision bf16 MFMA GEMM, 128x64 tile, depth-2 prefetch (qkv GEMM) ----
__global__ __launch_bounds__(256) void mgemm128x64_kernel(
    const bf16* __restrict__ Ah, const bf16* __restrict__ Al,
    const bf16* __restrict__ Bh, const bf16* __restrict__ Bl,
    const float* __restrict__ bias, bf16* __restrict__ Oh, bf16* __restrict__ Ol,
    int M, int N, int K) {
    __shared__ short AsH[2 * 4096];
    __shared__ short AsL[2 * 4096];
    __shared__ short BsH[2 * 2048];
    __shared__ short BsL[2 * 2048];
    const short* AbH = (const short*)Ah;
    const short* AbL = (const short*)Al;
    const short* BbH = (const short*)Bh;
    const short* BbL = (const short*)Bl;
    int bm = blockIdx.y * 128, bn = blockIdx.x * 64;
    int t = threadIdx.x, lane = t & 63, w = t >> 6;
    int wm = (w >> 1) * 64, wn = (w & 1) * 32;
    int p0 = t, p1 = t + 256;
    int ra0 = p0 >> 2, ka0 = (p0 & 3) ^ ((ra0 >> 1) & 3);
    int ra1 = p1 >> 2, ka1 = (p1 & 3) ^ ((ra1 >> 1) & 3);
    int arow0 = bm + ra0; if (arow0 > M - 1) arow0 = M - 1;
    int arow1 = bm + ra1; if (arow1 > M - 1) arow1 = M - 1;
    long aoff0 = (long)arow0 * K + ka0 * 8;
    long aoff1 = (long)arow1 * K + ka1 * 8;
    int rb = t >> 2, kb2 = (t & 3) ^ ((rb >> 1) & 3);
    long boff = (long)(bn + rb) * K + kb2 * 8;
    int fr = lane & 15, fq = lane >> 4;
    int aOff[4], bOff[2];
    #pragma unroll
    for (int i = 0; i < 4; i++) {
        int row = wm + i * 16 + fr;
        aOff[i] = row * 32 + ((fq ^ ((row >> 1) & 3)) * 8);
    }
    #pragma unroll
    for (int j = 0; j < 2; j++) {
        int col = wn + j * 16 + fr;
        bOff[j] = col * 32 + ((fq ^ ((col >> 1) & 3)) * 8);
    }
    f32x4 acc[4][2] = {};
    bf16x8 sA0h0 = *(const bf16x8*)(AbH + aoff0);
    bf16x8 sA1h0 = *(const bf16x8*)(AbH + aoff1);
    bf16x8 sA0l0 = *(const bf16x8*)(AbL + aoff0);
    bf16x8 sA1l0 = *(const bf16x8*)(AbL + aoff1);
    bf16x8 sBh0  = *(const bf16x8*)(BbH + boff);
    bf16x8 sBl0  = *(const bf16x8*)(BbL + boff);
    bf16x8 sA0h1 = *(const bf16x8*)(AbH + aoff0 + 32);
    bf16x8 sA1h1 = *(const bf16x8*)(AbH + aoff1 + 32);
    bf16x8 sA0l1 = *(const bf16x8*)(AbL + aoff0 + 32);
    bf16x8 sA1l1 = *(const bf16x8*)(AbL + aoff1 + 32);
    bf16x8 sBh1  = *(const bf16x8*)(BbH + boff + 32);
    bf16x8 sBl1  = *(const bf16x8*)(BbL + boff + 32);
    for (int kk = 0; kk < K; kk += 64) {
        // ---- step 0 ----
        *(bf16x8*)&AsH[p0 * 8] = sA0h0;  *(bf16x8*)&AsH[p1 * 8] = sA1h0;
        *(bf16x8*)&AsL[p0 * 8] = sA0l0;  *(bf16x8*)&AsL[p1 * 8] = sA1l0;
        *(bf16x8*)&BsH[t * 8] = sBh0;
        *(bf16x8*)&BsL[t * 8] = sBl0;
        __syncthreads();
        {
            int kn = (kk + 64 < K) ? kk + 64 : kk;
            sA0h0 = *(const bf16x8*)(AbH + aoff0 + kn);
            sA1h0 = *(const bf16x8*)(AbH + aoff1 + kn);
            sA0l0 = *(const bf16x8*)(AbL + aoff0 + kn);
            sA1l0 = *(const bf16x8*)(AbL + aoff1 + kn);
            sBh0  = *(const bf16x8*)(BbH + boff + kn);
            sBl0  = *(const bf16x8*)(BbL + boff + kn);
        }
        {
            bf16x8 aH[4], aL[4], bH[2], bL[2];
            #pragma unroll
            for (int i = 0; i < 4; i++) {
                aH[i] = *(const bf16x8*)&AsH[aOff[i]];
                aL[i] = *(const bf16x8*)&AsL[aOff[i]];
            }
            #pragma unroll
            for (int j = 0; j < 2; j++) {
                bH[j] = *(const bf16x8*)&BsH[bOff[j]];
                bL[j] = *(const bf16x8*)&BsL[bOff[j]];
            }
            #pragma unroll
            for (int i = 0; i < 4; i++)
            #pragma unroll
            for (int j = 0; j < 2; j++) {
                acc[i][j] = __builtin_amdgcn_mfma_f32_16x16x32_bf16(aH[i], bH[j], acc[i][j], 0, 0, 0);
                acc[i][j] = __builtin_amdgcn_mfma_f32_16x16x32_bf16(aH[i], bL[j], acc[i][j], 0, 0, 0);
                acc[i][j] = __builtin_amdgcn_mfma_f32_16x16x32_bf16(aL[i], bH[j], acc[i][j], 0, 0, 0);
            }
        }
        // ---- step 1 ----
        *(bf16x8*)&AsH[4096 + p0 * 8] = sA0h1;  *(bf16x8*)&AsH[4096 + p1 * 8] = sA1h1;
        *(bf16x8*)&AsL[4096 + p0 * 8] = sA0l1;  *(bf16x8*)&AsL[4096 + p1 * 8] = sA1l1;
        *(bf16x8*)&BsH[2048 + t * 8] = sBh1;
        *(bf16x8*)&BsL[2048 + t * 8] = sBl1;
        __syncthreads();
        {
            int kn = (kk + 96 < K) ? kk + 96 : kk + 32;
            sA0h1 = *(const bf16x8*)(AbH + aoff0 + kn);
            sA1h1 = *(const bf16x8*)(AbH + aoff1 + kn);
            sA0l1 = *(const bf16x8*)(AbL + aoff0 + kn);
            sA1l1 = *(const bf16x8*)(AbL + aoff1 + kn);
            sBh1  = *(const bf16x8*)(BbH + boff + kn);
            sBl1  = *(const bf16x8*)(BbL + boff + kn);
        }
        {
            bf16x8 aH[4], aL[4], bH[2], bL[2];
            #pragma unroll
            for (int i = 0; i < 4; i++) {
                aH[i] = *(const bf16x8*)&AsH[4096 + aOff[i]];
                aL[i] = *(const bf16x8*)&AsL[4096 + aOff[i]];
            }
            #pragma unroll
            for (int j = 0; j < 2; j++) {
                bH[j] = *(const bf16x8*)&BsH[2048 + bOff[j]];
                bL[j] = *(const bf16x8*)&BsL[2048 + bOff[j]];
            }
            #pragma unroll
            for (int i = 0; i < 4; i++)
            #pragma unroll
            for (int j = 0; j < 2; j++) {
                acc[i][j] = __builtin_amdgcn_mfma_f32_16x16x32_bf16(aH[i], bH[j], acc[i][j], 0, 0, 0);
                acc[i][j] = __builtin_amdgcn_mfma_f32_16x16x32_bf16(aH[i], bL[j], acc[i][j], 0, 0, 0);
                acc[i][j] = __builtin_amdgcn_mfma_f32_16x16x32_bf16(aL[i], bH[j], acc[i][j], 0, 0, 0);
            }
        }
    }
    #pragma unroll
    for (int i = 0; i < 4; i++)
    #pragma unroll
    for (int j = 0; j < 2; j++)
    #pragma unroll
    for (int r = 0; r < 4; r++) {
        int row = bm + wm + i * 16 + fq * 4 + r;
        int col = bn + wn + j * 16 + fr;
        if (row < M) {
            long off = (long)row * N + col;
            float v = acc[i][j][r] + bias[col];
            bf16 hh, ll; split2(v, hh, ll);
            Oh[off] = hh; Ol[off] = ll;
        }
    }
}

// ---- split-precision MFMA flash SA: no-max softmax, single-bf16 P, V stride 72 ----
__global__ __launch_bounds__(256) void sa_mfma_kernel(
    const bf16* __restrict__ qh, const bf16* __restrict__ ql,
    bf16* __restrict__ oh, bf16* __restrict__ ol) {
    int qt = blockIdx.x, h = blockIdx.y, b = blockIdx.z;
    __shared__ short KsH[4096], KsL[4096];       // [kv][64], swz: col ^ ((kv&7)<<3)
    __shared__ short VtH[4608], VtL[4608];       // [d][72], swz: col ^ (((d>>3)&7)<<3)
    __shared__ short PHs[4][1024];               // per-wave P (single bf16)
    int t = threadIdx.x, lane = t & 63, w = t >> 6;
    int fr = lane & 15, fq = lane >> 4;
    const short* QH = (const short*)qh;
    const short* QL = (const short*)ql;
    long qrow = (long)(b * 1024 + qt * 64 + w * 16 + fr) * 1536 + h * 64;
    bf16x8 Qh2[2], Ql2[2];
    Qh2[0] = *(const bf16x8*)(QH + qrow + fq * 8);
    Qh2[1] = *(const bf16x8*)(QH + qrow + 32 + fq * 8);
    Ql2[0] = *(const bf16x8*)(QL + qrow + fq * 8);
    Ql2[1] = *(const bf16x8*)(QL + qrow + 32 + fq * 8);
    float l_i[4] = {0.f, 0.f, 0.f, 0.f};
    f32x4 o_acc[4] = {};
    int c0 = t, c1 = t + 256;
    int r0 = c0 >> 3, g0 = c0 & 7;               // r0 in 0..31
    int r1 = c1 >> 3, g1 = c1 & 7;               // r1 in 32..63
    int kd0 = r0 * 64 + ((g0 * 8) ^ ((r0 & 7) << 3));
    int kd1 = r1 * 64 + ((g1 * 8) ^ ((r1 & 7) << 3));
    long kb = (long)(b * 1024) * 1536 + 512 + h * 64;
    long vb = kb + 512;
    long lo0 = (long)r0 * 1536 + g0 * 8, lo1 = (long)r1 * 1536 + g1 * 8;
    short* ph = PHs[w];
    bf16x8 kh0 = *(const bf16x8*)(QH + kb + lo0);
    bf16x8 kh1 = *(const bf16x8*)(QH + kb + lo1);
    bf16x8 kl0 = *(const bf16x8*)(QL + kb + lo0);
    bf16x8 kl1 = *(const bf16x8*)(QL + kb + lo1);
    bf16x8 vh0 = *(const bf16x8*)(QH + vb + lo0);
    bf16x8 vh1 = *(const bf16x8*)(QH + vb + lo1);
    bf16x8 vl0 = *(const bf16x8*)(QL + vb + lo0);
    bf16x8 vl1 = *(const bf16x8*)(QL + vb + lo1);
    for (int kt = 0; kt < 16; kt++) {
        __syncthreads();          // A: all waves finished reading Ks/Vt of prev iter
        *(bf16x8*)&KsH[kd0] = kh0;  *(bf16x8*)&KsH[kd1] = kh1;
        *(bf16x8*)&KsL[kd0] = kl0;  *(bf16x8*)&KsL[kd1] = kl1;
        #pragma unroll
        for (int j = 0; j < 8; j++) {
            int d0 = g0 * 8 + j;
            int i0 = d0 * 72 + (r0 ^ (g0 << 3));
            VtH[i0] = ((short*)&vh0)[j];  VtL[i0] = ((short*)&vl0)[j];
            int d1 = g1 * 8 + j;
            int i1 = d1 * 72 + (r1 ^ (g1 << 3));
            VtH[i1] = ((short*)&vh1)[j];  VtL[i1] = ((short*)&vl1)[j];
        }
        __syncthreads();          // B: staging visible
        int ktn = (kt + 1 < 16) ? kt + 1 : kt;
        long ko = kb + (long)(ktn * 64) * 1536;
        long vo = vb + (long)(ktn * 64) * 1536;
        bf16x8 nkh0 = *(const bf16x8*)(QH + ko + lo0);
        bf16x8 nkh1 = *(const bf16x8*)(QH + ko + lo1);
        bf16x8 nkl0 = *(const bf16x8*)(QL + ko + lo0);
        bf16x8 nkl1 = *(const bf16x8*)(QL + ko + lo1);
        bf16x8 nvh0 = *(const bf16x8*)(QH + vo + lo0);
        bf16x8 nvh1 = *(const bf16x8*)(QH + vo + lo1);
        bf16x8 nvl0 = *(const bf16x8*)(QL + vo + lo0);
        bf16x8 nvl1 = *(const bf16x8*)(QL + vo + lo1);
        __builtin_amdgcn_s_setprio(1);
        f32x4 s[4] = {};
        #pragma unroll
        for (int cf = 0; cf < 4; cf++) {
            int kvrow = cf * 16 + fr;
            #pragma unroll
            for (int kf = 0; kf < 2; kf++) {
                int idx = kvrow * 64 + ((kf * 32 + fq * 8) ^ ((kvrow & 7) << 3));
                bf16x8 Bh2 = *(const bf16x8*)&KsH[idx];
                bf16x8 Bl2 = *(const bf16x8*)&KsL[idx];
                s[cf] = __builtin_amdgcn_mfma_f32_16x16x32_bf16(Qh2[kf], Bh2, s[cf], 0, 0, 0);
                s[cf] = __builtin_amdgcn_mfma_f32_16x16x32_bf16(Qh2[kf], Bl2, s[cf], 0, 0, 0);
                s[cf] = __builtin_amdgcn_mfma_f32_16x16x32_bf16(Ql2[kf], Bh2, s[cf], 0, 0, 0);
            }
        }
        __builtin_amdgcn_s_setprio(0);
        #pragma unroll
        for (int cf = 0; cf < 4; cf++)
        #pragma unroll
        for (int reg = 0; reg < 4; reg++) {
            float e = __expf(s[cf][reg] * 0.125f);
            bf16 eb = __float2bfloat16(e);
            l_i[reg] += __bfloat162float(eb);
            int q = fq * 4 + reg, kv = cf * 16 + fr;
            int idx = q * 64 + (kv ^ ((q & 7) << 3));
            ph[idx] = *(short*)&eb;
        }
        asm volatile("s_waitcnt lgkmcnt(0)" ::: "memory");
        __builtin_amdgcn_sched_barrier(0);
        __builtin_amdgcn_s_setprio(1);
        bf16x8 Pf_h[2];
        #pragma unroll
        for (int kf = 0; kf < 2; kf++) {
            int idx = fr * 64 + ((kf * 32 + fq * 8) ^ ((fr & 7) << 3));
            Pf_h[kf] = *(const bf16x8*)&ph[idx];
        }
        #pragma unroll
        for (int cf = 0; cf < 4; cf++) {
            int d = cf * 16 + fr;
            #pragma unroll
            for (int kf = 0; kf < 2; kf++) {
                int idx = d * 72 + ((kf * 32 + fq * 8) ^ (((d >> 3) & 7) << 3));
                bf16x8 Vh2 = *(const bf16x8*)&VtH[idx];
                bf16x8 Vl2 = *(const bf16x8*)&VtL[idx];
                o_acc[cf] = __builtin_amdgcn_mfma_f32_16x16x32_bf16(Pf_h[kf], Vh2, o_acc[cf], 0, 0, 0);
                o_acc[cf] = __builtin_amdgcn_mfma_f32_16x16x32_bf16(Pf_h[kf], Vl2, o_acc[cf], 0, 0, 0);
            }
        }
        __builtin_amdgcn_s_setprio(0);
        kh0 = nkh0; kh1 = nkh1; kl0 = nkl0; kl1 = nkl1;
        vh0 = nvh0; vh1 = nvh1; vl0 = nvl0; vl1 = nvl1;
    }
    #pragma unroll
    for (int reg = 0; reg < 4; reg++) {
        float rs = l_i[reg];
        rs += __shfl_xor(rs, 1);
        rs += __shfl_xor(rs, 2);
        rs += __shfl_xor(rs, 4);
        rs += __shfl_xor(rs, 8);
        float inv = 1.f / rs;
        long m = (long)(b * 1024 + qt * 64 + w * 16 + fq * 4 + reg);
        #pragma unroll
        for (int cf = 0; cf < 4; cf++) {
            float v = o_acc[cf][reg] * inv;
            bf16 hh, ll; split2(v, hh, ll);
            long off = m * DIMC + h * 64 + cf * 16 + fr;
            oh[off] = hh; ol[off] = ll;
        }
    }
}

// ---- split-precision MFMA cross-attention: 77 keys padded to 96, single-bf16 P ----
__global__ __launch_bounds__(256) void ca_mfma_kernel(
    const bf16* __restrict__ qh, const bf16* __restrict__ ql,
    const bf16* __restrict__ kvh, const bf16* __restrict__ kvl,
    bf16* __restrict__ oh, bf16* __restrict__ ol) {
    int qt = blockIdx.x, h = blockIdx.y, b = blockIdx.z;
    __shared__ short UH[8192], UL[8192];
    __shared__ short PHs[4][2048];
    int t = threadIdx.x, lane = t & 63, w = t >> 6;
    int fr = lane & 15, fq = lane >> 4;
    const short* QH = (const short*)qh;
    const short* QL = (const short*)ql;
    const short* KVH = (const short*)kvh;
    const short* KVL = (const short*)kvl;
    long qrow = (long)(b * 1024 + qt * 64 + w * 16 + fr) * DIMC + h * 64;
    bf16x8 Qh2[2], Ql2[2];
    Qh2[0] = *(const bf16x8*)(QH + qrow + fq * 8);
    Qh2[1] = *(const bf16x8*)(QH + qrow + 32 + fq * 8);
    Ql2[0] = *(const bf16x8*)(QL + qrow + fq * 8);
    Ql2[1] = *(const bf16x8*)(QL + qrow + 32 + fq * 8);
    for (int c = t; c < 768; c += 256) {
        int r = c >> 3, g = c & 7;
        int idx = r * 64 + ((g * 8) ^ ((r & 7) << 3));
        bf16x8 vh = {}, vl = {};
        if (r < 77) {
            long src = (long)(b * 77 + r) * 1024 + h * 64 + g * 8;
            vh = *(const bf16x8*)(KVH + src);
            vl = *(const bf16x8*)(KVL + src);
        }
        *(bf16x8*)&UH[idx] = vh;
        *(bf16x8*)&UL[idx] = vl;
    }
    __syncthreads();
    f32x4 s[5] = {};
    #pragma unroll
    for (int cf = 0; cf < 5; cf++) {
        int kvrow = cf * 16 + fr;
        #pragma unroll
        for (int kf = 0; kf < 2; kf++) {
            int idx = kvrow * 64 + ((kf * 32 + fq * 8) ^ ((kvrow & 7) << 3));
            bf16x8 Bh2 = *(const bf16x8*)&UH[idx];
            bf16x8 Bl2 = *(const bf16x8*)&UL[idx];
            s[cf] = __builtin_amdgcn_mfma_f32_16x16x32_bf16(Qh2[kf], Bh2, s[cf], 0, 0, 0);
            s[cf] = __builtin_amdgcn_mfma_f32_16x16x32_bf16(Qh2[kf], Bl2, s[cf], 0, 0, 0);
            s[cf] = __builtin_amdgcn_mfma_f32_16x16x32_bf16(Ql2[kf], Bh2, s[cf], 0, 0, 0);
        }
    }
    float inv[4];
    #pragma unroll
    for (int reg = 0; reg < 4; reg++) {
        float rs = 0.f;
        #pragma unroll
        for (int cf = 0; cf < 5; cf++) {
            int kv = cf * 16 + fr;
            float e = (kv < 77) ? __expf(s[cf][reg] * 0.125f) : 0.f;
            s[cf][reg] = e;
            rs += e;
        }
        rs += __shfl_xor(rs, 1);
        rs += __shfl_xor(rs, 2);
        rs += __shfl_xor(rs, 4);
        rs += __shfl_xor(rs, 8);
        inv[reg] = 1.f / rs;
    }
    short* ph = PHs[w];
    #pragma unroll
    for (int cf = 0; cf < 6; cf++)
    #pragma unroll
    for (int reg = 0; reg < 4; reg++) {
        int q = fq * 4 + reg, kv = cf * 16 + fr;
        int idx = q * 128 + (kv ^ ((q & 7) << 3));
        float pv = (cf < 5) ? s[cf][reg] * inv[reg] : 0.f;
        bf16 pb = __float2bfloat16(pv);
        ph[idx] = *(short*)&pb;
    }
    __syncthreads();
    for (int c = t; c < 768; c += 256) {
        int r = c >> 3, g = c & 7;
        bf16x8 vh = {}, vl = {};
        if (r < 77) {
            long src = (long)(b * 77 + r) * 1024 + 512 + h * 64 + g * 8;
            vh = *(const bf16x8*)(KVH + src);
            vl = *(const bf16x8*)(KVL + src);
        }
        #pragma unroll
        for (int j = 0; j < 8; j++) {
            int d = g * 8 + j;
            int idx = d * 128 + (r ^ (((d >> 3) & 7) << 3));
            UH[idx] = ((short*)&vh)[j];
            UL[idx] = ((short*)&vl)[j];
        }
    }
    __syncthreads();
    f32x4 o_acc[4] = {};
    bf16x8 Pf_h[3];
    #pragma unroll
    for (int kf = 0; kf < 3; kf++) {
        int idx = fr * 128 + ((kf * 32 + fq * 8) ^ ((fr & 7) << 3));
        Pf_h[kf] = *(const bf16x8*)&ph[idx];
    }
    #pragma unroll
    for (int cf = 0; cf < 4; cf++) {
        int d = cf * 16 + fr;
        #pragma unroll
        for (int kf = 0; kf < 3; kf++) {
            int idx = d * 128 + ((kf * 32 + fq * 8) ^ (((d >> 3) & 7) << 3));
            bf16x8 Vh2 = *(const bf16x8*)&UH[idx];
            bf16x8 Vl2 = *(const bf16x8*)&UL[idx];
            o_acc[cf] = __builtin_amdgcn_mfma_f32_16x16x32_bf16(Pf_h[kf], Vh2, o_acc[cf], 0, 0, 0);
            o_acc[cf] = __builtin_amdgcn_mfma_f32_16x16x32_bf16(Pf_h[kf], Vl2, o_acc[cf], 0, 0, 0);
        }
    }
    #pragma unroll
    for (int reg = 0; reg < 4; reg++) {
        long m = (long)(b * 1024 + qt * 64 + w * 16 + fq * 4 + reg);
        #pragma unroll
        for (int cf = 0; cf < 4; cf++) {
            bf16 hh, ll; split2(o_acc[cf][reg], hh, ll);
            long off = m * DIMC + h * 64 + cf * 16 + fr;
            oh[off] = hh; ol[off] = ll;
        }
    }
}

// ---- MoE grouped MFMA GEMM1, 64x128 tile, depth-2 prefetch: hid = gelu(xn·w1 + b1) ----
__global__ __launch_bounds__(256) void moe128_1_kernel(
    const bf16* __restrict__ xn_b, const bf16* __restrict__ e1T, const float* __restrict__ e_b1,
    const int* __restrict__ table, const int* __restrict__ ntiles, const int* __restrict__ perm,
    bf16* __restrict__ hid_b) {
    if (blockIdx.y >= ntiles[0]) return;
    int e = table[2 * blockIdx.y], row0 = table[2 * blockIdx.y + 1];
    int bn = blockIdx.x * 128;
    __shared__ short As[2 * 2048];
    __shared__ short Bs[2 * 4096];
    __shared__ int rowsS[64];
    int t = threadIdx.x, lane = t & 63, w = t >> 6;
    if (t < 64) rowsS[t] = perm[row0 + t];
    __syncthreads();
    int wm = (w >> 1) * 32, wn = (w & 1) * 64;
    int ra = t >> 2, ka = (t & 3) ^ ((ra >> 1) & 3);
    int tok0 = rowsS[ra]; if (tok0 < 0) tok0 = 0;
    const short* Xs = (const short*)xn_b;
    const short* Ws = (const short*)(e1T + (long)e * HIDC * DIMC);
    const short* a0 = Xs + (long)tok0 * DIMC + ka * 8;
    int p0 = t, p1 = t + 256;
    int rb0 = p0 >> 2, kb0 = (p0 & 3) ^ ((rb0 >> 1) & 3);
    int rb1 = p1 >> 2, kb1 = (p1 & 3) ^ ((rb1 >> 1) & 3);
    const short* b0 = Ws + (long)(bn + rb0) * DIMC + kb0 * 8;
    const short* b1 = Ws + (long)(bn + rb1) * DIMC + kb1 * 8;
    int fr = lane & 15, fq = lane >> 4;
    int aOff[2], bOff[4];
    #pragma unroll
    for (int i = 0; i < 2; i++) {
        int row = wm + i * 16 + fr;
        aOff[i] = row * 32 + ((fq ^ ((row >> 1) & 3)) * 8);
    }
    #pragma unroll
    for (int j = 0; j < 4; j++) {
        int col = wn + j * 16 + fr;
        bOff[j] = col * 32 + ((fq ^ ((col >> 1) & 3)) * 8);
    }
    f32x4 acc[2][4] = {};
    bf16x8 va_0  = *(const bf16x8*)a0;
    bf16x8 vb0_0 = *(const bf16x8*)b0;
    bf16x8 vb1_0 = *(const bf16x8*)b1;
    bf16x8 va_1  = *(const bf16x8*)(a0 + 32);
    bf16x8 vb0_1 = *(const bf16x8*)(b0 + 32);
    bf16x8 vb1_1 = *(const bf16x8*)(b1 + 32);
    for (int kk = 0; kk < DIMC; kk += 64) {
        *(bf16x8*)&As[t * 8] = va_0;
        *(bf16x8*)&Bs[p0 * 8] = vb0_0;
        *(bf16x8*)&Bs[p1 * 8] = vb1_0;
        __syncthreads();
        {
            int kn = (kk + 64 < DIMC) ? kk + 64 : kk;
            va_0  = *(const bf16x8*)(a0 + kn);
            vb0_0 = *(const bf16x8*)(b0 + kn);
            vb1_0 = *(const bf16x8*)(b1 + kn);
        }
        {
            bf16x8 aF[2], bF[4];
            #pragma unroll
            for (int i = 0; i < 2; i++) aF[i] = *(const bf16x8*)&As[aOff[i]];
            #pragma unroll
            for (int j = 0; j < 4; j++) bF[j] = *(const bf16x8*)&Bs[bOff[j]];
            #pragma unroll
            for (int i = 0; i < 2; i++)
            #pragma unroll
            for (int j = 0; j < 4; j++)
                acc[i][j] = __builtin_amdgcn_mfma_f32_16x16x32_bf16(aF[i], bF[j], acc[i][j], 0, 0, 0);
        }
        *(bf16x8*)&As[2048 + t * 8] = va_1;
        *(bf16x8*)&Bs[4096 + p0 * 8] = vb0_1;
        *(bf16x8*)&Bs[4096 + p1 * 8] = vb1_1;
        __syncthreads();
        {
            int kn = (kk + 96 < DIMC) ? kk + 96 : kk + 32;
            va_1  = *(const bf16x8*)(a0 + kn);
            vb0_1 = *(const bf16x8*)(b0 + kn);
            vb1_1 = *(const bf16x8*)(b1 + kn);
        }
        {
            bf16x8 aF[2], bF[4];
            #pragma unroll
            for (int i = 0; i < 2; i++) aF[i] = *(const bf16x8*)&As[2048 + aOff[i]];
            #pragma unroll
            for (int j = 0; j < 4; j++) bF[j] = *(const bf16x8*)&Bs[4096 + bOff[j]];
            #pragma unroll
            for (int i = 0; i < 2; i++)
            #pragma unroll
            for (int j = 0; j < 4; j++)
                acc[i][j] = __builtin_amdgcn_mfma_f32_16x16x32_bf16(aF[i], bF[j], acc[i][j], 0, 0, 0);
        }
    }
    const float* bb = e_b1 + (long)e * HIDC;
    #pragma unroll
    for (int i = 0; i < 2; i++)
    #pragma unroll
    for (int r = 0; r < 4; r++) {
        int tok = rowsS[wm + i * 16 + fq * 4 + r];
        if (tok < 0) continue;
        #pragma unroll
        for (int j = 0; j < 4; j++) {
            int col = bn + wn + j * 16 + fr;
            float v = acc[i][j][r] + bb[col];
            v = 0.5f * v * (1.f + erff(v * 0.70710678f));
            hid_b[(long)tok * HIDC + col] = __float2bfloat16(v);
        }
    }
}

// ---- MoE grouped MFMA GEMM2, split-K (z=0/1 over K halves), 64x64 tile, depth-2 ----
// Writes raw fp32 partials (no bias/resid); combine kernel finishes.
__global__ __launch_bounds__(256) void moe64k2_kernel(
    const bf16* __restrict__ hid_b, const bf16* __restrict__ e2T,
    const int* __restrict__ table, const int* __restrict__ ntiles, const int* __restrict__ perm,
    float* __restrict__ pa, float* __restrict__ pb) {
    if (blockIdx.y >= ntiles[0]) return;
    int e = table[2 * blockIdx.y], row0 = table[2 * blockIdx.y + 1];
    int bn = blockIdx.x * 64;
    int kbase = blockIdx.z * (HIDC / 2);
    float* part = blockIdx.z ? pb : pa;
    __shared__ short As[2 * 2048];
    __shared__ short Bs[2 * 2048];
    __shared__ int rowsS[64];
    int t = threadIdx.x, lane = t & 63, w = t >> 6;
    if (t < 64) rowsS[t] = perm[row0 + t];
    __syncthreads();
    int wm = (w >> 1) * 32, wn = (w & 1) * 32;
    int r0 = t >> 2, k0s = (t & 3) ^ ((r0 >> 1) & 3);
    int tok0 = rowsS[r0]; if (tok0 < 0) tok0 = 0;
    const short* Hs = (const short*)hid_b;
    const short* Ws = (const short*)(e2T + (long)e * DIMC * HIDC);
    const short* a0 = Hs + (long)tok0 * HIDC + kbase + k0s * 8;
    const short* b0 = Ws + (long)(bn + r0) * HIDC + kbase + k0s * 8;
    int fr = lane & 15, fq = lane >> 4;
    int aOff[2], bOff[2];
    #pragma unroll
    for (int i = 0; i < 2; i++) {
        int row = wm + i * 16 + fr;
        aOff[i] = row * 32 + ((fq ^ ((row >> 1) & 3)) * 8);
        int col = wn + i * 16 + fr;
        bOff[i] = col * 32 + ((fq ^ ((col >> 1) & 3)) * 8);
    }
    f32x4 acc[2][2] = {};
    bf16x8 va_0 = *(const bf16x8*)a0;
    bf16x8 vb_0 = *(const bf16x8*)b0;
    bf16x8 va_1 = *(const bf16x8*)(a0 + 32);
    bf16x8 vb_1 = *(const bf16x8*)(b0 + 32);
    const int KH = HIDC / 2;
    for (int kk = 0; kk < KH; kk += 64) {
        // ---- step 0 ----
        *(bf16x8*)&As[t * 8] = va_0;
        *(bf16x8*)&Bs[t * 8] = vb_0;
        __syncthreads();
        {
            int kn = (kk + 64 < KH) ? kk + 64 : kk;
            va_0 = *(const bf16x8*)(a0 + kn);
            vb_0 = *(const bf16x8*)(b0 + kn);
        }
        {
            bf16x8 aF[2], bF[2];
            #pragma unroll
            for (int i = 0; i < 2; i++) {
                aF[i] = *(const bf16x8*)&As[aOff[i]];
                bF[i] = *(const bf16x8*)&Bs[bOff[i]];
            }
            #pragma unroll
            for (int i = 0; i < 2; i++)
            #pragma unroll
            for (int j = 0; j < 2; j++)
                acc[i][j] = __builtin_amdgcn_mfma_f32_16x16x32_bf16(aF[i], bF[j], acc[i][j], 0, 0, 0);
        }
        // ---- step 1 ----
        *(bf16x8*)&As[2048 + t * 8] = va_1;
        *(bf16x8*)&Bs[2048 + t * 8] = vb_1;
        __syncthreads();
        {
            int kn = (kk + 96 < KH) ? kk + 96 : kk + 32;
            va_1 = *(const bf16x8*)(a0 + kn);
            vb_1 = *(const bf16x8*)(b0 + kn);
        }
        {
            bf16x8 aF[2], bF[2];
            #pragma unroll
            for (int i = 0; i < 2; i++) {
                aF[i] = *(const bf16x8*)&As[2048 + aOff[i]];
                bF[i] = *(const bf16x8*)&Bs[2048 + bOff[i]];
            }
            #pragma unroll
            for (int i = 0; i < 2; i++)
            #pragma unroll
            for (int j = 0; j < 2; j++)
                acc[i][j] = __builtin_amdgcn_mfma_f32_16x16x32_bf16(aF[i], bF[j], acc[i][j], 0, 0, 0);
        }
    }
    #pragma unroll
    for (int i = 0; i < 2; i++)
    #pragma unroll
    for (int r = 0; r < 4; r++) {
        int tok = rowsS[wm + i * 16 + fq * 4 + r];
        if (tok < 0) continue;
        #pragma unroll
        for (int j = 0; j < 2; j++) {
            int col = bn + wn + j * 16 + fr;
            part[(long)tok * DIMC + col] = acc[i][j][r];
        }
    }
}

// ---- MoE combine: out = resid + pa + pb + b2[expert(tok)] -> split bf16 ----
__global__ void moecomb_kernel(const float* __restrict__ pa, const float* __restrict__ pb,
                               const float* __restrict__ resid, const float* __restrict__ e_b2,
                               const int* __restrict__ idx,
                               bf16* __restrict__ outh, bf16* __restrict__ outl) {
    long g = (long)(blockIdx.x * blockDim.x + threadIdx.x) * 4;
    int tok = (int)(g >> 9);
    int col = (int)(g & 511);
    int e = idx[tok];
    float4 a = *(const float4*)(pa + g);
    float4 b = *(const float4*)(pb + g);
    float4 r = *(const float4*)(resid + g);
    float4 bi = *(const float4*)(e_b2 + (long)e * DIMC + col);
    float v[4] = {r.x + a.x + b.x + bi.x, r.y + a.y + b.y + bi.y,
                  r.z + a.z + b.z + bi.z, r.w + a.w + b.w + bi.w};
    #pragma unroll
    for (int j = 0; j < 4; j++) {
        bf16 hh, ll; split2(v[j], hh, ll);
        outh[g + j] = hh; outl[g + j] = ll;
    }
}

// ---------------- LayerNorm: optional fp32 + bf16 hi/lo outputs ----------------
__global__ void ln_kernel(const float* __restrict__ x, const float* __restrict__ g,
                          const float* __restrict__ b, float* __restrict__ y,
                          bf16* __restrict__ yh, bf16* __restrict__ yl) {
    int tok = blockIdx.x;
    int t = threadIdx.x;
    const float* xr = x + (long)tok * DIMC;
    float v0 = xr[t], v1 = xr[t + 256];
    __shared__ float red[256];
    red[t] = v0 + v1; __syncthreads();
    for (int s = 128; s > 0; s >>= 1) { if (t < s) red[t] += red[t + s]; __syncthreads(); }
    float mu = red[0] * (1.f / DIMC);
    __syncthreads();
    float d0 = v0 - mu, d1 = v1 - mu;
    red[t] = d0 * d0 + d1 * d1; __syncthreads();
    for (int s = 128; s > 0; s >>= 1) { if (t < s) red[t] += red[t + s]; __syncthreads(); }
    float rs = rsqrtf(red[0] * (1.f / DIMC) + 1e-5f);
    float o0 = d0 * rs * g[t] + b[t];
    float o1 = d1 * rs * g[t + 256] + b[t + 256];
    if (y) { y[(long)tok * DIMC + t] = o0; y[(long)tok * DIMC + t + 256] = o1; }
    bf16 h, l;
    split2(o0, h, l); yh[(long)tok * DIMC + t] = h;       yl[(long)tok * DIMC + t] = l;
    split2(o1, h, l); yh[(long)tok * DIMC + t + 256] = h; yl[(long)tok * DIMC + t + 256] = l;
}

// ---------------- router text-part tw = w @ r_text_mu, wave-parallel (+ cnt zero) ----------------
__global__ void tw_kernel(const float* __restrict__ w, const float* __restrict__ r_text_mu,
                          float* __restrict__ tw, int* __restrict__ cnt) {
    int t = threadIdx.x, wv = t >> 6, lane = t & 63;
    if (blockIdx.x == 0 && t < NE) cnt[t] = 0;
    int entry = blockIdx.x * 4 + wv;          // 0..511
    int b = entry >> 7, c = entry & 127;
    const float* wr = w + (long)b * LATC;
    float s = 0.f;
    #pragma unroll
    for (int j = 0; j < 8; j++) {
        int k = lane + j * 64;
        s += wr[k] * r_text_mu[(long)k * 128 + c];
    }
    s += __shfl_xor(s, 1);
    s += __shfl_xor(s, 2);
    s += __shfl_xor(s, 4);
    s += __shfl_xor(s, 8);
    s += __shfl_xor(s, 16);
    s += __shfl_xor(s, 32);
    if (lane == 0) tw[entry] = s;
}

// ---------------- router: perm poison + tp (from tw) + logits + argmax ----------------
__global__ void route_kernel(const float* __restrict__ feat, const float* __restrict__ tw,
                             const float* __restrict__ r_comb_mu, const float* __restrict__ r_temp,
                             float* __restrict__ onehot, int* __restrict__ idx, int* __restrict__ cnt,
                             int* __restrict__ perm) {
    __shared__ float rc[256][8];
    __shared__ float tws[512];
    __shared__ float tps[32];
    int t = threadIdx.x;
    for (int i = t; i < 2048; i += 256) rc[i >> 3][i & 7] = r_comb_mu[i];
    for (int i = t; i < 512; i += 256) tws[i] = tw[i];
    __syncthreads();
    if (t < 32) {
        int b = t >> 3, e = t & 7;
        float s = 0.f;
        #pragma unroll 8
        for (int c = 0; c < 128; c++) s += tws[b * 128 + c] * rc[128 + c][e];
        tps[t] = s;
    }
    __syncthreads();
    int n = blockIdx.x * blockDim.x + t;
    if (n < MAXT * 64) perm[n] = -1;
    if (n >= NTOK) return;
    int b = n >> 10;
    float tmp = fmaxf(r_temp[0], 0.1f);
    float invt = 1.f / tmp;
    const float4* fr4 = (const float4*)(feat + (long)n * 128);
    float lg[8];
    #pragma unroll
    for (int e = 0; e < 8; e++) lg[e] = 0.f;
    #pragma unroll
    for (int c4 = 0; c4 < 32; c4++) {
        float4 f = fr4[c4];
        float fa[4] = {f.x, f.y, f.z, f.w};
        #pragma unroll
        for (int q = 0; q < 4; q++) {
            int c = c4 * 4 + q;
            #pragma unroll
            for (int e = 0; e < 8; e++) lg[e] += fa[q] * rc[c][e];
        }
    }
    #pragma unroll
    for (int e = 0; e < 8; e++) lg[e] = (lg[e] + tps[b * 8 + e]) * invt;
    float best = lg[0]; int bi = 0;
    #pragma unroll
    for (int e = 1; e < 8; e++) { if (lg[e] > best) { best = lg[e]; bi = e; } }
    #pragma unroll
    for (int e = 0; e < 8; e++) onehot[(long)n * 8 + e] = (e == bi) ? 1.f : 0.f;
    idx[n] = bi;
    atomicAdd(&cnt[bi], 1);
}

// ---------------- offsets + scatter fused (single block, LDS cursors) ----------------
__global__ void offscatter_kernel(const int* __restrict__ cnt, const int* __restrict__ idx,
                                  int* __restrict__ ntiles, int* __restrict__ table,
                                  int* __restrict__ perm) {
    __shared__ int cur[NE];
    int t = threadIdx.x;
    if (t == 0) {
        int po = 0, nt = 0;
        for (int e = 0; e < NE; e++) {
            cur[e] = po;
            int tiles = (cnt[e] + 63) >> 6;
            for (int j = 0; j < tiles; j++) { table[2 * nt] = e; table[2 * nt + 1] = po + j * 64; nt++; }
            po += tiles * 64;
        }
        ntiles[0] = nt;
    }
    __syncthreads();
    for (int n = t; n < NTOK; n += 256) {
        int e = idx[n];
        int pos = atomicAdd(&cur[e], 1);
        perm[pos] = n;
    }
}

extern "C" void kernel_launch(void* const* d_in, const int* in_sizes, int n_in,
                              void* d_out, int out_size, void* d_ws, size_t ws_size,
                              hipStream_t stream) {
    const float* x        = (const float*)d_in[0];
    const float* w        = (const float*)d_in[1];
    const float* text     = (const float*)d_in[2];
    const float* pin_w    = (const float*)d_in[3];
    const float* pin_mw   = (const float*)d_in[4];
    const float* pin_mb   = (const float*)d_in[5];
    const float* pout_w   = (const float*)d_in[6];
    const float* pout_mw  = (const float*)d_in[7];
    const float* pout_mb  = (const float*)d_in[8];
    const float* ln1g     = (const float*)d_in[9];
    const float* ln1b     = (const float*)d_in[10];
    const float* ln2g     = (const float*)d_in[11];
    const float* ln2b     = (const float*)d_in[12];
    const float* ln3g     = (const float*)d_in[13];
    const float* ln3b     = (const float*)d_in[14];
    const float* sa_in_w  = (const float*)d_in[15];
    const float* sa_in_b  = (const float*)d_in[16];
    const float* sa_out_w = (const float*)d_in[17];
    const float* sa_out_b = (const float*)d_in[18];
    const float* ca_in_w  = (const float*)d_in[19];
    const float* ca_in_b  = (const float*)d_in[20];
    const float* ca_out_w = (const float*)d_in[21];
    const float* ca_out_b = (const float*)d_in[22];
    const float* r_feat   = (const float*)d_in[23];
    const float* r_text   = (const float*)d_in[24];
    const float* r_comb   = (const float*)d_in[25];
    const float* r_temp   = (const float*)d_in[26];
    const float* e_w1     = (const float*)d_in[27];
    const float* e_b1     = (const float*)d_in[28];
    const float* e_w2     = (const float*)d_in[29];
    const float* e_b2     = (const float*)d_in[30];

    float* out    = (float*)d_out;               // [B, DIM, H, W]
    float* onehot = out + (long)BB * DIMC * HWX; // [4096, 8]

    // ---------------- workspace: fp32 pool ----------------
    float* f32p = (float*)d_ws;
    float* style_in  = f32p;                 // 2048 (reused as tw[512] after wtmod2)
    float* style_out = f32p + 2048;          // 2048
    int*   idx       = (int*)(f32p + 4128);  // 4096
    int*   cnt       = (int*)(f32p + 8224);  // 8
    int*   ntiles    = (int*)(f32p + 8240);  // 8
    int*   table     = (int*)(f32p + 8248);  // 256
    int*   perm      = (int*)(f32p + 8504);  // 4608 -> ends 13112
    float* x_flat    = f32p + 13496;         // 2097152
    float* xn        = x_flat + 2097152;     // 2097152 (home of wtC split)
    float* qkv       = xn + 2097152;         // 6291456 (SA q split / CA q split home)
    float* spill     = qkv + 6291456;        // 2097152 (e2T tail)
    float* tw        = style_in;             // 512 floats, dead style region

    // ---------------- bf16 pool (phase-aliased) ----------------
    bf16* bp = (bf16*)(f32p + 12596408);
    bf16* R1 = bp;                           // 6291456 elems, phases
    bf16* xT_h  = R1;
    bf16* xT_l  = R1 + 2097152;
    bf16* wtA_h = R1 + 4194304;
    bf16* wtA_l = R1 + 5242880;
    bf16* obuf_h = R1;
    bf16* obuf_l = R1 + 2097152;
    bf16* kvt_h  = R1 + 4194304;                       // [308][1024] split
    bf16* kvt_l  = kvt_h + 315392;
    float* feat  = (float*)(kvt_l + 315392);           // 524288 fp32
    bf16* xn_h = R1 + 6291456;               // 2097152
    bf16* xn_l = xn_h + 2097152;             // 2097152
    bf16* WB   = xn_l + 2097152;             // 8388608: weights (early) / hid_b (late)
    bf16* text_h   = WB;
    bf16* text_l   = text_h + 157696;
    bf16* sawin_h  = text_l + 157696;
    bf16* sawin_l  = sawin_h + 786432;
    bf16* sawout_h = sawin_l + 786432;
    bf16* sawout_l = sawout_h + 262144;
    bf16* caw_h    = sawout_l + 262144;
    bf16* caw_l    = caw_h + 786432;
    bf16* cawout_h = caw_l + 786432;
    bf16* cawout_l = cawout_h + 262144;
    bf16* rfT_h    = cawout_l + 262144;      // [128][512] split r_feat^T
    bf16* rfT_l    = rfT_h + 65536;
    bf16* hid_b    = WB;                     // overlays weights after ca_out
    bf16* e1T = (bf16*)qkv;                  // [8][2048][512] in qkv+spill
    bf16* e2T = e1T + 8388608;
    bf16* xfl_h = xn_h;                      // combine writes split output here
    bf16* xfl_l = xn_l;
    bf16* wtC_h = (bf16*)xn;                 // modconv-out weight (dead fp32 region)
    bf16* wtC_l = wtC_h + 1048576;
    bf16* q_h = (bf16*)qkv;                  // [4096][1536]
    bf16* q_l = q_h + 6291456;
    bf16* ca_qh = (bf16*)qkv;                // [4096][512]
    bf16* ca_ql = ca_qh + 2097152;
    float* part_a = out;                     // 2097152 fp32, dead until modconv-out
    float* part_b = (float*)R1;              // 2097152 fp32 in dead R1 region
    (void)ws_size; (void)spill;

    auto mg = [&](const bf16* Ah, const bf16* Al, const bf16* Bh, const bf16* Bl,
                  const float* bias, const float* resid, float* C, bf16* Oh, bf16* Ol,
                  int M, int N, int K, long ab, long bb, long cb, int csm, int csn, int nb) {
        dim3 g(N / 64, (M + 63) / 64, nb);
        hipLaunchKernelGGL(mgemm64_kernel, g, dim3(256), 0, stream,
                           Ah, Al, Bh, Bl, bias, resid, C, Oh, Ol, M, N, K, ab, bb, cb, csm, csn);
    };

    // ---- fused input conversions (hi/lo): one launch for all 5 flat arrays ----
    {
        int n0 = 1536 * 512, n1 = 512 * 512, n2 = 1536 * 512, n3 = 512 * 512, n4 = BB * TXT * 512;
        int total = n0 + n1 + n2 + n3 + n4;
        hipLaunchKernelGGL(cvtall_kernel, dim3((total / 4 + 255) / 256), dim3(256), 0, stream,
                           sa_in_w, sawin_h, sawin_l, n0,
                           sa_out_w, sawout_h, sawout_l, n1,
                           ca_in_w, caw_h, caw_l, n2,
                           ca_out_w, cawout_h, cawout_l, n3,
                           text, text_h, text_l, n4);
    }
    // ---- fused transposes: x (z<4) + r_feat (z==4) ----
    hipLaunchKernelGGL(trcvt2x_kernel, dim3(32, 16, 5), dim3(256), 0, stream,
                       x, xT_h, xT_l, r_feat, rfT_h, rfT_l);

    // ---- both modconv styles + weights up front (wtC in dead xn region) ----
    hipLaunchKernelGGL(style2_kernel, dim3(16), dim3(256), 0, stream,
                       w, pin_mw, pin_mb, pout_mw, pout_mb, style_in, style_out);
    hipLaunchKernelGGL(wtmod2_kernel, dim3(2 * BB * DIMC), dim3(256), 0, stream,
                       pin_w, style_in, pout_w, style_out, wtA_h, wtA_l, wtC_h, wtC_l);
    // ---- router text part, early (style_in region now dead -> tw) ----
    hipLaunchKernelGGL(tw_kernel, dim3(128), dim3(256), 0, stream, w, r_text, tw, cnt);

    // ---- modconv in ----
    mg(xT_h, xT_l, wtA_h, wtA_l, nullptr, nullptr, x_flat, nullptr, nullptr,
       HWX, DIMC, DIMC, (long)HWX * DIMC, (long)DIMC * DIMC, (long)HWX * DIMC, DIMC, 1, BB);

    // ---- LN1 + self-attention (split MFMA) ----
    hipLaunchKernelGGL(ln_kernel, dim3(NTOK), dim3(256), 0, stream, x_flat, ln1g, ln1b,
                       (float*)nullptr, xn_h, xn_l);
    // qkv projection via high-reuse 128x64 kernel
    hipLaunchKernelGGL(mgemm128x64_kernel, dim3(1536 / 64, NTOK / 128), dim3(256), 0, stream,
                       xn_h, xn_l, sawin_h, sawin_l, sa_in_b, q_h, q_l, NTOK, 1536, 512);
    hipLaunchKernelGGL(sa_mfma_kernel, dim3(16, HEADS, BB), dim3(256), 0, stream,
                       q_h, q_l, obuf_h, obuf_l);
    mg(obuf_h, obuf_l, sawout_h, sawout_l, sa_out_b, x_flat, x_flat, nullptr, nullptr,
       NTOK, 512, 512, 0, 0, 0, 512, 1, 1);

    // ---- LN2 + cross-attention (split MFMA) ----
    hipLaunchKernelGGL(ln_kernel, dim3(NTOK), dim3(256), 0, stream, x_flat, ln2g, ln2b,
                       (float*)nullptr, xn_h, xn_l);
    mg(xn_h, xn_l, caw_h, caw_l, ca_in_b, nullptr, nullptr, ca_qh, ca_ql,
       NTOK, 512, 512, 0, 0, 0, 512, 1, 1);
    mg(text_h, text_l, caw_h + 512 * 512, caw_l + 512 * 512, ca_in_b + 512, nullptr, nullptr,
       kvt_h, kvt_l, BB * TXT, 1024, 512, 0, 0, 0, 1024, 1, 1);
    hipLaunchKernelGGL(ca_mfma_kernel, dim3(16, HEADS, BB), dim3(256), 0, stream,
                       ca_qh, ca_ql, kvt_h, kvt_l, obuf_h, obuf_l);
    // expert weight transposes (qkv region dead after ca_mfma) — one fused launch
    hipLaunchKernelGGL(tr2x_kernel, dim3(64, 16, 16), dim3(256), 0, stream,
                       e_w1, e1T, e_w2, e2T);
    mg(obuf_h, obuf_l, cawout_h, cawout_l, ca_out_b, x_flat, x_flat, nullptr, nullptr,
       NTOK, 512, 512, 0, 0, 0, 512, 1, 1);

    // ---- LN3 + router (feat via split MFMA) ----
    hipLaunchKernelGGL(ln_kernel, dim3(NTOK), dim3(256), 0, stream, x_flat, ln3g, ln3b,
                       (float*)nullptr, xn_h, xn_l);
    mg(xn_h, xn_l, rfT_h, rfT_l, nullptr, nullptr, feat, nullptr, nullptr,
       NTOK, 128, 512, 0, 0, 0, 128, 1, 1);
    hipLaunchKernelGGL(route_kernel, dim3(18), dim3(256), 0, stream,
                       feat, tw, r_comb, r_temp, onehot, idx, cnt, perm);
    hipLaunchKernelGGL(offscatter_kernel, dim3(1), dim3(256), 0, stream,
                       cnt, idx, ntiles, table, perm);

    // ---- MoE grouped MFMA GEMMs: gemm1 64x128; gemm2 split-K=2 + combine ----
    hipLaunchKernelGGL(moe128_1_kernel, dim3(HIDC / 128, MAXT), dim3(256), 0, stream,
                       xn_h, e1T, e_b1, table, ntiles, perm, hid_b);
    hipLaunchKernelGGL(moe64k2_kernel, dim3(DIMC / 64, MAXT, 2), dim3(256), 0, stream,
                       hid_b, e2T, table, ntiles, perm, part_a, part_b);
    hipLaunchKernelGGL(moecomb_kernel, dim3(NTOK * DIMC / 4 / 256), dim3(256), 0, stream,
                       part_a, part_b, x_flat, e_b2, idx, xfl_h, xfl_l);

    // ---- modconv out (weights already prepared; overwrites part_a=out) ----
    mg(wtC_h, wtC_l, xfl_h, xfl_l, nullptr, nullptr, out, nullptr, nullptr,
       DIMC, HWX, DIMC, (long)DIMC * DIMC, (long)HWX * DIMC, (long)DIMC * HWX, HWX, 1, BB);
}